// Round 2
// baseline (1707.446 us; speedup 1.0000x reference)
//
#include <hip/hip_runtime.h>
#include <hip/hip_bf16.h>
#include <math.h>

#define SCAN_T 256
#define SCAN_ELEMS 2048

__device__ __forceinline__ float wave_reduce_max(float v) {
  #pragma unroll
  for (int off = 32; off; off >>= 1) v = fmaxf(v, __shfl_xor(v, off));
  return v;
}
__device__ __forceinline__ float wave_reduce_sum(float v) {
  #pragma unroll
  for (int off = 32; off; off >>= 1) v += __shfl_xor(v, off);
  return v;
}

// ---------------- CSR build ----------------

__global__ void k_count_deg(const int* __restrict__ ei, int* __restrict__ deg,
                            int E, int EE) {
  int e = blockIdx.x * blockDim.x + threadIdx.x;
  if (e >= EE) return;
  int d = (e < E) ? ei[E + e] : (e - E);
  atomicAdd(&deg[d], 1);
}

__global__ void k_scan_partial(const int* __restrict__ deg, int* __restrict__ partial, int n) {
  __shared__ int s[SCAN_T];
  int base = blockIdx.x * SCAN_ELEMS;
  int sum = 0;
  for (int i = threadIdx.x; i < SCAN_ELEMS; i += SCAN_T) {
    int idx = base + i;
    if (idx < n) sum += deg[idx];
  }
  s[threadIdx.x] = sum;
  __syncthreads();
  for (int off = SCAN_T / 2; off; off >>= 1) {
    if (threadIdx.x < off) s[threadIdx.x] += s[threadIdx.x + off];
    __syncthreads();
  }
  if (threadIdx.x == 0) partial[blockIdx.x] = s[0];
}

__global__ void k_scan_top(int* __restrict__ partial, int nb, int* __restrict__ total) {
  if (threadIdx.x == 0 && blockIdx.x == 0) {
    int run = 0;
    for (int i = 0; i < nb; i++) { int v = partial[i]; partial[i] = run; run += v; }
    *total = run;
  }
}

__global__ void k_scan_final(const int* __restrict__ deg, const int* __restrict__ partial,
                             int* __restrict__ rowptr, int n) {
  __shared__ int s[SCAN_T];
  int b = blockIdx.x, t = threadIdx.x;
  int base = b * SCAN_ELEMS + t * 8;
  int v[8]; int tot = 0;
  #pragma unroll
  for (int i = 0; i < 8; i++) { int idx = base + i; v[i] = (idx < n) ? deg[idx] : 0; tot += v[i]; }
  s[t] = tot;
  __syncthreads();
  for (int off = 1; off < SCAN_T; off <<= 1) {
    int add = (t >= off) ? s[t - off] : 0;
    __syncthreads();
    s[t] += add;
    __syncthreads();
  }
  int excl = (t ? s[t - 1] : 0) + partial[b];
  #pragma unroll
  for (int i = 0; i < 8; i++) { int idx = base + i; if (idx < n) rowptr[idx] = excl; excl += v[i]; }
}

__global__ void k_scatter(const int* __restrict__ ei, const int* __restrict__ rowptr,
                          int* __restrict__ fill, int* __restrict__ csr_src, int E, int EE) {
  int e = blockIdx.x * blockDim.x + threadIdx.x;
  if (e >= EE) return;
  int s, d;
  if (e < E) { s = ei[e]; d = ei[E + e]; } else { s = e - E; d = s; }
  int pos = rowptr[d] + atomicAdd(&fill[d], 1);
  csr_src[pos] = s;
}

// ---------------- GEMM h = x@W fused with alpha reductions ----------------

template <int FIN>
__global__ __launch_bounds__(256) void k_gemm2(
    const float* __restrict__ x, const float* __restrict__ W,
    const float* __restrict__ avs, const float* __restrict__ avd,
    float* __restrict__ h, float* __restrict__ as_out, float* __restrict__ ad_out,
    int Nn, int ntiles) {
  __shared__ float Wl[FIN * 64];
  __shared__ float xs[2][32 * FIN];
  int t = threadIdx.x, lane = t & 63, wid = t >> 6;

  for (int i = t; i < FIN * 16; i += 256)
    ((float4*)Wl)[i] = ((const float4*)W)[i];
  float As = avs[lane], Ad = avd[lane];

  const size_t limit4 = ((size_t)Nn * FIN) / 4;

  auto stage = [&](int buf, int tl) {
    size_t g0 = (size_t)tl * (32 * FIN / 4);
    float4* dst = (float4*)xs[buf];
    const float4* src = (const float4*)x;
    #pragma unroll
    for (int i = 0; i < 8 * FIN / 256; i++) {
      int li = i * 256 + t;
      size_t gi = g0 + li;
      dst[li] = (gi < limit4) ? src[gi] : make_float4(0.f, 0.f, 0.f, 0.f);
    }
  };

  int nb = gridDim.x;
  int tile = blockIdx.x;
  if (tile >= ntiles) return;

  stage(0, tile);
  __syncthreads();
  int buf = 0;
  while (tile < ntiles) {
    int nxt = tile + nb;
    if (nxt < ntiles) stage(buf ^ 1, nxt);

    int row0 = tile * 32 + wid * 8;
    float acc[8];
    #pragma unroll
    for (int r = 0; r < 8; r++) acc[r] = 0.f;
    const float* xw = &xs[buf][(wid * 8) * FIN];

    #pragma unroll
    for (int kb = 0; kb < FIN; kb += 32) {
      float wreg[32];
      #pragma unroll
      for (int k = 0; k < 32; k++) wreg[k] = Wl[(kb + k) * 64 + lane];
      #pragma unroll
      for (int r = 0; r < 8; r++) {
        const float4* xr = (const float4*)(xw + r * FIN + kb);
        #pragma unroll
        for (int k4 = 0; k4 < 8; k4++) {
          float4 xv = xr[k4];   // wave-uniform address -> LDS broadcast
          acc[r] = fmaf(xv.x, wreg[k4 * 4 + 0], acc[r]);
          acc[r] = fmaf(xv.y, wreg[k4 * 4 + 1], acc[r]);
          acc[r] = fmaf(xv.z, wreg[k4 * 4 + 2], acc[r]);
          acc[r] = fmaf(xv.w, wreg[k4 * 4 + 3], acc[r]);
        }
      }
    }

    #pragma unroll
    for (int r = 0; r < 8; r++) {
      int row = row0 + r;
      if (row < Nn) {
        h[(size_t)row * 64 + lane] = acc[r];
        float vs = wave_reduce_sum(acc[r] * As);
        float vd = wave_reduce_sum(acc[r] * Ad);
        if (lane == 0) { as_out[row] = vs; ad_out[row] = vd; }
      }
    }

    __syncthreads();
    buf ^= 1;
    tile = nxt;
  }
}

// ---------------- per-dst-node softmax aggregation ----------------

__global__ __launch_bounds__(256) void k_agg2(
    const int* __restrict__ rowptr, const int* __restrict__ csr_src,
    const float* __restrict__ h, const float* __restrict__ as_,
    const float* __restrict__ ad_, const float* __restrict__ bias,
    float* __restrict__ out, int Nn) {
  int t = threadIdx.x, lane = t & 63, wid = t >> 6;
  int n = blockIdx.x * 4 + wid;
  if (n >= Nn) return;
  int r0 = rowptr[n], r1 = rowptr[n + 1];
  int deg = r1 - r0;
  float ad = ad_[n];
  float acc = 0.f;

  if (deg <= 64) {
    int src = (lane < deg) ? csr_src[r0 + lane] : 0;
    float e = (lane < deg) ? (as_[src] + ad) : -3.0e38f;
    e = (e >= 0.f) ? e : 0.2f * e;
    float m = wave_reduce_max(e);
    float p = (lane < deg) ? __expf(e - m) : 0.f;
    float inv = 1.f / (wave_reduce_sum(p) + 1e-16f);

    int jj = 0;
    for (; jj + 4 <= deg; jj += 4) {
      float p0 = __shfl(p, jj),     p1 = __shfl(p, jj + 1);
      float p2 = __shfl(p, jj + 2), p3 = __shfl(p, jj + 3);
      int s0 = __shfl(src, jj),     s1 = __shfl(src, jj + 1);
      int s2 = __shfl(src, jj + 2), s3 = __shfl(src, jj + 3);
      float v0 = h[(size_t)s0 * 64 + lane];
      float v1 = h[(size_t)s1 * 64 + lane];
      float v2 = h[(size_t)s2 * 64 + lane];
      float v3 = h[(size_t)s3 * 64 + lane];
      acc = fmaf(p0, v0, acc);
      acc = fmaf(p1, v1, acc);
      acc = fmaf(p2, v2, acc);
      acc = fmaf(p3, v3, acc);
    }
    for (; jj < deg; ++jj) {
      float pj = __shfl(p, jj);
      int sj = __shfl(src, jj);
      acc = fmaf(pj, h[(size_t)sj * 64 + lane], acc);
    }
    acc *= inv;
  } else {
    float m = -3.0e38f;
    for (int j = r0 + lane; j < r1; j += 64) {
      float e = as_[csr_src[j]] + ad;
      e = (e >= 0.f) ? e : 0.2f * e;
      m = fmaxf(m, e);
    }
    m = wave_reduce_max(m);
    float ssum = 0.f;
    for (int j = r0; j < r1; ++j) {
      int src = csr_src[j];
      float e = as_[src] + ad;
      e = (e >= 0.f) ? e : 0.2f * e;
      float p = __expf(e - m);
      ssum += p;
      acc = fmaf(p, h[(size_t)src * 64 + lane], acc);
    }
    acc /= (ssum + 1e-16f);
  }

  float o = acc + bias[lane];
  out[(size_t)n * 64 + lane] = fmaxf(o, 0.f);
}

// ---------------- final linear + sigmoid ----------------

__global__ __launch_bounds__(256) void k_final(
    const float* __restrict__ h, const float* __restrict__ Wl,
    const float* __restrict__ bl, float* __restrict__ out, int Nn) {
  int t = threadIdx.x, lane = t & 63, wid = t >> 6;
  int n = blockIdx.x * 4 + wid;
  if (n >= Nn) return;
  float v = h[(size_t)n * 64 + lane] * Wl[lane];
  v = wave_reduce_sum(v);
  if (lane == 0) {
    float z = v + bl[0];
    out[n] = 1.f / (1.f + __expf(-z));
  }
}

extern "C" void kernel_launch(void* const* d_in, const int* in_sizes, int n_in,
                              void* d_out, int out_size, void* d_ws, size_t ws_size,
                              hipStream_t stream) {
  const float* x   = (const float*)d_in[0];
  const int*   ei  = (const int*)d_in[1];
  const float* W1  = (const float*)d_in[2];
  const float* a1s = (const float*)d_in[3];
  const float* a1d = (const float*)d_in[4];
  const float* b1  = (const float*)d_in[5];
  const float* W2  = (const float*)d_in[6];
  const float* a2s = (const float*)d_in[7];
  const float* a2d = (const float*)d_in[8];
  const float* b2  = (const float*)d_in[9];
  const float* W3  = (const float*)d_in[10];
  const float* a3s = (const float*)d_in[11];
  const float* a3d = (const float*)d_in[12];
  const float* b3  = (const float*)d_in[13];
  const float* Wl  = (const float*)d_in[14];
  const float* bl  = (const float*)d_in[15];

  const int N  = in_sizes[0] / 128;
  const int E  = in_sizes[1] / 2;
  const int EE = E + N;

  char* p = (char*)d_ws;
  auto alloc = [&](size_t bytes) { char* r = p; p += (bytes + 255) & ~(size_t)255; return r; };
  int*   deg     = (int*)alloc((size_t)N * 4);
  int*   fill    = (int*)alloc((size_t)N * 4);
  int*   rowptr  = (int*)alloc((size_t)(N + 1) * 4);
  int*   partial = (int*)alloc(256 * 4);
  int*   csr_src = (int*)alloc((size_t)EE * 4);
  float* hbuf    = (float*)alloc((size_t)N * 64 * 4);
  float* obuf    = (float*)alloc((size_t)N * 64 * 4);
  float* as_     = (float*)alloc((size_t)N * 4);
  float* ad_     = (float*)alloc((size_t)N * 4);

  hipMemsetAsync(deg,  0, (size_t)N * 4, stream);
  hipMemsetAsync(fill, 0, (size_t)N * 4, stream);

  int eb = (EE + 255) / 256;
  k_count_deg<<<eb, 256, 0, stream>>>(ei, deg, E, EE);
  int nchunks = (N + SCAN_ELEMS - 1) / SCAN_ELEMS;
  k_scan_partial<<<nchunks, SCAN_T, 0, stream>>>(deg, partial, N);
  k_scan_top<<<1, 64, 0, stream>>>(partial, nchunks, rowptr + N);
  k_scan_final<<<nchunks, SCAN_T, 0, stream>>>(deg, partial, rowptr, N);
  k_scatter<<<eb, 256, 0, stream>>>(ei, rowptr, fill, csr_src, E, EE);

  int ntiles = (N + 31) / 32;
  int gemm_grid = ntiles < 1024 ? ntiles : 1024;
  int nb = (N + 3) / 4;

  k_gemm2<128><<<gemm_grid, 256, 0, stream>>>(x, W1, a1s, a1d, hbuf, as_, ad_, N, ntiles);
  k_agg2<<<nb, 256, 0, stream>>>(rowptr, csr_src, hbuf, as_, ad_, b1, obuf, N);
  k_gemm2<64><<<gemm_grid, 256, 0, stream>>>(obuf, W2, a2s, a2d, hbuf, as_, ad_, N, ntiles);
  k_agg2<<<nb, 256, 0, stream>>>(rowptr, csr_src, hbuf, as_, ad_, b2, obuf, N);
  k_gemm2<64><<<gemm_grid, 256, 0, stream>>>(obuf, W3, a3s, a3d, hbuf, as_, ad_, N, ntiles);
  k_agg2<<<nb, 256, 0, stream>>>(rowptr, csr_src, hbuf, as_, ad_, b3, obuf, N);
  k_final<<<nb, 256, 0, stream>>>(obuf, Wl, bl, (float*)d_out, N);
}

// Round 3
// 608.396 us; speedup vs baseline: 2.8065x; 2.8065x over previous
//
#include <hip/hip_runtime.h>
#include <hip/hip_bf16.h>
#include <math.h>

#define SCAN_T 256
#define SCAN_ELEMS 2048

__device__ __forceinline__ float wave_reduce_max(float v) {
  #pragma unroll
  for (int off = 32; off; off >>= 1) v = fmaxf(v, __shfl_xor(v, off));
  return v;
}
__device__ __forceinline__ float wave_reduce_sum(float v) {
  #pragma unroll
  for (int off = 32; off; off >>= 1) v += __shfl_xor(v, off);
  return v;
}
__device__ __forceinline__ void wave_reduce_sum2(float& a, float& b) {
  #pragma unroll
  for (int off = 32; off; off >>= 1) {
    a += __shfl_xor(a, off);
    b += __shfl_xor(b, off);
  }
}

// ---------------- CSR build ----------------

__global__ void k_count_deg(const int* __restrict__ ei, int* __restrict__ deg,
                            int E, int EE) {
  int e = blockIdx.x * blockDim.x + threadIdx.x;
  if (e >= EE) return;
  int d = (e < E) ? ei[E + e] : (e - E);
  atomicAdd(&deg[d], 1);
}

__global__ void k_scan_partial(const int* __restrict__ deg, int* __restrict__ partial, int n) {
  __shared__ int s[SCAN_T];
  int base = blockIdx.x * SCAN_ELEMS;
  int sum = 0;
  for (int i = threadIdx.x; i < SCAN_ELEMS; i += SCAN_T) {
    int idx = base + i;
    if (idx < n) sum += deg[idx];
  }
  s[threadIdx.x] = sum;
  __syncthreads();
  for (int off = SCAN_T / 2; off; off >>= 1) {
    if (threadIdx.x < off) s[threadIdx.x] += s[threadIdx.x + off];
    __syncthreads();
  }
  if (threadIdx.x == 0) partial[blockIdx.x] = s[0];
}

__global__ void k_scan_top(int* __restrict__ partial, int nb, int* __restrict__ total) {
  if (threadIdx.x == 0 && blockIdx.x == 0) {
    int run = 0;
    for (int i = 0; i < nb; i++) { int v = partial[i]; partial[i] = run; run += v; }
    *total = run;
  }
}

__global__ void k_scan_final(const int* __restrict__ deg, const int* __restrict__ partial,
                             int* __restrict__ rowptr, int n) {
  __shared__ int s[SCAN_T];
  int b = blockIdx.x, t = threadIdx.x;
  int base = b * SCAN_ELEMS + t * 8;
  int v[8]; int tot = 0;
  #pragma unroll
  for (int i = 0; i < 8; i++) { int idx = base + i; v[i] = (idx < n) ? deg[idx] : 0; tot += v[i]; }
  s[t] = tot;
  __syncthreads();
  for (int off = 1; off < SCAN_T; off <<= 1) {
    int add = (t >= off) ? s[t - off] : 0;
    __syncthreads();
    s[t] += add;
    __syncthreads();
  }
  int excl = (t ? s[t - 1] : 0) + partial[b];
  #pragma unroll
  for (int i = 0; i < 8; i++) { int idx = base + i; if (idx < n) rowptr[idx] = excl; excl += v[i]; }
}

__global__ void k_scatter(const int* __restrict__ ei, const int* __restrict__ rowptr,
                          int* __restrict__ fill, int* __restrict__ csr_src, int E, int EE) {
  int e = blockIdx.x * blockDim.x + threadIdx.x;
  if (e >= EE) return;
  int s, d;
  if (e < E) { s = ei[e]; d = ei[E + e]; } else { s = e - E; d = s; }
  int pos = rowptr[d] + atomicAdd(&fill[d], 1);
  csr_src[pos] = s;
}

// ---------------- GEMM h = x@W fused with alpha reductions ----------------
// 32 rows/block, 8 rows/wave, lane = output feature. W in LDS; one 16-wide
// k-block of W cached in VGPRs (wreg[16], k-loop NOT unrolled); x read
// directly from global with wave-uniform addresses (coalesced broadcast).

template <int FIN>
__global__ __launch_bounds__(256, 2) void k_gemm3(
    const float* __restrict__ x, const float* __restrict__ W,
    const float* __restrict__ avs, const float* __restrict__ avd,
    float* __restrict__ h, float* __restrict__ as_out, float* __restrict__ ad_out,
    int Nn) {
  __shared__ float Wl[FIN * 64];
  int t = threadIdx.x, lane = t & 63, wid = t >> 6;
  #pragma unroll
  for (int i = 0; i < FIN / 16; i++)
    ((float4*)Wl)[i * 256 + t] = ((const float4*)W)[i * 256 + t];
  float As = avs[lane], Ad = avd[lane];
  __syncthreads();

  int row0 = blockIdx.x * 32 + wid * 8;
  const float* xp[8];
  #pragma unroll
  for (int r = 0; r < 8; r++) {
    int rc = row0 + r;
    if (rc > Nn - 1) rc = Nn - 1;
    xp[r] = x + (size_t)rc * FIN;
  }
  float acc[8];
  #pragma unroll
  for (int r = 0; r < 8; r++) acc[r] = 0.f;

  #pragma unroll 1
  for (int kb = 0; kb < FIN; kb += 16) {
    float wreg[16];
    #pragma unroll
    for (int k = 0; k < 16; k++) wreg[k] = Wl[(kb + k) * 64 + lane];
    #pragma unroll
    for (int r = 0; r < 8; r++) {
      const float4* xr = (const float4*)(xp[r] + kb);
      float4 a0 = xr[0];
      float4 a1 = xr[1];
      float4 a2 = xr[2];
      float4 a3 = xr[3];
      acc[r] = fmaf(a0.x, wreg[0],  acc[r]);
      acc[r] = fmaf(a0.y, wreg[1],  acc[r]);
      acc[r] = fmaf(a0.z, wreg[2],  acc[r]);
      acc[r] = fmaf(a0.w, wreg[3],  acc[r]);
      acc[r] = fmaf(a1.x, wreg[4],  acc[r]);
      acc[r] = fmaf(a1.y, wreg[5],  acc[r]);
      acc[r] = fmaf(a1.z, wreg[6],  acc[r]);
      acc[r] = fmaf(a1.w, wreg[7],  acc[r]);
      acc[r] = fmaf(a2.x, wreg[8],  acc[r]);
      acc[r] = fmaf(a2.y, wreg[9],  acc[r]);
      acc[r] = fmaf(a2.z, wreg[10], acc[r]);
      acc[r] = fmaf(a2.w, wreg[11], acc[r]);
      acc[r] = fmaf(a3.x, wreg[12], acc[r]);
      acc[r] = fmaf(a3.y, wreg[13], acc[r]);
      acc[r] = fmaf(a3.z, wreg[14], acc[r]);
      acc[r] = fmaf(a3.w, wreg[15], acc[r]);
    }
  }

  #pragma unroll
  for (int r = 0; r < 8; r++) {
    int row = row0 + r;
    if (row < Nn) {
      h[(size_t)row * 64 + lane] = acc[r];
      float vs = acc[r] * As;
      float vd = acc[r] * Ad;
      wave_reduce_sum2(vs, vd);
      if (lane == 0) { as_out[row] = vs; ad_out[row] = vd; }
    }
  }
}

// ---------------- per-dst-node softmax aggregation ----------------
// FINAL=0: out[n][:] = relu(agg + bias)
// FINAL=1: fout[n] = sigmoid(relu(agg + bias) . Wlin + blin)   (readout fused)

template <int FINAL>
__global__ __launch_bounds__(256) void k_agg3(
    const int* __restrict__ rowptr, const int* __restrict__ csr_src,
    const float* __restrict__ h, const float* __restrict__ as_,
    const float* __restrict__ ad_, const float* __restrict__ bias,
    float* __restrict__ out, const float* __restrict__ Wlin,
    const float* __restrict__ blin, float* __restrict__ fout, int Nn) {
  int t = threadIdx.x, lane = t & 63, wid = t >> 6;
  int n = blockIdx.x * 4 + wid;
  if (n >= Nn) return;
  int r0 = rowptr[n], r1 = rowptr[n + 1];
  int deg = r1 - r0;
  float ad = ad_[n];
  float acc = 0.f;

  if (deg <= 64) {
    int src = (lane < deg) ? csr_src[r0 + lane] : 0;
    float e = (lane < deg) ? (as_[src] + ad) : -3.0e38f;
    e = (e >= 0.f) ? e : 0.2f * e;
    float m = wave_reduce_max(e);
    float p = (lane < deg) ? __expf(e - m) : 0.f;
    float inv = 1.f / (wave_reduce_sum(p) + 1e-16f);

    int jj = 0;
    for (; jj + 4 <= deg; jj += 4) {
      float p0 = __shfl(p, jj),     p1 = __shfl(p, jj + 1);
      float p2 = __shfl(p, jj + 2), p3 = __shfl(p, jj + 3);
      int s0 = __shfl(src, jj),     s1 = __shfl(src, jj + 1);
      int s2 = __shfl(src, jj + 2), s3 = __shfl(src, jj + 3);
      float v0 = h[(size_t)s0 * 64 + lane];
      float v1 = h[(size_t)s1 * 64 + lane];
      float v2 = h[(size_t)s2 * 64 + lane];
      float v3 = h[(size_t)s3 * 64 + lane];
      acc = fmaf(p0, v0, acc);
      acc = fmaf(p1, v1, acc);
      acc = fmaf(p2, v2, acc);
      acc = fmaf(p3, v3, acc);
    }
    for (; jj < deg; ++jj) {
      float pj = __shfl(p, jj);
      int sj = __shfl(src, jj);
      acc = fmaf(pj, h[(size_t)sj * 64 + lane], acc);
    }
    acc *= inv;
  } else {
    float m = -3.0e38f;
    for (int j = r0 + lane; j < r1; j += 64) {
      float e = as_[csr_src[j]] + ad;
      e = (e >= 0.f) ? e : 0.2f * e;
      m = fmaxf(m, e);
    }
    m = wave_reduce_max(m);
    float ssum = 0.f;
    for (int j = r0; j < r1; ++j) {
      int src = csr_src[j];
      float e = as_[src] + ad;
      e = (e >= 0.f) ? e : 0.2f * e;
      float p = __expf(e - m);
      ssum += p;
      acc = fmaf(p, h[(size_t)src * 64 + lane], acc);
    }
    acc /= (ssum + 1e-16f);
  }

  float o = fmaxf(acc + bias[lane], 0.f);
  if (FINAL) {
    float rv = wave_reduce_sum(o * Wlin[lane]);
    if (lane == 0) {
      float z = rv + blin[0];
      fout[n] = 1.f / (1.f + __expf(-z));
    }
  } else {
    out[(size_t)n * 64 + lane] = o;
  }
}

extern "C" void kernel_launch(void* const* d_in, const int* in_sizes, int n_in,
                              void* d_out, int out_size, void* d_ws, size_t ws_size,
                              hipStream_t stream) {
  const float* x   = (const float*)d_in[0];
  const int*   ei  = (const int*)d_in[1];
  const float* W1  = (const float*)d_in[2];
  const float* a1s = (const float*)d_in[3];
  const float* a1d = (const float*)d_in[4];
  const float* b1  = (const float*)d_in[5];
  const float* W2  = (const float*)d_in[6];
  const float* a2s = (const float*)d_in[7];
  const float* a2d = (const float*)d_in[8];
  const float* b2  = (const float*)d_in[9];
  const float* W3  = (const float*)d_in[10];
  const float* a3s = (const float*)d_in[11];
  const float* a3d = (const float*)d_in[12];
  const float* b3  = (const float*)d_in[13];
  const float* Wl  = (const float*)d_in[14];
  const float* bl  = (const float*)d_in[15];

  const int N  = in_sizes[0] / 128;
  const int E  = in_sizes[1] / 2;
  const int EE = E + N;

  char* p = (char*)d_ws;
  auto alloc = [&](size_t bytes) { char* r = p; p += (bytes + 255) & ~(size_t)255; return r; };
  int*   deg     = (int*)alloc((size_t)N * 4);
  int*   fill    = (int*)alloc((size_t)N * 4);
  int*   rowptr  = (int*)alloc((size_t)(N + 1) * 4);
  int*   partial = (int*)alloc(256 * 4);
  int*   csr_src = (int*)alloc((size_t)EE * 4);
  float* hbuf    = (float*)alloc((size_t)N * 64 * 4);
  float* obuf    = (float*)alloc((size_t)N * 64 * 4);
  float* as_     = (float*)alloc((size_t)N * 4);
  float* ad_     = (float*)alloc((size_t)N * 4);

  hipMemsetAsync(deg,  0, (size_t)N * 4, stream);
  hipMemsetAsync(fill, 0, (size_t)N * 4, stream);

  int eb = (EE + 255) / 256;
  k_count_deg<<<eb, 256, 0, stream>>>(ei, deg, E, EE);
  int nchunks = (N + SCAN_ELEMS - 1) / SCAN_ELEMS;
  k_scan_partial<<<nchunks, SCAN_T, 0, stream>>>(deg, partial, N);
  k_scan_top<<<1, 64, 0, stream>>>(partial, nchunks, rowptr + N);
  k_scan_final<<<nchunks, SCAN_T, 0, stream>>>(deg, partial, rowptr, N);
  k_scatter<<<eb, 256, 0, stream>>>(ei, rowptr, fill, csr_src, E, EE);

  int gb = (N + 31) / 32;
  int nb = (N + 3) / 4;

  // layer 1
  k_gemm3<128><<<gb, 256, 0, stream>>>(x, W1, a1s, a1d, hbuf, as_, ad_, N);
  k_agg3<0><<<nb, 256, 0, stream>>>(rowptr, csr_src, hbuf, as_, ad_, b1, obuf,
                                    nullptr, nullptr, nullptr, N);
  // layer 2
  k_gemm3<64><<<gb, 256, 0, stream>>>(obuf, W2, a2s, a2d, hbuf, as_, ad_, N);
  k_agg3<0><<<nb, 256, 0, stream>>>(rowptr, csr_src, hbuf, as_, ad_, b2, obuf,
                                    nullptr, nullptr, nullptr, N);
  // layer 3 (+ fused readout)
  k_gemm3<64><<<gb, 256, 0, stream>>>(obuf, W3, a3s, a3d, hbuf, as_, ad_, N);
  k_agg3<1><<<nb, 256, 0, stream>>>(rowptr, csr_src, hbuf, as_, ad_, b3, nullptr,
                                    Wl, bl, (float*)d_out, N);
}

// Round 4
// 566.994 us; speedup vs baseline: 3.0114x; 1.0730x over previous
//
#include <hip/hip_runtime.h>
#include <hip/hip_bf16.h>
#include <math.h>

#define SCAN_T 256
#define SCAN_ELEMS 2048

__device__ __forceinline__ float wave_reduce_max(float v) {
  #pragma unroll
  for (int off = 32; off; off >>= 1) v = fmaxf(v, __shfl_xor(v, off));
  return v;
}
__device__ __forceinline__ float wave_reduce_sum(float v) {
  #pragma unroll
  for (int off = 32; off; off >>= 1) v += __shfl_xor(v, off);
  return v;
}
__device__ __forceinline__ void wave_reduce_sum2(float& a, float& b) {
  #pragma unroll
  for (int off = 32; off; off >>= 1) {
    a += __shfl_xor(a, off);
    b += __shfl_xor(b, off);
  }
}

// async global->LDS, 16 B per lane (global_load_lds_dwordx4)
__device__ __forceinline__ void async_copy16(const float* gsrc, float* ldst) {
  __builtin_amdgcn_global_load_lds(
      (const __attribute__((address_space(1))) void*)gsrc,
      (__attribute__((address_space(3))) void*)ldst, 16, 0, 0);
}

// ---------------- CSR build ----------------

__global__ void k_count_deg(const int* __restrict__ ei, int* __restrict__ deg,
                            int E, int EE) {
  int e = blockIdx.x * blockDim.x + threadIdx.x;
  if (e >= EE) return;
  int d = (e < E) ? ei[E + e] : (e - E);
  atomicAdd(&deg[d], 1);
}

__global__ void k_scan_partial(const int* __restrict__ deg, int* __restrict__ partial, int n) {
  __shared__ int s[SCAN_T];
  int base = blockIdx.x * SCAN_ELEMS;
  int sum = 0;
  for (int i = threadIdx.x; i < SCAN_ELEMS; i += SCAN_T) {
    int idx = base + i;
    if (idx < n) sum += deg[idx];
  }
  s[threadIdx.x] = sum;
  __syncthreads();
  for (int off = SCAN_T / 2; off; off >>= 1) {
    if (threadIdx.x < off) s[threadIdx.x] += s[threadIdx.x + off];
    __syncthreads();
  }
  if (threadIdx.x == 0) partial[blockIdx.x] = s[0];
}

__global__ void k_scan_top(int* __restrict__ partial, int nb, int* __restrict__ total) {
  if (threadIdx.x == 0 && blockIdx.x == 0) {
    int run = 0;
    for (int i = 0; i < nb; i++) { int v = partial[i]; partial[i] = run; run += v; }
    *total = run;
  }
}

__global__ void k_scan_final(const int* __restrict__ deg, const int* __restrict__ partial,
                             int* __restrict__ rowptr, int n) {
  __shared__ int s[SCAN_T];
  int b = blockIdx.x, t = threadIdx.x;
  int base = b * SCAN_ELEMS + t * 8;
  int v[8]; int tot = 0;
  #pragma unroll
  for (int i = 0; i < 8; i++) { int idx = base + i; v[i] = (idx < n) ? deg[idx] : 0; tot += v[i]; }
  s[t] = tot;
  __syncthreads();
  for (int off = 1; off < SCAN_T; off <<= 1) {
    int add = (t >= off) ? s[t - off] : 0;
    __syncthreads();
    s[t] += add;
    __syncthreads();
  }
  int excl = (t ? s[t - 1] : 0) + partial[b];
  #pragma unroll
  for (int i = 0; i < 8; i++) { int idx = base + i; if (idx < n) rowptr[idx] = excl; excl += v[i]; }
}

__global__ void k_scatter(const int* __restrict__ ei, const int* __restrict__ rowptr,
                          int* __restrict__ fill, int* __restrict__ csr_src, int E, int EE) {
  int e = blockIdx.x * blockDim.x + threadIdx.x;
  if (e >= EE) return;
  int s, d;
  if (e < E) { s = ei[e]; d = ei[E + e]; } else { s = e - E; d = s; }
  int pos = rowptr[d] + atomicAdd(&fill[d], 1);
  csr_src[pos] = s;
}

// ---------------- GEMM h = x@W fused with alpha reductions ----------------
// Grid-stride persistent blocks. W in LDS (once per block). 32-row x tiles
// double-buffered in LDS, filled asynchronously via global_load_lds (no VGPR
// round-trip). Compute: 8 rows/wave, lane = out feature, wreg[16] k-block.

template <int FIN>
__device__ __forceinline__ void stage_tile(const float* __restrict__ x, float* xs,
                                           int tile, int wid, int lane) {
  const size_t base = (size_t)tile * (32 * FIN);
  #pragma unroll
  for (int i = 0; i < FIN / 32; i++) {
    int chunk = wid * (FIN / 32) + i;          // 256 floats (1024 B) per chunk
    async_copy16(x + base + chunk * 256 + lane * 4, xs + chunk * 256);
  }
}

template <int FIN>
__global__ __launch_bounds__(256) void k_gemm4(
    const float* __restrict__ x, const float* __restrict__ W,
    const float* __restrict__ avs, const float* __restrict__ avd,
    float* __restrict__ h, float* __restrict__ as_out, float* __restrict__ ad_out,
    int Nn, int ntiles) {
  __shared__ float Wl[FIN * 64];
  __shared__ float xs[2][32 * FIN];
  int t = threadIdx.x, lane = t & 63, wid = t >> 6;

  #pragma unroll
  for (int i = 0; i < FIN / 16; i++)
    ((float4*)Wl)[i * 256 + t] = ((const float4*)W)[i * 256 + t];
  float As = avs[lane], Ad = avd[lane];

  int tile = blockIdx.x;
  if (tile >= ntiles) return;
  stage_tile<FIN>(x, xs[0], tile, wid, lane);
  __syncthreads();                 // drains stage vmcnt + W lgkm + barrier
  int buf = 0;

  while (tile < ntiles) {
    int nxt = tile + gridDim.x;
    if (nxt < ntiles) stage_tile<FIN>(x, xs[buf ^ 1], nxt, wid, lane);

    float acc[8];
    #pragma unroll
    for (int r = 0; r < 8; r++) acc[r] = 0.f;
    const float* xw = &xs[buf][(wid * 8) * FIN];

    #pragma unroll 1
    for (int kb = 0; kb < FIN; kb += 16) {
      float wreg[16];
      #pragma unroll
      for (int k = 0; k < 16; k++) wreg[k] = Wl[(kb + k) * 64 + lane];
      #pragma unroll
      for (int r = 0; r < 8; r++) {
        const float4* xr = (const float4*)(xw + r * FIN + kb);
        float4 a0 = xr[0];
        float4 a1 = xr[1];
        float4 a2 = xr[2];
        float4 a3 = xr[3];
        acc[r] = fmaf(a0.x, wreg[0],  acc[r]);
        acc[r] = fmaf(a0.y, wreg[1],  acc[r]);
        acc[r] = fmaf(a0.z, wreg[2],  acc[r]);
        acc[r] = fmaf(a0.w, wreg[3],  acc[r]);
        acc[r] = fmaf(a1.x, wreg[4],  acc[r]);
        acc[r] = fmaf(a1.y, wreg[5],  acc[r]);
        acc[r] = fmaf(a1.z, wreg[6],  acc[r]);
        acc[r] = fmaf(a1.w, wreg[7],  acc[r]);
        acc[r] = fmaf(a2.x, wreg[8],  acc[r]);
        acc[r] = fmaf(a2.y, wreg[9],  acc[r]);
        acc[r] = fmaf(a2.z, wreg[10], acc[r]);
        acc[r] = fmaf(a2.w, wreg[11], acc[r]);
        acc[r] = fmaf(a3.x, wreg[12], acc[r]);
        acc[r] = fmaf(a3.y, wreg[13], acc[r]);
        acc[r] = fmaf(a3.z, wreg[14], acc[r]);
        acc[r] = fmaf(a3.w, wreg[15], acc[r]);
      }
    }

    int row0 = tile * 32 + wid * 8;
    #pragma unroll
    for (int r = 0; r < 8; r++) {
      int row = row0 + r;
      if (row < Nn) {
        h[(size_t)row * 64 + lane] = acc[r];
        float vs = acc[r] * As;
        float vd = acc[r] * Ad;
        wave_reduce_sum2(vs, vd);
        if (lane == 0) { as_out[row] = vs; ad_out[row] = vd; }
      }
    }

    __syncthreads();               // all reads of xs[buf] done; prefetch landed
    buf ^= 1;
    tile = nxt;
  }
}

// ---------------- per-dst-node softmax aggregation ----------------
// FINAL=0: out[n][:] = relu(agg + bias)
// FINAL=1: fout[n] = sigmoid(relu(agg + bias) . Wlin + blin)

template <int FINAL>
__global__ __launch_bounds__(256) void k_agg3(
    const int* __restrict__ rowptr, const int* __restrict__ csr_src,
    const float* __restrict__ h, const float* __restrict__ as_,
    const float* __restrict__ ad_, const float* __restrict__ bias,
    float* __restrict__ out, const float* __restrict__ Wlin,
    const float* __restrict__ blin, float* __restrict__ fout, int Nn) {
  int t = threadIdx.x, lane = t & 63, wid = t >> 6;
  int n = blockIdx.x * 4 + wid;
  if (n >= Nn) return;
  int r0 = rowptr[n], r1 = rowptr[n + 1];
  int deg = r1 - r0;
  float ad = ad_[n];
  float acc = 0.f;

  if (deg <= 64) {
    int src = (lane < deg) ? csr_src[r0 + lane] : 0;
    float e = (lane < deg) ? (as_[src] + ad) : -3.0e38f;
    e = (e >= 0.f) ? e : 0.2f * e;
    float m = wave_reduce_max(e);
    float p = (lane < deg) ? __expf(e - m) : 0.f;
    float inv = 1.f / (wave_reduce_sum(p) + 1e-16f);

    int jj = 0;
    for (; jj + 4 <= deg; jj += 4) {
      float p0 = __shfl(p, jj),     p1 = __shfl(p, jj + 1);
      float p2 = __shfl(p, jj + 2), p3 = __shfl(p, jj + 3);
      int s0 = __shfl(src, jj),     s1 = __shfl(src, jj + 1);
      int s2 = __shfl(src, jj + 2), s3 = __shfl(src, jj + 3);
      float v0 = h[(size_t)s0 * 64 + lane];
      float v1 = h[(size_t)s1 * 64 + lane];
      float v2 = h[(size_t)s2 * 64 + lane];
      float v3 = h[(size_t)s3 * 64 + lane];
      acc = fmaf(p0, v0, acc);
      acc = fmaf(p1, v1, acc);
      acc = fmaf(p2, v2, acc);
      acc = fmaf(p3, v3, acc);
    }
    for (; jj < deg; ++jj) {
      float pj = __shfl(p, jj);
      int sj = __shfl(src, jj);
      acc = fmaf(pj, h[(size_t)sj * 64 + lane], acc);
    }
    acc *= inv;
  } else {
    float m = -3.0e38f;
    for (int j = r0 + lane; j < r1; j += 64) {
      float e = as_[csr_src[j]] + ad;
      e = (e >= 0.f) ? e : 0.2f * e;
      m = fmaxf(m, e);
    }
    m = wave_reduce_max(m);
    float ssum = 0.f;
    for (int j = r0; j < r1; ++j) {
      int src = csr_src[j];
      float e = as_[src] + ad;
      e = (e >= 0.f) ? e : 0.2f * e;
      float p = __expf(e - m);
      ssum += p;
      acc = fmaf(p, h[(size_t)src * 64 + lane], acc);
    }
    acc /= (ssum + 1e-16f);
  }

  float o = fmaxf(acc + bias[lane], 0.f);
  if (FINAL) {
    float rv = wave_reduce_sum(o * Wlin[lane]);
    if (lane == 0) {
      float z = rv + blin[0];
      fout[n] = 1.f / (1.f + __expf(-z));
    }
  } else {
    out[(size_t)n * 64 + lane] = o;
  }
}

extern "C" void kernel_launch(void* const* d_in, const int* in_sizes, int n_in,
                              void* d_out, int out_size, void* d_ws, size_t ws_size,
                              hipStream_t stream) {
  const float* x   = (const float*)d_in[0];
  const int*   ei  = (const int*)d_in[1];
  const float* W1  = (const float*)d_in[2];
  const float* a1s = (const float*)d_in[3];
  const float* a1d = (const float*)d_in[4];
  const float* b1  = (const float*)d_in[5];
  const float* W2  = (const float*)d_in[6];
  const float* a2s = (const float*)d_in[7];
  const float* a2d = (const float*)d_in[8];
  const float* b2  = (const float*)d_in[9];
  const float* W3  = (const float*)d_in[10];
  const float* a3s = (const float*)d_in[11];
  const float* a3d = (const float*)d_in[12];
  const float* b3  = (const float*)d_in[13];
  const float* Wl  = (const float*)d_in[14];
  const float* bl  = (const float*)d_in[15];

  const int N  = in_sizes[0] / 128;
  const int E  = in_sizes[1] / 2;
  const int EE = E + N;

  char* p = (char*)d_ws;
  auto alloc = [&](size_t bytes) { char* r = p; p += (bytes + 255) & ~(size_t)255; return r; };
  int*   deg     = (int*)alloc((size_t)N * 4);
  int*   fill    = (int*)alloc((size_t)N * 4);
  int*   rowptr  = (int*)alloc((size_t)(N + 1) * 4);
  int*   partial = (int*)alloc(256 * 4);
  int*   csr_src = (int*)alloc((size_t)EE * 4);
  float* hbuf    = (float*)alloc((size_t)N * 64 * 4);
  float* obuf    = (float*)alloc((size_t)N * 64 * 4);
  float* as_     = (float*)alloc((size_t)N * 4);
  float* ad_     = (float*)alloc((size_t)N * 4);

  hipMemsetAsync(deg,  0, (size_t)N * 4, stream);
  hipMemsetAsync(fill, 0, (size_t)N * 4, stream);

  int eb = (EE + 255) / 256;
  k_count_deg<<<eb, 256, 0, stream>>>(ei, deg, E, EE);
  int nchunks = (N + SCAN_ELEMS - 1) / SCAN_ELEMS;
  k_scan_partial<<<nchunks, SCAN_T, 0, stream>>>(deg, partial, N);
  k_scan_top<<<1, 64, 0, stream>>>(partial, nchunks, rowptr + N);
  k_scan_final<<<nchunks, SCAN_T, 0, stream>>>(deg, partial, rowptr, N);
  k_scatter<<<eb, 256, 0, stream>>>(ei, rowptr, fill, csr_src, E, EE);

  int ntiles = (N + 31) / 32;
  int g1 = ntiles < 512 ? ntiles : 512;    // FIN=128: 64 KB LDS -> 2 blocks/CU
  int g2 = ntiles < 1280 ? ntiles : 1280;  // FIN=64:  32 KB LDS -> 5 blocks/CU
  int nb = (N + 3) / 4;

  // layer 1
  k_gemm4<128><<<g1, 256, 0, stream>>>(x, W1, a1s, a1d, hbuf, as_, ad_, N, ntiles);
  k_agg3<0><<<nb, 256, 0, stream>>>(rowptr, csr_src, hbuf, as_, ad_, b1, obuf,
                                    nullptr, nullptr, nullptr, N);
  // layer 2
  k_gemm4<64><<<g2, 256, 0, stream>>>(obuf, W2, a2s, a2d, hbuf, as_, ad_, N, ntiles);
  k_agg3<0><<<nb, 256, 0, stream>>>(rowptr, csr_src, hbuf, as_, ad_, b2, obuf,
                                    nullptr, nullptr, nullptr, N);
  // layer 3 (+ fused readout)
  k_gemm4<64><<<g2, 256, 0, stream>>>(obuf, W3, a3s, a3d, hbuf, as_, ad_, N, ntiles);
  k_agg3<1><<<nb, 256, 0, stream>>>(rowptr, csr_src, hbuf, as_, ad_, b3, nullptr,
                                    Wl, bl, (float*)d_out, N);
}

// Round 5
// 521.294 us; speedup vs baseline: 3.2754x; 1.0877x over previous
//
#include <hip/hip_runtime.h>
#include <hip/hip_bf16.h>
#include <math.h>

#define SCAN_T 256
#define SCAN_ELEMS 2048

__device__ __forceinline__ float wave_reduce_max(float v) {
  #pragma unroll
  for (int off = 32; off; off >>= 1) v = fmaxf(v, __shfl_xor(v, off));
  return v;
}
__device__ __forceinline__ float wave_reduce_sum(float v) {
  #pragma unroll
  for (int off = 32; off; off >>= 1) v += __shfl_xor(v, off);
  return v;
}
__device__ __forceinline__ void wave_reduce_sum2(float& a, float& b) {
  #pragma unroll
  for (int off = 32; off; off >>= 1) {
    a += __shfl_xor(a, off);
    b += __shfl_xor(b, off);
  }
}

// async global->LDS, 16 B per lane (global_load_lds_dwordx4)
__device__ __forceinline__ void async_copy16(const float* gsrc, float* ldst) {
  __builtin_amdgcn_global_load_lds(
      (const __attribute__((address_space(1))) void*)gsrc,
      (__attribute__((address_space(3))) void*)ldst, 16, 0, 0);
}

// ---------------- CSR build ----------------
// pass 1: deg count + per-edge slot (the atomic we must pay anyway)
__global__ void k_count_slot(const int* __restrict__ ei, int* __restrict__ deg,
                             int* __restrict__ slot, int E, int EE) {
  int e = blockIdx.x * blockDim.x + threadIdx.x;
  if (e >= EE) return;
  int d = (e < E) ? ei[E + e] : (e - E);
  slot[e] = atomicAdd(&deg[d], 1);
}

__global__ void k_scan_partial(const int* __restrict__ deg, int* __restrict__ partial, int n) {
  __shared__ int s[SCAN_T];
  int base = blockIdx.x * SCAN_ELEMS;
  int sum = 0;
  for (int i = threadIdx.x; i < SCAN_ELEMS; i += SCAN_T) {
    int idx = base + i;
    if (idx < n) sum += deg[idx];
  }
  s[threadIdx.x] = sum;
  __syncthreads();
  for (int off = SCAN_T / 2; off; off >>= 1) {
    if (threadIdx.x < off) s[threadIdx.x] += s[threadIdx.x + off];
    __syncthreads();
  }
  if (threadIdx.x == 0) partial[blockIdx.x] = s[0];
}

__global__ void k_scan_top(int* __restrict__ partial, int nb, int* __restrict__ total) {
  if (threadIdx.x == 0 && blockIdx.x == 0) {
    int run = 0;
    for (int i = 0; i < nb; i++) { int v = partial[i]; partial[i] = run; run += v; }
    *total = run;
  }
}

__global__ void k_scan_final(const int* __restrict__ deg, const int* __restrict__ partial,
                             int* __restrict__ rowptr, int n) {
  __shared__ int s[SCAN_T];
  int b = blockIdx.x, t = threadIdx.x;
  int base = b * SCAN_ELEMS + t * 8;
  int v[8]; int tot = 0;
  #pragma unroll
  for (int i = 0; i < 8; i++) { int idx = base + i; v[i] = (idx < n) ? deg[idx] : 0; tot += v[i]; }
  s[t] = tot;
  __syncthreads();
  for (int off = 1; off < SCAN_T; off <<= 1) {
    int add = (t >= off) ? s[t - off] : 0;
    __syncthreads();
    s[t] += add;
    __syncthreads();
  }
  int excl = (t ? s[t - 1] : 0) + partial[b];
  #pragma unroll
  for (int i = 0; i < 8; i++) { int idx = base + i; if (idx < n) rowptr[idx] = excl; excl += v[i]; }
}

// pass 2: atomic-free scatter
__global__ void k_scatter2(const int* __restrict__ ei, const int* __restrict__ rowptr,
                           const int* __restrict__ slot, int* __restrict__ csr_src,
                           int E, int EE) {
  int e = blockIdx.x * blockDim.x + threadIdx.x;
  if (e >= EE) return;
  int s, d;
  if (e < E) { s = ei[e]; d = ei[E + e]; } else { s = e - E; d = s; }
  int pos = rowptr[d] + slot[e];
  __builtin_nontemporal_store(s, &csr_src[pos]);
}

// ---------------- GEMM h = x@W fused with alpha reductions ----------------

template <int FIN>
__device__ __forceinline__ void stage_tile(const float* __restrict__ x, float* xs,
                                           int tile, int wid, int lane) {
  const size_t base = (size_t)tile * (32 * FIN);
  #pragma unroll
  for (int i = 0; i < FIN / 32; i++) {
    int chunk = wid * (FIN / 32) + i;          // 256 floats (1024 B) per chunk
    async_copy16(x + base + chunk * 256 + lane * 4, xs + chunk * 256);
  }
}

template <int FIN>
__global__ __launch_bounds__(256) void k_gemm4(
    const float* __restrict__ x, const float* __restrict__ W,
    const float* __restrict__ avs, const float* __restrict__ avd,
    float* __restrict__ h, float* __restrict__ as_out, float* __restrict__ ad_out,
    int Nn, int ntiles) {
  __shared__ float Wl[FIN * 64];
  __shared__ float xs[2][32 * FIN];
  int t = threadIdx.x, lane = t & 63, wid = t >> 6;

  #pragma unroll
  for (int i = 0; i < FIN / 16; i++)
    ((float4*)Wl)[i * 256 + t] = ((const float4*)W)[i * 256 + t];
  float As = avs[lane], Ad = avd[lane];

  int tile = blockIdx.x;
  if (tile >= ntiles) return;
  stage_tile<FIN>(x, xs[0], tile, wid, lane);
  __syncthreads();
  int buf = 0;

  while (tile < ntiles) {
    int nxt = tile + gridDim.x;
    if (nxt < ntiles) stage_tile<FIN>(x, xs[buf ^ 1], nxt, wid, lane);

    float acc[8];
    #pragma unroll
    for (int r = 0; r < 8; r++) acc[r] = 0.f;
    const float* xw = &xs[buf][(wid * 8) * FIN];

    #pragma unroll 1
    for (int kb = 0; kb < FIN; kb += 16) {
      float wreg[16];
      #pragma unroll
      for (int k = 0; k < 16; k++) wreg[k] = Wl[(kb + k) * 64 + lane];
      #pragma unroll
      for (int r = 0; r < 8; r++) {
        const float4* xr = (const float4*)(xw + r * FIN + kb);
        float4 a0 = xr[0];
        float4 a1 = xr[1];
        float4 a2 = xr[2];
        float4 a3 = xr[3];
        acc[r] = fmaf(a0.x, wreg[0],  acc[r]);
        acc[r] = fmaf(a0.y, wreg[1],  acc[r]);
        acc[r] = fmaf(a0.z, wreg[2],  acc[r]);
        acc[r] = fmaf(a0.w, wreg[3],  acc[r]);
        acc[r] = fmaf(a1.x, wreg[4],  acc[r]);
        acc[r] = fmaf(a1.y, wreg[5],  acc[r]);
        acc[r] = fmaf(a1.z, wreg[6],  acc[r]);
        acc[r] = fmaf(a1.w, wreg[7],  acc[r]);
        acc[r] = fmaf(a2.x, wreg[8],  acc[r]);
        acc[r] = fmaf(a2.y, wreg[9],  acc[r]);
        acc[r] = fmaf(a2.z, wreg[10], acc[r]);
        acc[r] = fmaf(a2.w, wreg[11], acc[r]);
        acc[r] = fmaf(a3.x, wreg[12], acc[r]);
        acc[r] = fmaf(a3.y, wreg[13], acc[r]);
        acc[r] = fmaf(a3.z, wreg[14], acc[r]);
        acc[r] = fmaf(a3.w, wreg[15], acc[r]);
      }
    }

    int row0 = tile * 32 + wid * 8;
    #pragma unroll
    for (int r = 0; r < 8; r++) {
      int row = row0 + r;
      if (row < Nn) {
        h[(size_t)row * 64 + lane] = acc[r];
        float vs = acc[r] * As;
        float vd = acc[r] * Ad;
        wave_reduce_sum2(vs, vd);
        if (lane == 0) { as_out[row] = vs; ad_out[row] = vd; }
      }
    }

    __syncthreads();
    buf ^= 1;
    tile = nxt;
  }
}

// ---------------- per-dst-node softmax aggregation ----------------

template <int FINAL>
__global__ __launch_bounds__(256) void k_agg3(
    const int* __restrict__ rowptr, const int* __restrict__ csr_src,
    const float* __restrict__ h, const float* __restrict__ as_,
    const float* __restrict__ ad_, const float* __restrict__ bias,
    float* __restrict__ out, const float* __restrict__ Wlin,
    const float* __restrict__ blin, float* __restrict__ fout, int Nn) {
  int t = threadIdx.x, lane = t & 63, wid = t >> 6;
  int n = blockIdx.x * 4 + wid;
  if (n >= Nn) return;
  int r0 = rowptr[n], r1 = rowptr[n + 1];
  int deg = r1 - r0;
  float ad = ad_[n];
  float acc = 0.f;

  if (deg <= 64) {
    int src = (lane < deg) ? csr_src[r0 + lane] : 0;
    float e = (lane < deg) ? (as_[src] + ad) : -3.0e38f;
    e = (e >= 0.f) ? e : 0.2f * e;
    float m = wave_reduce_max(e);
    float p = (lane < deg) ? __expf(e - m) : 0.f;
    float inv = 1.f / (wave_reduce_sum(p) + 1e-16f);

    int jj = 0;
    for (; jj + 4 <= deg; jj += 4) {
      float p0 = __shfl(p, jj),     p1 = __shfl(p, jj + 1);
      float p2 = __shfl(p, jj + 2), p3 = __shfl(p, jj + 3);
      int s0 = __shfl(src, jj),     s1 = __shfl(src, jj + 1);
      int s2 = __shfl(src, jj + 2), s3 = __shfl(src, jj + 3);
      float v0 = h[(size_t)s0 * 64 + lane];
      float v1 = h[(size_t)s1 * 64 + lane];
      float v2 = h[(size_t)s2 * 64 + lane];
      float v3 = h[(size_t)s3 * 64 + lane];
      acc = fmaf(p0, v0, acc);
      acc = fmaf(p1, v1, acc);
      acc = fmaf(p2, v2, acc);
      acc = fmaf(p3, v3, acc);
    }
    for (; jj < deg; ++jj) {
      float pj = __shfl(p, jj);
      int sj = __shfl(src, jj);
      acc = fmaf(pj, h[(size_t)sj * 64 + lane], acc);
    }
    acc *= inv;
  } else {
    float m = -3.0e38f;
    for (int j = r0 + lane; j < r1; j += 64) {
      float e = as_[csr_src[j]] + ad;
      e = (e >= 0.f) ? e : 0.2f * e;
      m = fmaxf(m, e);
    }
    m = wave_reduce_max(m);
    float ssum = 0.f;
    for (int j = r0; j < r1; ++j) {
      int src = csr_src[j];
      float e = as_[src] + ad;
      e = (e >= 0.f) ? e : 0.2f * e;
      float p = __expf(e - m);
      ssum += p;
      acc = fmaf(p, h[(size_t)src * 64 + lane], acc);
    }
    acc /= (ssum + 1e-16f);
  }

  float o = fmaxf(acc + bias[lane], 0.f);
  if (FINAL) {
    float rv = wave_reduce_sum(o * Wlin[lane]);
    if (lane == 0) {
      float z = rv + blin[0];
      fout[n] = 1.f / (1.f + __expf(-z));
    }
  } else {
    out[(size_t)n * 64 + lane] = o;
  }
}

extern "C" void kernel_launch(void* const* d_in, const int* in_sizes, int n_in,
                              void* d_out, int out_size, void* d_ws, size_t ws_size,
                              hipStream_t stream) {
  const float* x   = (const float*)d_in[0];
  const int*   ei  = (const int*)d_in[1];
  const float* W1  = (const float*)d_in[2];
  const float* a1s = (const float*)d_in[3];
  const float* a1d = (const float*)d_in[4];
  const float* b1  = (const float*)d_in[5];
  const float* W2  = (const float*)d_in[6];
  const float* a2s = (const float*)d_in[7];
  const float* a2d = (const float*)d_in[8];
  const float* b2  = (const float*)d_in[9];
  const float* W3  = (const float*)d_in[10];
  const float* a3s = (const float*)d_in[11];
  const float* a3d = (const float*)d_in[12];
  const float* b3  = (const float*)d_in[13];
  const float* Wl  = (const float*)d_in[14];
  const float* bl  = (const float*)d_in[15];

  const int N  = in_sizes[0] / 128;
  const int E  = in_sizes[1] / 2;
  const int EE = E + N;

  char* p = (char*)d_ws;
  auto alloc = [&](size_t bytes) { char* r = p; p += (bytes + 255) & ~(size_t)255; return r; };
  int*   deg     = (int*)alloc((size_t)N * 4);
  int*   rowptr  = (int*)alloc((size_t)(N + 1) * 4);
  int*   partial = (int*)alloc(256 * 4);
  int*   csr_src = (int*)alloc((size_t)EE * 4);
  float* hbuf    = (float*)alloc((size_t)N * 64 * 4);
  float* obuf    = (float*)alloc((size_t)N * 64 * 4);
  float* as_     = (float*)alloc((size_t)N * 4);
  float* ad_     = (float*)alloc((size_t)N * 4);

  // slot[] (EE ints = 6.8 MB) aliases hbuf: dead before k_gemm4 writes hbuf
  int* slot = (int*)hbuf;

  hipMemsetAsync(deg, 0, (size_t)N * 4, stream);

  int eb = (EE + 255) / 256;
  k_count_slot<<<eb, 256, 0, stream>>>(ei, deg, slot, E, EE);
  int nchunks = (N + SCAN_ELEMS - 1) / SCAN_ELEMS;
  k_scan_partial<<<nchunks, SCAN_T, 0, stream>>>(deg, partial, N);
  k_scan_top<<<1, 64, 0, stream>>>(partial, nchunks, rowptr + N);
  k_scan_final<<<nchunks, SCAN_T, 0, stream>>>(deg, partial, rowptr, N);
  k_scatter2<<<eb, 256, 0, stream>>>(ei, rowptr, slot, csr_src, E, EE);

  int ntiles = (N + 31) / 32;
  int g1 = ntiles < 512 ? ntiles : 512;    // FIN=128: 64 KB LDS -> 2 blocks/CU
  int g2 = ntiles < 1280 ? ntiles : 1280;  // FIN=64:  32 KB LDS -> 5 blocks/CU
  int nb = (N + 3) / 4;

  // layer 1
  k_gemm4<128><<<g1, 256, 0, stream>>>(x, W1, a1s, a1d, hbuf, as_, ad_, N, ntiles);
  k_agg3<0><<<nb, 256, 0, stream>>>(rowptr, csr_src, hbuf, as_, ad_, b1, obuf,
                                    nullptr, nullptr, nullptr, N);
  // layer 2
  k_gemm4<64><<<g2, 256, 0, stream>>>(obuf, W2, a2s, a2d, hbuf, as_, ad_, N, ntiles);
  k_agg3<0><<<nb, 256, 0, stream>>>(rowptr, csr_src, hbuf, as_, ad_, b2, obuf,
                                    nullptr, nullptr, nullptr, N);
  // layer 3 (+ fused readout)
  k_gemm4<64><<<g2, 256, 0, stream>>>(obuf, W3, a3s, a3d, hbuf, as_, ad_, N, ntiles);
  k_agg3<1><<<nb, 256, 0, stream>>>(rowptr, csr_src, hbuf, as_, ad_, b3, nullptr,
                                    Wl, bl, (float*)d_out, N);
}

// Round 6
// 426.029 us; speedup vs baseline: 4.0078x; 1.2236x over previous
//
#include <hip/hip_runtime.h>
#include <hip/hip_bf16.h>
#include <math.h>

#define SCAN_T 256
#define SCAN_ELEMS 2048

__device__ __forceinline__ float wave_reduce_max(float v) {
  #pragma unroll
  for (int off = 32; off; off >>= 1) v = fmaxf(v, __shfl_xor(v, off));
  return v;
}
__device__ __forceinline__ float wave_reduce_sum(float v) {
  #pragma unroll
  for (int off = 32; off; off >>= 1) v += __shfl_xor(v, off);
  return v;
}

// round-to-nearest-even f32 -> bf16 (as ushort)
__device__ __forceinline__ unsigned f2bf(float f) {
  unsigned u = __float_as_uint(f);
  return (u + 0x7fffu + ((u >> 16) & 1u)) >> 16;
}
__device__ __forceinline__ float bf2f(unsigned short us) {
  return __uint_as_float(((unsigned)us) << 16);
}

// async global->LDS, 16 B per lane (global_load_lds_dwordx4)
__device__ __forceinline__ void async_copy16(const float* gsrc, float* ldst) {
  __builtin_amdgcn_global_load_lds(
      (const __attribute__((address_space(1))) void*)gsrc,
      (__attribute__((address_space(3))) void*)ldst, 16, 0, 0);
}

// ---------------- CSR build ----------------

__global__ void k_count_slot(const int* __restrict__ ei, int* __restrict__ deg,
                             unsigned short* __restrict__ slot, int E, int EE) {
  int e = blockIdx.x * blockDim.x + threadIdx.x;
  if (e >= EE) return;
  int d = (e < E) ? ei[E + e] : (e - E);
  slot[e] = (unsigned short)atomicAdd(&deg[d], 1);
}

__global__ void k_scan_partial(const int* __restrict__ deg, int* __restrict__ partial, int n) {
  __shared__ int s[SCAN_T];
  int base = blockIdx.x * SCAN_ELEMS;
  int sum = 0;
  for (int i = threadIdx.x; i < SCAN_ELEMS; i += SCAN_T) {
    int idx = base + i;
    if (idx < n) sum += deg[idx];
  }
  s[threadIdx.x] = sum;
  __syncthreads();
  for (int off = SCAN_T / 2; off; off >>= 1) {
    if (threadIdx.x < off) s[threadIdx.x] += s[threadIdx.x + off];
    __syncthreads();
  }
  if (threadIdx.x == 0) partial[blockIdx.x] = s[0];
}

__global__ void k_scan_top(int* __restrict__ partial, int nb, int* __restrict__ total) {
  if (threadIdx.x == 0 && blockIdx.x == 0) {
    int run = 0;
    for (int i = 0; i < nb; i++) { int v = partial[i]; partial[i] = run; run += v; }
    *total = run;
  }
}

__global__ void k_scan_final(const int* __restrict__ deg, const int* __restrict__ partial,
                             int* __restrict__ rowptr, int n) {
  __shared__ int s[SCAN_T];
  int b = blockIdx.x, t = threadIdx.x;
  int base = b * SCAN_ELEMS + t * 8;
  int v[8]; int tot = 0;
  #pragma unroll
  for (int i = 0; i < 8; i++) { int idx = base + i; v[i] = (idx < n) ? deg[idx] : 0; tot += v[i]; }
  s[t] = tot;
  __syncthreads();
  for (int off = 1; off < SCAN_T; off <<= 1) {
    int add = (t >= off) ? s[t - off] : 0;
    __syncthreads();
    s[t] += add;
    __syncthreads();
  }
  int excl = (t ? s[t - 1] : 0) + partial[b];
  #pragma unroll
  for (int i = 0; i < 8; i++) { int idx = base + i; if (idx < n) rowptr[idx] = excl; excl += v[i]; }
}

__global__ void k_scatter2(const int* __restrict__ ei, const int* __restrict__ rowptr,
                           const unsigned short* __restrict__ slot, int* __restrict__ csr_src,
                           int E, int EE) {
  int e = blockIdx.x * blockDim.x + threadIdx.x;
  if (e >= EE) return;
  int s, d;
  if (e < E) { s = ei[e]; d = ei[E + e]; } else { s = e - E; d = s; }
  int pos = rowptr[d] + (int)slot[e];
  __builtin_nontemporal_store(s, &csr_src[pos]);
}

// ---------------- GEMM h = x@W fused with alpha reductions ----------------
// 32-row tiles, double-buffered via global_load_lds. 2-features-per-lane:
// lane = (rh = lane>>5) row-half x (fl = lane&31) feature-pair. Each x LDS
// broadcast feeds 8 FMAs/lane (halves LDS-pipe pressure vs lane=feature).
// h is written as packed bf16 (halves aggregation gather traffic).

template <int FIN>
__device__ __forceinline__ void stage_tile(const float* __restrict__ x, float* xs,
                                           int tile, int wid, int lane) {
  const size_t base = (size_t)tile * (32 * FIN);
  #pragma unroll
  for (int i = 0; i < FIN / 32; i++) {
    int chunk = wid * (FIN / 32) + i;          // 256 floats (1024 B) per chunk
    async_copy16(x + base + chunk * 256 + lane * 4, xs + chunk * 256);
  }
}

#define FMA2(av, wr) \
  acc0[r] = fmaf(av, wreg[wr].x, acc0[r]); \
  acc1[r] = fmaf(av, wreg[wr].y, acc1[r]);

template <int FIN>
__global__ __launch_bounds__(256) void k_gemm5(
    const float* __restrict__ x, const float* __restrict__ W,
    const float* __restrict__ avs, const float* __restrict__ avd,
    unsigned* __restrict__ h, float* __restrict__ as_out, float* __restrict__ ad_out,
    int Nn, int ntiles) {
  __shared__ float Wl[FIN * 64];
  __shared__ float xs[2][32 * FIN];
  int t = threadIdx.x, lane = t & 63, wid = t >> 6;
  int fl = lane & 31, rh = lane >> 5;

  #pragma unroll
  for (int i = 0; i < FIN / 16; i++)
    ((float4*)Wl)[i * 256 + t] = ((const float4*)W)[i * 256 + t];
  float2 As2 = *(const float2*)&avs[2 * fl];
  float2 Ad2 = *(const float2*)&avd[2 * fl];

  int tile = blockIdx.x;
  if (tile >= ntiles) return;
  stage_tile<FIN>(x, xs[0], tile, wid, lane);
  __syncthreads();
  int buf = 0;

  while (tile < ntiles) {
    int nxt = tile + gridDim.x;
    if (nxt < ntiles) stage_tile<FIN>(x, xs[buf ^ 1], nxt, wid, lane);

    float acc0[4], acc1[4];
    #pragma unroll
    for (int r = 0; r < 4; r++) { acc0[r] = 0.f; acc1[r] = 0.f; }
    const float* xw = &xs[buf][(wid * 8 + rh * 4) * FIN];
    const float2* wcol = (const float2*)&Wl[2 * fl];   // stride 32 float2 per k

    #pragma unroll 1
    for (int kb = 0; kb < FIN; kb += 16) {
      float2 wreg[16];
      #pragma unroll
      for (int k = 0; k < 16; k++) wreg[k] = wcol[(kb + k) * 32];
      #pragma unroll
      for (int r = 0; r < 4; r++) {
        const float4* xr = (const float4*)(xw + r * FIN + kb);
        float4 a0 = xr[0], a1 = xr[1], a2 = xr[2], a3 = xr[3];
        FMA2(a0.x, 0)  FMA2(a0.y, 1)  FMA2(a0.z, 2)  FMA2(a0.w, 3)
        FMA2(a1.x, 4)  FMA2(a1.y, 5)  FMA2(a1.z, 6)  FMA2(a1.w, 7)
        FMA2(a2.x, 8)  FMA2(a2.y, 9)  FMA2(a2.z, 10) FMA2(a2.w, 11)
        FMA2(a3.x, 12) FMA2(a3.y, 13) FMA2(a3.z, 14) FMA2(a3.w, 15)
      }
    }

    int row0 = tile * 32 + wid * 8 + rh * 4;
    #pragma unroll
    for (int r = 0; r < 4; r++) {
      int row = row0 + r;
      bool ok = row < Nn;
      if (ok) {
        unsigned pk = (f2bf(acc1[r]) << 16) | f2bf(acc0[r]);
        h[(size_t)row * 32 + fl] = pk;
      }
      float vs = acc0[r] * As2.x + acc1[r] * As2.y;
      float vd = acc0[r] * Ad2.x + acc1[r] * Ad2.y;
      #pragma unroll
      for (int off = 16; off; off >>= 1) {   // reduce within each 32-lane half
        vs += __shfl_xor(vs, off);
        vd += __shfl_xor(vd, off);
      }
      if (ok && fl == 0) { as_out[row] = vs; ad_out[row] = vd; }
    }

    __syncthreads();
    buf ^= 1;
    tile = nxt;
  }
}

// ---------------- per-dst-node softmax aggregation (bf16 h gathers) -------

template <int FINAL>
__global__ __launch_bounds__(256) void k_agg4(
    const int* __restrict__ rowptr, const int* __restrict__ csr_src,
    const unsigned short* __restrict__ hb, const float* __restrict__ as_,
    const float* __restrict__ ad_, const float* __restrict__ bias,
    float* __restrict__ out, const float* __restrict__ Wlin,
    const float* __restrict__ blin, float* __restrict__ fout, int Nn) {
  int t = threadIdx.x, lane = t & 63, wid = t >> 6;
  int n = blockIdx.x * 4 + wid;
  if (n >= Nn) return;
  int r0 = rowptr[n], r1 = rowptr[n + 1];
  int deg = r1 - r0;
  float ad = ad_[n];
  float acc = 0.f;

  if (deg <= 64) {
    int src = (lane < deg) ? csr_src[r0 + lane] : 0;
    float e = (lane < deg) ? (as_[src] + ad) : -3.0e38f;
    e = (e >= 0.f) ? e : 0.2f * e;
    float m = wave_reduce_max(e);
    float p = (lane < deg) ? __expf(e - m) : 0.f;
    float inv = 1.f / (wave_reduce_sum(p) + 1e-16f);

    int jj = 0;
    for (; jj + 4 <= deg; jj += 4) {
      float p0 = __shfl(p, jj),     p1 = __shfl(p, jj + 1);
      float p2 = __shfl(p, jj + 2), p3 = __shfl(p, jj + 3);
      int s0 = __shfl(src, jj),     s1 = __shfl(src, jj + 1);
      int s2 = __shfl(src, jj + 2), s3 = __shfl(src, jj + 3);
      float v0 = bf2f(hb[(size_t)s0 * 64 + lane]);
      float v1 = bf2f(hb[(size_t)s1 * 64 + lane]);
      float v2 = bf2f(hb[(size_t)s2 * 64 + lane]);
      float v3 = bf2f(hb[(size_t)s3 * 64 + lane]);
      acc = fmaf(p0, v0, acc);
      acc = fmaf(p1, v1, acc);
      acc = fmaf(p2, v2, acc);
      acc = fmaf(p3, v3, acc);
    }
    for (; jj < deg; ++jj) {
      float pj = __shfl(p, jj);
      int sj = __shfl(src, jj);
      acc = fmaf(pj, bf2f(hb[(size_t)sj * 64 + lane]), acc);
    }
    acc *= inv;
  } else {
    float m = -3.0e38f;
    for (int j = r0 + lane; j < r1; j += 64) {
      float e = as_[csr_src[j]] + ad;
      e = (e >= 0.f) ? e : 0.2f * e;
      m = fmaxf(m, e);
    }
    m = wave_reduce_max(m);
    float ssum = 0.f;
    for (int j = r0; j < r1; ++j) {
      int src = csr_src[j];
      float e = as_[src] + ad;
      e = (e >= 0.f) ? e : 0.2f * e;
      float p = __expf(e - m);
      ssum += p;
      acc = fmaf(p, bf2f(hb[(size_t)src * 64 + lane]), acc);
    }
    acc /= (ssum + 1e-16f);
  }

  float o = fmaxf(acc + bias[lane], 0.f);
  if (FINAL) {
    float rv = wave_reduce_sum(o * Wlin[lane]);
    if (lane == 0) {
      float z = rv + blin[0];
      fout[n] = 1.f / (1.f + __expf(-z));
    }
  } else {
    out[(size_t)n * 64 + lane] = o;
  }
}

extern "C" void kernel_launch(void* const* d_in, const int* in_sizes, int n_in,
                              void* d_out, int out_size, void* d_ws, size_t ws_size,
                              hipStream_t stream) {
  const float* x   = (const float*)d_in[0];
  const int*   ei  = (const int*)d_in[1];
  const float* W1  = (const float*)d_in[2];
  const float* a1s = (const float*)d_in[3];
  const float* a1d = (const float*)d_in[4];
  const float* b1  = (const float*)d_in[5];
  const float* W2  = (const float*)d_in[6];
  const float* a2s = (const float*)d_in[7];
  const float* a2d = (const float*)d_in[8];
  const float* b2  = (const float*)d_in[9];
  const float* W3  = (const float*)d_in[10];
  const float* a3s = (const float*)d_in[11];
  const float* a3d = (const float*)d_in[12];
  const float* b3  = (const float*)d_in[13];
  const float* Wl  = (const float*)d_in[14];
  const float* bl  = (const float*)d_in[15];

  const int N  = in_sizes[0] / 128;
  const int E  = in_sizes[1] / 2;
  const int EE = E + N;

  char* p = (char*)d_ws;
  auto alloc = [&](size_t bytes) { char* r = p; p += (bytes + 255) & ~(size_t)255; return r; };
  int*      deg     = (int*)alloc((size_t)N * 4);
  int*      rowptr  = (int*)alloc((size_t)(N + 1) * 4);
  int*      partial = (int*)alloc(256 * 4);
  int*      csr_src = (int*)alloc((size_t)EE * 4);
  unsigned* hbuf    = (unsigned*)alloc((size_t)N * 64 * 2);   // bf16 packed x2
  float*    obuf    = (float*)alloc((size_t)N * 64 * 4);
  float*    as_     = (float*)alloc((size_t)N * 4);
  float*    ad_     = (float*)alloc((size_t)N * 4);

  // slot[] (EE ushorts = 3.4 MB) aliases hbuf (12.8 MB): dead before gemm writes h
  unsigned short* slot = (unsigned short*)hbuf;

  hipMemsetAsync(deg, 0, (size_t)N * 4, stream);

  int eb = (EE + 255) / 256;
  k_count_slot<<<eb, 256, 0, stream>>>(ei, deg, slot, E, EE);
  int nchunks = (N + SCAN_ELEMS - 1) / SCAN_ELEMS;
  k_scan_partial<<<nchunks, SCAN_T, 0, stream>>>(deg, partial, N);
  k_scan_top<<<1, 64, 0, stream>>>(partial, nchunks, rowptr + N);
  k_scan_final<<<nchunks, SCAN_T, 0, stream>>>(deg, partial, rowptr, N);
  k_scatter2<<<eb, 256, 0, stream>>>(ei, rowptr, slot, csr_src, E, EE);

  int ntiles = (N + 31) / 32;
  int g1 = ntiles < 512 ? ntiles : 512;    // FIN=128: 64 KB LDS -> 2 blocks/CU
  int g2 = ntiles < 1024 ? ntiles : 1024;  // FIN=64:  32 KB LDS
  int nb = (N + 3) / 4;

  const unsigned short* hb = (const unsigned short*)hbuf;

  // layer 1
  k_gemm5<128><<<g1, 256, 0, stream>>>(x, W1, a1s, a1d, hbuf, as_, ad_, N, ntiles);
  k_agg4<0><<<nb, 256, 0, stream>>>(rowptr, csr_src, hb, as_, ad_, b1, obuf,
                                    nullptr, nullptr, nullptr, N);
  // layer 2
  k_gemm5<64><<<g2, 256, 0, stream>>>(obuf, W2, a2s, a2d, hbuf, as_, ad_, N, ntiles);
  k_agg4<0><<<nb, 256, 0, stream>>>(rowptr, csr_src, hb, as_, ad_, b2, obuf,
                                    nullptr, nullptr, nullptr, N);
  // layer 3 (+ fused readout)
  k_gemm5<64><<<g2, 256, 0, stream>>>(obuf, W3, a3s, a3d, hbuf, as_, ad_, N, ntiles);
  k_agg4<1><<<nb, 256, 0, stream>>>(rowptr, csr_src, hb, as_, ad_, b3, nullptr,
                                    Wl, bl, (float*)d_out, N);
}

// Round 7
// 407.817 us; speedup vs baseline: 4.1868x; 1.0447x over previous
//
#include <hip/hip_runtime.h>
#include <hip/hip_bf16.h>
#include <math.h>

#define SCAN_T 256
#define SCAN_ELEMS 2048

__device__ __forceinline__ float wave_reduce_max(float v) {
  #pragma unroll
  for (int off = 32; off; off >>= 1) v = fmaxf(v, __shfl_xor(v, off));
  return v;
}
__device__ __forceinline__ float wave_reduce_sum(float v) {
  #pragma unroll
  for (int off = 32; off; off >>= 1) v += __shfl_xor(v, off);
  return v;
}

// round-to-nearest-even f32 -> bf16 (as ushort)
__device__ __forceinline__ unsigned f2bf(float f) {
  unsigned u = __float_as_uint(f);
  return (u + 0x7fffu + ((u >> 16) & 1u)) >> 16;
}

// async global->LDS, 16 B per lane (global_load_lds_dwordx4)
__device__ __forceinline__ void async_copy16(const float* gsrc, float* ldst) {
  __builtin_amdgcn_global_load_lds(
      (const __attribute__((address_space(1))) void*)gsrc,
      (__attribute__((address_space(3))) void*)ldst, 16, 0, 0);
}

// ---------------- CSR build ----------------

__global__ void k_count_slot(const int* __restrict__ ei, int* __restrict__ deg,
                             unsigned short* __restrict__ slot, int E, int EE) {
  int e = blockIdx.x * blockDim.x + threadIdx.x;
  if (e >= EE) return;
  int d = (e < E) ? ei[E + e] : (e - E);
  slot[e] = (unsigned short)atomicAdd(&deg[d], 1);
}

__global__ void k_scan_partial(const int* __restrict__ deg, int* __restrict__ partial, int n) {
  __shared__ int s[SCAN_T];
  int base = blockIdx.x * SCAN_ELEMS;
  int sum = 0;
  for (int i = threadIdx.x; i < SCAN_ELEMS; i += SCAN_T) {
    int idx = base + i;
    if (idx < n) sum += deg[idx];
  }
  s[threadIdx.x] = sum;
  __syncthreads();
  for (int off = SCAN_T / 2; off; off >>= 1) {
    if (threadIdx.x < off) s[threadIdx.x] += s[threadIdx.x + off];
    __syncthreads();
  }
  if (threadIdx.x == 0) partial[blockIdx.x] = s[0];
}

__global__ void k_scan_top(int* __restrict__ partial, int nb, int* __restrict__ total) {
  if (threadIdx.x == 0 && blockIdx.x == 0) {
    int run = 0;
    for (int i = 0; i < nb; i++) { int v = partial[i]; partial[i] = run; run += v; }
    *total = run;
  }
}

__global__ void k_scan_final(const int* __restrict__ deg, const int* __restrict__ partial,
                             int* __restrict__ rowptr, int n) {
  __shared__ int s[SCAN_T];
  int b = blockIdx.x, t = threadIdx.x;
  int base = b * SCAN_ELEMS + t * 8;
  int v[8]; int tot = 0;
  #pragma unroll
  for (int i = 0; i < 8; i++) { int idx = base + i; v[i] = (idx < n) ? deg[idx] : 0; tot += v[i]; }
  s[t] = tot;
  __syncthreads();
  for (int off = 1; off < SCAN_T; off <<= 1) {
    int add = (t >= off) ? s[t - off] : 0;
    __syncthreads();
    s[t] += add;
    __syncthreads();
  }
  int excl = (t ? s[t - 1] : 0) + partial[b];
  #pragma unroll
  for (int i = 0; i < 8; i++) { int idx = base + i; if (idx < n) rowptr[idx] = excl; excl += v[i]; }
}

__global__ void k_scatter2(const int* __restrict__ ei, const int* __restrict__ rowptr,
                           const unsigned short* __restrict__ slot, int* __restrict__ csr_src,
                           int E, int EE) {
  int e = blockIdx.x * blockDim.x + threadIdx.x;
  if (e >= EE) return;
  int s, d;
  if (e < E) { s = ei[e]; d = ei[E + e]; } else { s = e - E; d = s; }
  int pos = rowptr[d] + (int)slot[e];
  __builtin_nontemporal_store(s, &csr_src[pos]);
}

// ---------------- GEMM h = x@W fused with alpha reductions ----------------

template <int FIN>
__device__ __forceinline__ void stage_tile(const float* __restrict__ x, float* xs,
                                           int tile, int wid, int lane) {
  const size_t base = (size_t)tile * (32 * FIN);
  #pragma unroll
  for (int i = 0; i < FIN / 32; i++) {
    int chunk = wid * (FIN / 32) + i;          // 256 floats (1024 B) per chunk
    async_copy16(x + base + chunk * 256 + lane * 4, xs + chunk * 256);
  }
}

#define FMA2(av, wr) \
  acc0[r] = fmaf(av, wreg[wr].x, acc0[r]); \
  acc1[r] = fmaf(av, wreg[wr].y, acc1[r]);

template <int FIN>
__global__ __launch_bounds__(256) void k_gemm5(
    const float* __restrict__ x, const float* __restrict__ W,
    const float* __restrict__ avs, const float* __restrict__ avd,
    unsigned* __restrict__ h, float* __restrict__ as_out, float* __restrict__ ad_out,
    int Nn, int ntiles) {
  __shared__ float Wl[FIN * 64];
  __shared__ float xs[2][32 * FIN];
  int t = threadIdx.x, lane = t & 63, wid = t >> 6;
  int fl = lane & 31, rh = lane >> 5;

  #pragma unroll
  for (int i = 0; i < FIN / 16; i++)
    ((float4*)Wl)[i * 256 + t] = ((const float4*)W)[i * 256 + t];
  float2 As2 = *(const float2*)&avs[2 * fl];
  float2 Ad2 = *(const float2*)&avd[2 * fl];

  int tile = blockIdx.x;
  if (tile >= ntiles) return;
  stage_tile<FIN>(x, xs[0], tile, wid, lane);
  __syncthreads();
  int buf = 0;

  while (tile < ntiles) {
    int nxt = tile + gridDim.x;
    if (nxt < ntiles) stage_tile<FIN>(x, xs[buf ^ 1], nxt, wid, lane);

    float acc0[4], acc1[4];
    #pragma unroll
    for (int r = 0; r < 4; r++) { acc0[r] = 0.f; acc1[r] = 0.f; }
    const float* xw = &xs[buf][(wid * 8 + rh * 4) * FIN];
    const float2* wcol = (const float2*)&Wl[2 * fl];   // stride 32 float2 per k

    #pragma unroll 1
    for (int kb = 0; kb < FIN; kb += 16) {
      float2 wreg[16];
      #pragma unroll
      for (int k = 0; k < 16; k++) wreg[k] = wcol[(kb + k) * 32];
      #pragma unroll
      for (int r = 0; r < 4; r++) {
        const float4* xr = (const float4*)(xw + r * FIN + kb);
        float4 a0 = xr[0], a1 = xr[1], a2 = xr[2], a3 = xr[3];
        FMA2(a0.x, 0)  FMA2(a0.y, 1)  FMA2(a0.z, 2)  FMA2(a0.w, 3)
        FMA2(a1.x, 4)  FMA2(a1.y, 5)  FMA2(a1.z, 6)  FMA2(a1.w, 7)
        FMA2(a2.x, 8)  FMA2(a2.y, 9)  FMA2(a2.z, 10) FMA2(a2.w, 11)
        FMA2(a3.x, 12) FMA2(a3.y, 13) FMA2(a3.z, 14) FMA2(a3.w, 15)
      }
    }

    int row0 = tile * 32 + wid * 8 + rh * 4;
    #pragma unroll
    for (int r = 0; r < 4; r++) {
      int row = row0 + r;
      bool ok = row < Nn;
      if (ok) {
        unsigned pk = (f2bf(acc1[r]) << 16) | f2bf(acc0[r]);
        h[(size_t)row * 32 + fl] = pk;
      }
      float vs = acc0[r] * As2.x + acc1[r] * As2.y;
      float vd = acc0[r] * Ad2.x + acc1[r] * Ad2.y;
      #pragma unroll
      for (int off = 16; off; off >>= 1) {   // reduce within each 32-lane half
        vs += __shfl_xor(vs, off);
        vd += __shfl_xor(vd, off);
      }
      if (ok && fl == 0) { as_out[row] = vs; ad_out[row] = vd; }
    }

    __syncthreads();
    buf ^= 1;
    tile = nxt;
  }
}

// ---------------- per-dst-node softmax aggregation ----------------
// 2 edges per iteration: rh-half = edge parity, fl = feature pair.
// {p,src} staged in per-wave LDS; one ds_read_b64 broadcasts both per 2 edges.

template <int FINAL>
__global__ __launch_bounds__(256) void k_agg5(
    const int* __restrict__ rowptr, const int* __restrict__ csr_src,
    const unsigned* __restrict__ hp, const float* __restrict__ as_,
    const float* __restrict__ ad_, const float* __restrict__ bias,
    float* __restrict__ out, const float* __restrict__ Wlin,
    const float* __restrict__ blin, float* __restrict__ fout, int Nn) {
  __shared__ float2 psbuf[4][64];
  int t = threadIdx.x, lane = t & 63, wid = t >> 6;
  int fl = lane & 31, rh = lane >> 5;
  int n = blockIdx.x * 4 + wid;
  if (n >= Nn) return;
  int r0 = rowptr[n], r1 = rowptr[n + 1];
  int deg = r1 - r0;
  float ad = ad_[n];
  float acc0 = 0.f, acc1 = 0.f;

  if (deg <= 64) {
    int src = (lane < deg) ? csr_src[r0 + lane] : 0;
    float e = (lane < deg) ? (as_[src] + ad) : -3.0e38f;
    e = (e >= 0.f) ? e : 0.2f * e;
    float m = wave_reduce_max(e);
    float p = (lane < deg) ? __expf(e - m) : 0.f;
    float inv = 1.f / (wave_reduce_sum(p) + 1e-16f);
    psbuf[wid][lane] = make_float2(p, __int_as_float(src));

    float b0 = 0.f, b1 = 0.f;
    int jj = 0;
    for (; jj + 4 <= deg; jj += 4) {
      float2 ps0 = psbuf[wid][jj + rh];
      float2 ps1 = psbuf[wid][jj + 2 + rh];
      unsigned v0 = hp[(size_t)__float_as_int(ps0.y) * 32 + fl];
      unsigned v1 = hp[(size_t)__float_as_int(ps1.y) * 32 + fl];
      acc0 = fmaf(ps0.x, __uint_as_float(v0 << 16), acc0);
      acc1 = fmaf(ps0.x, __uint_as_float(v0 & 0xffff0000u), acc1);
      b0 = fmaf(ps1.x, __uint_as_float(v1 << 16), b0);
      b1 = fmaf(ps1.x, __uint_as_float(v1 & 0xffff0000u), b1);
    }
    for (; jj < deg; jj += 2) {
      float2 ps0 = psbuf[wid][jj + rh];      // jj+rh==deg lane holds p=0
      unsigned v0 = hp[(size_t)__float_as_int(ps0.y) * 32 + fl];
      acc0 = fmaf(ps0.x, __uint_as_float(v0 << 16), acc0);
      acc1 = fmaf(ps0.x, __uint_as_float(v0 & 0xffff0000u), acc1);
    }
    acc0 += b0; acc1 += b1;
    acc0 += __shfl_xor(acc0, 32);            // combine edge-parity halves
    acc1 += __shfl_xor(acc1, 32);
    acc0 *= inv; acc1 *= inv;
  } else {
    // rare fallback (deg > 64): all lanes process every edge with their fl pair
    float m = -3.0e38f;
    for (int j = r0 + lane; j < r1; j += 64) {
      float e = as_[csr_src[j]] + ad;
      e = (e >= 0.f) ? e : 0.2f * e;
      m = fmaxf(m, e);
    }
    m = wave_reduce_max(m);
    float ssum = 0.f;
    for (int j = r0; j < r1; ++j) {
      int src = csr_src[j];
      float e = as_[src] + ad;
      e = (e >= 0.f) ? e : 0.2f * e;
      float p = __expf(e - m);
      ssum += p;
      unsigned v = hp[(size_t)src * 32 + fl];
      acc0 = fmaf(p, __uint_as_float(v << 16), acc0);
      acc1 = fmaf(p, __uint_as_float(v & 0xffff0000u), acc1);
    }
    float inv2 = 1.f / (ssum + 1e-16f);
    acc0 *= inv2; acc1 *= inv2;
  }

  float2 bi = ((const float2*)bias)[fl];
  float o0 = fmaxf(acc0 + bi.x, 0.f);
  float o1 = fmaxf(acc1 + bi.y, 0.f);
  if (FINAL) {
    float2 wl = ((const float2*)Wlin)[fl];
    float rv = (rh == 0) ? (o0 * wl.x + o1 * wl.y) : 0.f;
    rv = wave_reduce_sum(rv);
    if (lane == 0) {
      float z = rv + blin[0];
      fout[n] = 1.f / (1.f + __expf(-z));
    }
  } else {
    if (rh == 0) ((float2*)out)[(size_t)n * 32 + fl] = make_float2(o0, o1);
  }
}

extern "C" void kernel_launch(void* const* d_in, const int* in_sizes, int n_in,
                              void* d_out, int out_size, void* d_ws, size_t ws_size,
                              hipStream_t stream) {
  const float* x   = (const float*)d_in[0];
  const int*   ei  = (const int*)d_in[1];
  const float* W1  = (const float*)d_in[2];
  const float* a1s = (const float*)d_in[3];
  const float* a1d = (const float*)d_in[4];
  const float* b1  = (const float*)d_in[5];
  const float* W2  = (const float*)d_in[6];
  const float* a2s = (const float*)d_in[7];
  const float* a2d = (const float*)d_in[8];
  const float* b2  = (const float*)d_in[9];
  const float* W3  = (const float*)d_in[10];
  const float* a3s = (const float*)d_in[11];
  const float* a3d = (const float*)d_in[12];
  const float* b3  = (const float*)d_in[13];
  const float* Wl  = (const float*)d_in[14];
  const float* bl  = (const float*)d_in[15];

  const int N  = in_sizes[0] / 128;
  const int E  = in_sizes[1] / 2;
  const int EE = E + N;

  char* p = (char*)d_ws;
  auto alloc = [&](size_t bytes) { char* r = p; p += (bytes + 255) & ~(size_t)255; return r; };
  int*      deg     = (int*)alloc((size_t)N * 4);
  int*      rowptr  = (int*)alloc((size_t)(N + 1) * 4);
  int*      partial = (int*)alloc(256 * 4);
  int*      csr_src = (int*)alloc((size_t)EE * 4);
  unsigned* hbuf    = (unsigned*)alloc((size_t)N * 64 * 2);   // bf16 packed x2
  float*    obuf    = (float*)alloc((size_t)N * 64 * 4);
  float*    as_     = (float*)alloc((size_t)N * 4);
  float*    ad_     = (float*)alloc((size_t)N * 4);

  // slot[] (EE ushorts = 3.4 MB) aliases hbuf (12.8 MB): dead before gemm writes h
  unsigned short* slot = (unsigned short*)hbuf;

  hipMemsetAsync(deg, 0, (size_t)N * 4, stream);

  int eb = (EE + 255) / 256;
  k_count_slot<<<eb, 256, 0, stream>>>(ei, deg, slot, E, EE);
  int nchunks = (N + SCAN_ELEMS - 1) / SCAN_ELEMS;
  k_scan_partial<<<nchunks, SCAN_T, 0, stream>>>(deg, partial, N);
  k_scan_top<<<1, 64, 0, stream>>>(partial, nchunks, rowptr + N);
  k_scan_final<<<nchunks, SCAN_T, 0, stream>>>(deg, partial, rowptr, N);
  k_scatter2<<<eb, 256, 0, stream>>>(ei, rowptr, slot, csr_src, E, EE);

  int ntiles = (N + 31) / 32;
  int g1 = ntiles < 512 ? ntiles : 512;    // FIN=128: 64 KB LDS -> 2 blocks/CU
  int g2 = ntiles < 1024 ? ntiles : 1024;  // FIN=64:  32 KB LDS
  int nb = (N + 3) / 4;

  // layer 1
  k_gemm5<128><<<g1, 256, 0, stream>>>(x, W1, a1s, a1d, hbuf, as_, ad_, N, ntiles);
  k_agg5<0><<<nb, 256, 0, stream>>>(rowptr, csr_src, hbuf, as_, ad_, b1, obuf,
                                    nullptr, nullptr, nullptr, N);
  // layer 2
  k_gemm5<64><<<g2, 256, 0, stream>>>(obuf, W2, a2s, a2d, hbuf, as_, ad_, N, ntiles);
  k_agg5<0><<<nb, 256, 0, stream>>>(rowptr, csr_src, hbuf, as_, ad_, b2, obuf,
                                    nullptr, nullptr, nullptr, N);
  // layer 3 (+ fused readout)
  k_gemm5<64><<<g2, 256, 0, stream>>>(obuf, W3, a3s, a3d, hbuf, as_, ad_, N, ntiles);
  k_agg5<1><<<nb, 256, 0, stream>>>(rowptr, csr_src, hbuf, as_, ad_, b3, nullptr,
                                    Wl, bl, (float*)d_out, N);
}

// Round 8
// 327.604 us; speedup vs baseline: 5.2119x; 1.2448x over previous
//
#include <hip/hip_runtime.h>
#include <hip/hip_bf16.h>
#include <math.h>

#define BSH 8          // 256 nodes per bucket
#define MAXBK 512      // >= nbk = ceil(N/256)
#define PCHUNK 4096    // edges per k_part block

__device__ __forceinline__ float wave_reduce_max(float v) {
  #pragma unroll
  for (int off = 32; off; off >>= 1) v = fmaxf(v, __shfl_xor(v, off));
  return v;
}
__device__ __forceinline__ float wave_reduce_sum(float v) {
  #pragma unroll
  for (int off = 32; off; off >>= 1) v += __shfl_xor(v, off);
  return v;
}

// round-to-nearest-even f32 -> bf16 (as ushort)
__device__ __forceinline__ unsigned f2bf(float f) {
  unsigned u = __float_as_uint(f);
  return (u + 0x7fffu + ((u >> 16) & 1u)) >> 16;
}

// async global->LDS, 16 B per lane (global_load_lds_dwordx4)
__device__ __forceinline__ void async_copy16(const float* gsrc, float* ldst) {
  __builtin_amdgcn_global_load_lds(
      (const __attribute__((address_space(1))) void*)gsrc,
      (__attribute__((address_space(3))) void*)ldst, 16, 0, 0);
}

// exclusive scan of arr[0..n) (n multiple of 64, <= MAXBK) by wave 0 of block
__device__ __forceinline__ void wave0_excl_scan(unsigned* arr, unsigned* out, int n, int t) {
  if (t < 64) {
    unsigned carry = 0;
    for (int c = 0; c < n / 64; c++) {
      unsigned v = arr[c * 64 + t];
      unsigned s = v;
      #pragma unroll
      for (int off = 1; off < 64; off <<= 1) {
        unsigned u = __shfl_up(s, off);
        if ((t & 63) >= off) s += u;
      }
      out[c * 64 + t] = s - v + carry;
      carry += __shfl(s, 63);
    }
  }
}

// ---------------- radix-bucketed CSR build (no global data atomics) -------

__global__ __launch_bounds__(256) void k_bhist(const int* __restrict__ ei,
                                               unsigned* __restrict__ gbucket,
                                               int E, int EE, int nbk) {
  __shared__ unsigned hist[MAXBK];
  int t = threadIdx.x;
  for (int i = t; i < nbk; i += 256) hist[i] = 0;
  __syncthreads();
  for (int e = blockIdx.x * 256 + t; e < EE; e += gridDim.x * 256) {
    int d = (e < E) ? ei[E + e] : (e - E);
    atomicAdd(&hist[d >> BSH], 1u);
  }
  __syncthreads();
  for (int i = t; i < nbk; i += 256)
    if (hist[i]) atomicAdd(&gbucket[i], hist[i]);
}

__global__ __launch_bounds__(256) void k_bscan(const unsigned* __restrict__ gbucket,
                                               unsigned* __restrict__ bbase,
                                               unsigned* __restrict__ bfill,
                                               int nbk, int EE) {
  __shared__ unsigned arr[MAXBK], exc[MAXBK];
  int t = threadIdx.x;
  for (int i = t; i < MAXBK; i += 256) arr[i] = (i < nbk) ? gbucket[i] : 0u;
  __syncthreads();
  wave0_excl_scan(arr, exc, MAXBK, t);
  __syncthreads();
  for (int i = t; i < nbk; i += 256) { bbase[i] = exc[i]; bfill[i] = exc[i]; }
  if (t == 0) bbase[nbk] = (unsigned)EE;
}

__global__ __launch_bounds__(256) void k_part(const int* __restrict__ ei,
                                              unsigned* __restrict__ bfill,
                                              uint2* __restrict__ part,
                                              int E, int EE) {
  __shared__ uint2 stage[PCHUNK];
  __shared__ unsigned lcnt[MAXBK], lexcl[MAXBK], lbase[MAXBK];
  int t = threadIdx.x;
  int base = blockIdx.x * PCHUNK;
  int cnt = EE - base; if (cnt > PCHUNK) cnt = PCHUNK;
  for (int i = t; i < MAXBK; i += 256) lcnt[i] = 0;
  __syncthreads();

  uint2 ed[16]; unsigned loc[16];
  #pragma unroll
  for (int i = 0; i < 16; i++) {
    int e = base + i * 256 + t;
    if (e < EE) {
      int s, d;
      if (e < E) { s = ei[e]; d = ei[E + e]; } else { s = e - E; d = s; }
      ed[i] = make_uint2((unsigned)s, (unsigned)d);
      loc[i] = atomicAdd(&lcnt[(unsigned)d >> BSH], 1u);
    }
  }
  __syncthreads();
  wave0_excl_scan(lcnt, lexcl, MAXBK, t);
  __syncthreads();
  for (int i = t; i < MAXBK; i += 256) {
    unsigned c = lcnt[i];
    lbase[i] = c ? atomicAdd(&bfill[i], c) : 0u;
  }
  __syncthreads();
  #pragma unroll
  for (int i = 0; i < 16; i++) {
    int e = base + i * 256 + t;
    if (e < EE) stage[lexcl[ed[i].y >> BSH] + loc[i]] = ed[i];
  }
  __syncthreads();
  for (int i = t; i < cnt; i += 256) {
    uint2 v = stage[i];
    unsigned b = v.y >> BSH;
    part[lbase[b] + ((unsigned)i - lexcl[b])] = v;
  }
}

__global__ __launch_bounds__(256) void k_bcsr(const uint2* __restrict__ part,
                                              const unsigned* __restrict__ bbase,
                                              int* __restrict__ rowptr,
                                              int* __restrict__ csr_src,
                                              int Nn, int nbk) {
  __shared__ unsigned sdeg[256], sexcl[256], sfill[256];
  int t = threadIdx.x, b = blockIdx.x;
  int e0 = (int)bbase[b], e1 = (int)bbase[b + 1];
  sdeg[t] = 0; sfill[t] = 0;
  __syncthreads();
  for (int j = e0 + t; j < e1; j += 256)
    atomicAdd(&sdeg[part[j].y & 255u], 1u);
  __syncthreads();
  wave0_excl_scan(sdeg, sexcl, 256, t);
  __syncthreads();
  int node = (b << BSH) + t;
  if (node < Nn) rowptr[node] = e0 + (int)sexcl[t];
  if (b == nbk - 1 && t == 0) rowptr[Nn] = e1;
  for (int j = e0 + t; j < e1; j += 256) {
    uint2 v = part[j];
    unsigned dl = v.y & 255u;
    unsigned k = atomicAdd(&sfill[dl], 1u);
    csr_src[e0 + (int)sexcl[dl] + (int)k] = (int)v.x;
  }
}

// ---------------- GEMM h = x@W fused with alpha reductions ----------------

template <int FIN>
__device__ __forceinline__ void stage_tile(const float* __restrict__ x, float* xs,
                                           int tile, int wid, int lane) {
  const size_t base = (size_t)tile * (32 * FIN);
  #pragma unroll
  for (int i = 0; i < FIN / 32; i++) {
    int chunk = wid * (FIN / 32) + i;          // 256 floats (1024 B) per chunk
    async_copy16(x + base + chunk * 256 + lane * 4, xs + chunk * 256);
  }
}

#define FMA2(av, wr) \
  acc0[r] = fmaf(av, wreg[wr].x, acc0[r]); \
  acc1[r] = fmaf(av, wreg[wr].y, acc1[r]);

template <int FIN>
__global__ __launch_bounds__(256) void k_gemm5(
    const float* __restrict__ x, const float* __restrict__ W,
    const float* __restrict__ avs, const float* __restrict__ avd,
    unsigned* __restrict__ h, float* __restrict__ as_out, float* __restrict__ ad_out,
    int Nn, int ntiles) {
  __shared__ float Wl[FIN * 64];
  __shared__ float xs[2][32 * FIN];
  int t = threadIdx.x, lane = t & 63, wid = t >> 6;
  int fl = lane & 31, rh = lane >> 5;

  #pragma unroll
  for (int i = 0; i < FIN / 16; i++)
    ((float4*)Wl)[i * 256 + t] = ((const float4*)W)[i * 256 + t];
  float2 As2 = *(const float2*)&avs[2 * fl];
  float2 Ad2 = *(const float2*)&avd[2 * fl];

  int tile = blockIdx.x;
  if (tile >= ntiles) return;
  stage_tile<FIN>(x, xs[0], tile, wid, lane);
  __syncthreads();
  int buf = 0;

  while (tile < ntiles) {
    int nxt = tile + gridDim.x;
    if (nxt < ntiles) stage_tile<FIN>(x, xs[buf ^ 1], nxt, wid, lane);

    float acc0[4], acc1[4];
    #pragma unroll
    for (int r = 0; r < 4; r++) { acc0[r] = 0.f; acc1[r] = 0.f; }
    const float* xw = &xs[buf][(wid * 8 + rh * 4) * FIN];
    const float2* wcol = (const float2*)&Wl[2 * fl];   // stride 32 float2 per k

    #pragma unroll 1
    for (int kb = 0; kb < FIN; kb += 16) {
      float2 wreg[16];
      #pragma unroll
      for (int k = 0; k < 16; k++) wreg[k] = wcol[(kb + k) * 32];
      #pragma unroll
      for (int r = 0; r < 4; r++) {
        const float4* xr = (const float4*)(xw + r * FIN + kb);
        float4 a0 = xr[0], a1 = xr[1], a2 = xr[2], a3 = xr[3];
        FMA2(a0.x, 0)  FMA2(a0.y, 1)  FMA2(a0.z, 2)  FMA2(a0.w, 3)
        FMA2(a1.x, 4)  FMA2(a1.y, 5)  FMA2(a1.z, 6)  FMA2(a1.w, 7)
        FMA2(a2.x, 8)  FMA2(a2.y, 9)  FMA2(a2.z, 10) FMA2(a2.w, 11)
        FMA2(a3.x, 12) FMA2(a3.y, 13) FMA2(a3.z, 14) FMA2(a3.w, 15)
      }
    }

    int row0 = tile * 32 + wid * 8 + rh * 4;
    #pragma unroll
    for (int r = 0; r < 4; r++) {
      int row = row0 + r;
      bool ok = row < Nn;
      if (ok) {
        unsigned pk = (f2bf(acc1[r]) << 16) | f2bf(acc0[r]);
        h[(size_t)row * 32 + fl] = pk;
      }
      float vs = acc0[r] * As2.x + acc1[r] * As2.y;
      float vd = acc0[r] * Ad2.x + acc1[r] * Ad2.y;
      #pragma unroll
      for (int off = 16; off; off >>= 1) {   // reduce within each 32-lane half
        vs += __shfl_xor(vs, off);
        vd += __shfl_xor(vd, off);
      }
      if (ok && fl == 0) { as_out[row] = vs; ad_out[row] = vd; }
    }

    __syncthreads();
    buf ^= 1;
    tile = nxt;
  }
}

// ---------------- per-dst-node softmax aggregation ----------------

template <int FINAL>
__global__ __launch_bounds__(256) void k_agg5(
    const int* __restrict__ rowptr, const int* __restrict__ csr_src,
    const unsigned* __restrict__ hp, const float* __restrict__ as_,
    const float* __restrict__ ad_, const float* __restrict__ bias,
    float* __restrict__ out, const float* __restrict__ Wlin,
    const float* __restrict__ blin, float* __restrict__ fout, int Nn) {
  __shared__ float2 psbuf[4][64];
  int t = threadIdx.x, lane = t & 63, wid = t >> 6;
  int fl = lane & 31, rh = lane >> 5;
  int n = blockIdx.x * 4 + wid;
  if (n >= Nn) return;
  int r0 = rowptr[n], r1 = rowptr[n + 1];
  int deg = r1 - r0;
  float ad = ad_[n];
  float acc0 = 0.f, acc1 = 0.f;

  if (deg <= 64) {
    int src = (lane < deg) ? csr_src[r0 + lane] : 0;
    float e = (lane < deg) ? (as_[src] + ad) : -3.0e38f;
    e = (e >= 0.f) ? e : 0.2f * e;
    float m = wave_reduce_max(e);
    float p = (lane < deg) ? __expf(e - m) : 0.f;
    float inv = 1.f / (wave_reduce_sum(p) + 1e-16f);
    psbuf[wid][lane] = make_float2(p, __int_as_float(src));

    float b0 = 0.f, b1 = 0.f;
    int jj = 0;
    for (; jj + 4 <= deg; jj += 4) {
      float2 ps0 = psbuf[wid][jj + rh];
      float2 ps1 = psbuf[wid][jj + 2 + rh];
      unsigned v0 = hp[(size_t)__float_as_int(ps0.y) * 32 + fl];
      unsigned v1 = hp[(size_t)__float_as_int(ps1.y) * 32 + fl];
      acc0 = fmaf(ps0.x, __uint_as_float(v0 << 16), acc0);
      acc1 = fmaf(ps0.x, __uint_as_float(v0 & 0xffff0000u), acc1);
      b0 = fmaf(ps1.x, __uint_as_float(v1 << 16), b0);
      b1 = fmaf(ps1.x, __uint_as_float(v1 & 0xffff0000u), b1);
    }
    for (; jj < deg; jj += 2) {
      float2 ps0 = psbuf[wid][jj + rh];      // jj+rh==deg lane holds p=0
      unsigned v0 = hp[(size_t)__float_as_int(ps0.y) * 32 + fl];
      acc0 = fmaf(ps0.x, __uint_as_float(v0 << 16), acc0);
      acc1 = fmaf(ps0.x, __uint_as_float(v0 & 0xffff0000u), acc1);
    }
    acc0 += b0; acc1 += b1;
    acc0 += __shfl_xor(acc0, 32);            // combine edge-parity halves
    acc1 += __shfl_xor(acc1, 32);
    acc0 *= inv; acc1 *= inv;
  } else {
    float m = -3.0e38f;
    for (int j = r0 + lane; j < r1; j += 64) {
      float e = as_[csr_src[j]] + ad;
      e = (e >= 0.f) ? e : 0.2f * e;
      m = fmaxf(m, e);
    }
    m = wave_reduce_max(m);
    float ssum = 0.f;
    for (int j = r0; j < r1; ++j) {
      int src = csr_src[j];
      float e = as_[src] + ad;
      e = (e >= 0.f) ? e : 0.2f * e;
      float p = __expf(e - m);
      ssum += p;
      unsigned v = hp[(size_t)src * 32 + fl];
      acc0 = fmaf(p, __uint_as_float(v << 16), acc0);
      acc1 = fmaf(p, __uint_as_float(v & 0xffff0000u), acc1);
    }
    float inv2 = 1.f / (ssum + 1e-16f);
    acc0 *= inv2; acc1 *= inv2;
  }

  float2 bi = ((const float2*)bias)[fl];
  float o0 = fmaxf(acc0 + bi.x, 0.f);
  float o1 = fmaxf(acc1 + bi.y, 0.f);
  if (FINAL) {
    float2 wl = ((const float2*)Wlin)[fl];
    float rv = (rh == 0) ? (o0 * wl.x + o1 * wl.y) : 0.f;
    rv = wave_reduce_sum(rv);
    if (lane == 0) {
      float z = rv + blin[0];
      fout[n] = 1.f / (1.f + __expf(-z));
    }
  } else {
    if (rh == 0) ((float2*)out)[(size_t)n * 32 + fl] = make_float2(o0, o1);
  }
}

extern "C" void kernel_launch(void* const* d_in, const int* in_sizes, int n_in,
                              void* d_out, int out_size, void* d_ws, size_t ws_size,
                              hipStream_t stream) {
  const float* x   = (const float*)d_in[0];
  const int*   ei  = (const int*)d_in[1];
  const float* W1  = (const float*)d_in[2];
  const float* a1s = (const float*)d_in[3];
  const float* a1d = (const float*)d_in[4];
  const float* b1  = (const float*)d_in[5];
  const float* W2  = (const float*)d_in[6];
  const float* a2s = (const float*)d_in[7];
  const float* a2d = (const float*)d_in[8];
  const float* b2  = (const float*)d_in[9];
  const float* W3  = (const float*)d_in[10];
  const float* a3s = (const float*)d_in[11];
  const float* a3d = (const float*)d_in[12];
  const float* b3  = (const float*)d_in[13];
  const float* Wl  = (const float*)d_in[14];
  const float* bl  = (const float*)d_in[15];

  const int N  = in_sizes[0] / 128;
  const int E  = in_sizes[1] / 2;
  const int EE = E + N;
  const int nbk = (N + 255) >> 8;

  char* p = (char*)d_ws;
  auto alloc = [&](size_t bytes) { char* r = p; p += (bytes + 255) & ~(size_t)255; return r; };
  unsigned* gbucket = (unsigned*)alloc((size_t)MAXBK * 4);
  unsigned* bbase   = (unsigned*)alloc((size_t)(MAXBK + 1) * 4);
  unsigned* bfill   = (unsigned*)alloc((size_t)MAXBK * 4);
  int*      rowptr  = (int*)alloc((size_t)(N + 1) * 4);
  int*      csr_src = (int*)alloc((size_t)EE * 4);
  unsigned* hbuf    = (unsigned*)alloc((size_t)N * 64 * 2);   // bf16 packed x2
  float*    obuf    = (float*)alloc((size_t)N * 64 * 4);
  float*    as_     = (float*)alloc((size_t)N * 4);
  float*    ad_     = (float*)alloc((size_t)N * 4);

  // part[] (EE uint2 = 13.6 MB) aliases obuf (25.6 MB): dead before agg1 writes obuf
  uint2* part = (uint2*)obuf;

  hipMemsetAsync(gbucket, 0, (size_t)MAXBK * 4, stream);

  k_bhist<<<256, 256, 0, stream>>>(ei, gbucket, E, EE, nbk);
  k_bscan<<<1, 256, 0, stream>>>(gbucket, bbase, bfill, nbk, EE);
  k_part<<<(EE + PCHUNK - 1) / PCHUNK, 256, 0, stream>>>(ei, bfill, part, E, EE);
  k_bcsr<<<nbk, 256, 0, stream>>>(part, bbase, rowptr, csr_src, N, nbk);

  int ntiles = (N + 31) / 32;
  int g1 = ntiles < 512 ? ntiles : 512;    // FIN=128: 64 KB LDS -> 2 blocks/CU
  int g2 = ntiles < 1024 ? ntiles : 1024;  // FIN=64:  32 KB LDS
  int nb = (N + 3) / 4;

  // layer 1
  k_gemm5<128><<<g1, 256, 0, stream>>>(x, W1, a1s, a1d, hbuf, as_, ad_, N, ntiles);
  k_agg5<0><<<nb, 256, 0, stream>>>(rowptr, csr_src, hbuf, as_, ad_, b1, obuf,
                                    nullptr, nullptr, nullptr, N);
  // layer 2
  k_gemm5<64><<<g2, 256, 0, stream>>>(obuf, W2, a2s, a2d, hbuf, as_, ad_, N, ntiles);
  k_agg5<0><<<nb, 256, 0, stream>>>(rowptr, csr_src, hbuf, as_, ad_, b2, obuf,
                                    nullptr, nullptr, nullptr, N);
  // layer 3 (+ fused readout)
  k_gemm5<64><<<g2, 256, 0, stream>>>(obuf, W3, a3s, a3d, hbuf, as_, ad_, N, ntiles);
  k_agg5<1><<<nb, 256, 0, stream>>>(rowptr, csr_src, hbuf, as_, ad_, b3, nullptr,
                                    Wl, bl, (float*)d_out, N);
}

// Round 9
// 295.611 us; speedup vs baseline: 5.7760x; 1.1082x over previous
//
#include <hip/hip_runtime.h>
#include <hip/hip_bf16.h>
#include <math.h>

#define BSH 8          // 256 nodes per bucket
#define MAXBK 512      // >= nbk = ceil(N/256)
#define PCHUNK 4096    // edges per k_part block

__device__ __forceinline__ float wave_reduce_sum(float v) {
  #pragma unroll
  for (int off = 32; off; off >>= 1) v += __shfl_xor(v, off);
  return v;
}
__device__ __forceinline__ float half_reduce_max(float v) {
  #pragma unroll
  for (int off = 16; off; off >>= 1) v = fmaxf(v, __shfl_xor(v, off));
  return v;
}
__device__ __forceinline__ float half_reduce_sum(float v) {
  #pragma unroll
  for (int off = 16; off; off >>= 1) v += __shfl_xor(v, off);
  return v;
}

// round-to-nearest-even f32 -> bf16 (as ushort)
__device__ __forceinline__ unsigned f2bf(float f) {
  unsigned u = __float_as_uint(f);
  return (u + 0x7fffu + ((u >> 16) & 1u)) >> 16;
}

// async global->LDS, 16 B per lane (global_load_lds_dwordx4)
__device__ __forceinline__ void async_copy16(const float* gsrc, float* ldst) {
  __builtin_amdgcn_global_load_lds(
      (const __attribute__((address_space(1))) void*)gsrc,
      (__attribute__((address_space(3))) void*)ldst, 16, 0, 0);
}

// exclusive scan of arr[0..n) (n multiple of 64, <= MAXBK) by wave 0 of block
__device__ __forceinline__ void wave0_excl_scan(unsigned* arr, unsigned* out, int n, int t) {
  if (t < 64) {
    unsigned carry = 0;
    for (int c = 0; c < n / 64; c++) {
      unsigned v = arr[c * 64 + t];
      unsigned s = v;
      #pragma unroll
      for (int off = 1; off < 64; off <<= 1) {
        unsigned u = __shfl_up(s, off);
        if ((t & 63) >= off) s += u;
      }
      out[c * 64 + t] = s - v + carry;
      carry += __shfl(s, 63);
    }
  }
}

// ---------------- radix-bucketed CSR build (no global data atomics) -------

__global__ __launch_bounds__(256) void k_bhist(const int* __restrict__ ei,
                                               unsigned* __restrict__ gbucket,
                                               int E, int EE, int nbk) {
  __shared__ unsigned hist[MAXBK];
  int t = threadIdx.x;
  for (int i = t; i < nbk; i += 256) hist[i] = 0;
  __syncthreads();
  for (int e = blockIdx.x * 256 + t; e < EE; e += gridDim.x * 256) {
    int d = (e < E) ? ei[E + e] : (e - E);
    atomicAdd(&hist[d >> BSH], 1u);
  }
  __syncthreads();
  for (int i = t; i < nbk; i += 256)
    if (hist[i]) atomicAdd(&gbucket[i], hist[i]);
}

__global__ __launch_bounds__(256) void k_bscan(const unsigned* __restrict__ gbucket,
                                               unsigned* __restrict__ bbase,
                                               unsigned* __restrict__ bfill,
                                               int nbk, int EE) {
  __shared__ unsigned arr[MAXBK], exc[MAXBK];
  int t = threadIdx.x;
  for (int i = t; i < MAXBK; i += 256) arr[i] = (i < nbk) ? gbucket[i] : 0u;
  __syncthreads();
  wave0_excl_scan(arr, exc, MAXBK, t);
  __syncthreads();
  for (int i = t; i < nbk; i += 256) { bbase[i] = exc[i]; bfill[i] = exc[i]; }
  if (t == 0) bbase[nbk] = (unsigned)EE;
}

__global__ __launch_bounds__(256) void k_part(const int* __restrict__ ei,
                                              unsigned* __restrict__ bfill,
                                              uint2* __restrict__ part,
                                              int E, int EE) {
  __shared__ uint2 stage[PCHUNK];
  __shared__ unsigned lcnt[MAXBK], lexcl[MAXBK], lbase[MAXBK];
  int t = threadIdx.x;
  int base = blockIdx.x * PCHUNK;
  int cnt = EE - base; if (cnt > PCHUNK) cnt = PCHUNK;
  for (int i = t; i < MAXBK; i += 256) lcnt[i] = 0;
  __syncthreads();

  uint2 ed[16]; unsigned loc[16];
  #pragma unroll
  for (int i = 0; i < 16; i++) {
    int e = base + i * 256 + t;
    if (e < EE) {
      int s, d;
      if (e < E) { s = ei[e]; d = ei[E + e]; } else { s = e - E; d = s; }
      ed[i] = make_uint2((unsigned)s, (unsigned)d);
      loc[i] = atomicAdd(&lcnt[(unsigned)d >> BSH], 1u);
    }
  }
  __syncthreads();
  wave0_excl_scan(lcnt, lexcl, MAXBK, t);
  __syncthreads();
  for (int i = t; i < MAXBK; i += 256) {
    unsigned c = lcnt[i];
    lbase[i] = c ? atomicAdd(&bfill[i], c) : 0u;
  }
  __syncthreads();
  #pragma unroll
  for (int i = 0; i < 16; i++) {
    int e = base + i * 256 + t;
    if (e < EE) stage[lexcl[ed[i].y >> BSH] + loc[i]] = ed[i];
  }
  __syncthreads();
  for (int i = t; i < cnt; i += 256) {
    uint2 v = stage[i];
    unsigned b = v.y >> BSH;
    part[lbase[b] + ((unsigned)i - lexcl[b])] = v;
  }
}

__global__ __launch_bounds__(256) void k_bcsr(const uint2* __restrict__ part,
                                              const unsigned* __restrict__ bbase,
                                              int* __restrict__ rowptr,
                                              int* __restrict__ csr_src,
                                              int Nn, int nbk) {
  __shared__ unsigned sdeg[256], sexcl[256], sfill[256];
  int t = threadIdx.x, b = blockIdx.x;
  int e0 = (int)bbase[b], e1 = (int)bbase[b + 1];
  sdeg[t] = 0; sfill[t] = 0;
  __syncthreads();
  for (int j = e0 + t; j < e1; j += 256)
    atomicAdd(&sdeg[part[j].y & 255u], 1u);
  __syncthreads();
  wave0_excl_scan(sdeg, sexcl, 256, t);
  __syncthreads();
  int node = (b << BSH) + t;
  if (node < Nn) rowptr[node] = e0 + (int)sexcl[t];
  if (b == nbk - 1 && t == 0) rowptr[Nn] = e1;
  for (int j = e0 + t; j < e1; j += 256) {
    uint2 v = part[j];
    unsigned dl = v.y & 255u;
    unsigned k = atomicAdd(&sfill[dl], 1u);
    csr_src[e0 + (int)sexcl[dl] + (int)k] = (int)v.x;
  }
}

// ---------------- GEMM h = x@W fused with alpha reductions ----------------

template <int FIN>
__device__ __forceinline__ void stage_tile(const float* __restrict__ x, float* xs,
                                           int tile, int wid, int lane) {
  const size_t base = (size_t)tile * (32 * FIN);
  #pragma unroll
  for (int i = 0; i < FIN / 32; i++) {
    int chunk = wid * (FIN / 32) + i;          // 256 floats (1024 B) per chunk
    async_copy16(x + base + chunk * 256 + lane * 4, xs + chunk * 256);
  }
}

#define FMA2(av, wr) \
  acc0[r] = fmaf(av, wreg[wr].x, acc0[r]); \
  acc1[r] = fmaf(av, wreg[wr].y, acc1[r]);

template <int FIN>
__global__ __launch_bounds__(256) void k_gemm5(
    const float* __restrict__ x, const float* __restrict__ W,
    const float* __restrict__ avs, const float* __restrict__ avd,
    unsigned* __restrict__ h, float* __restrict__ as_out, float* __restrict__ ad_out,
    int Nn, int ntiles) {
  __shared__ float Wl[FIN * 64];
  __shared__ float xs[2][32 * FIN];
  int t = threadIdx.x, lane = t & 63, wid = t >> 6;
  int fl = lane & 31, rh = lane >> 5;

  #pragma unroll
  for (int i = 0; i < FIN / 16; i++)
    ((float4*)Wl)[i * 256 + t] = ((const float4*)W)[i * 256 + t];
  float2 As2 = *(const float2*)&avs[2 * fl];
  float2 Ad2 = *(const float2*)&avd[2 * fl];

  int tile = blockIdx.x;
  if (tile >= ntiles) return;
  stage_tile<FIN>(x, xs[0], tile, wid, lane);
  __syncthreads();
  int buf = 0;

  while (tile < ntiles) {
    int nxt = tile + gridDim.x;
    if (nxt < ntiles) stage_tile<FIN>(x, xs[buf ^ 1], nxt, wid, lane);

    float acc0[4], acc1[4];
    #pragma unroll
    for (int r = 0; r < 4; r++) { acc0[r] = 0.f; acc1[r] = 0.f; }
    const float* xw = &xs[buf][(wid * 8 + rh * 4) * FIN];
    const float2* wcol = (const float2*)&Wl[2 * fl];   // stride 32 float2 per k

    #pragma unroll 1
    for (int kb = 0; kb < FIN; kb += 16) {
      float2 wreg[16];
      #pragma unroll
      for (int k = 0; k < 16; k++) wreg[k] = wcol[(kb + k) * 32];
      #pragma unroll
      for (int r = 0; r < 4; r++) {
        const float4* xr = (const float4*)(xw + r * FIN + kb);
        float4 a0 = xr[0], a1 = xr[1], a2 = xr[2], a3 = xr[3];
        FMA2(a0.x, 0)  FMA2(a0.y, 1)  FMA2(a0.z, 2)  FMA2(a0.w, 3)
        FMA2(a1.x, 4)  FMA2(a1.y, 5)  FMA2(a1.z, 6)  FMA2(a1.w, 7)
        FMA2(a2.x, 8)  FMA2(a2.y, 9)  FMA2(a2.z, 10) FMA2(a2.w, 11)
        FMA2(a3.x, 12) FMA2(a3.y, 13) FMA2(a3.z, 14) FMA2(a3.w, 15)
      }
    }

    int row0 = tile * 32 + wid * 8 + rh * 4;
    #pragma unroll
    for (int r = 0; r < 4; r++) {
      int row = row0 + r;
      bool ok = row < Nn;
      if (ok) {
        unsigned pk = (f2bf(acc1[r]) << 16) | f2bf(acc0[r]);
        h[(size_t)row * 32 + fl] = pk;
      }
      float vs = acc0[r] * As2.x + acc1[r] * As2.y;
      float vd = acc0[r] * Ad2.x + acc1[r] * Ad2.y;
      #pragma unroll
      for (int off = 16; off; off >>= 1) {   // reduce within each 32-lane half
        vs += __shfl_xor(vs, off);
        vd += __shfl_xor(vd, off);
      }
      if (ok && fl == 0) { as_out[row] = vs; ad_out[row] = vd; }
    }

    __syncthreads();
    buf ^= 1;
    tile = nxt;
  }
}

// ---------------- per-dst-node softmax aggregation ----------------
// Half-wave (32 lanes) per node: fl = feature pair. Phase A edge-parallel
// for deg<=32 (99.99% of Poisson-16 nodes); serial-recompute fallback else.

template <int FINAL>
__global__ __launch_bounds__(256) void k_agg6(
    const int* __restrict__ rowptr, const int* __restrict__ csr_src,
    const unsigned* __restrict__ hp, const float* __restrict__ as_,
    const float* __restrict__ ad_, const float* __restrict__ bias,
    float* __restrict__ out, const float* __restrict__ Wlin,
    const float* __restrict__ blin, float* __restrict__ fout, int Nn) {
  __shared__ float2 psbuf[4][2][32];
  int t = threadIdx.x, lane = t & 63, wid = t >> 6;
  int fl = lane & 31, hh = lane >> 5;
  int n = blockIdx.x * 8 + wid * 2 + hh;
  bool valid = n < Nn;
  int nn = valid ? n : (Nn - 1);
  int r0 = rowptr[nn], r1 = rowptr[nn + 1];
  int deg = valid ? (r1 - r0) : 0;
  float ad = ad_[nn];
  float acc0 = 0.f, acc1 = 0.f;
  float inv;

  if (deg <= 32) {
    int src = (fl < deg) ? csr_src[r0 + fl] : 0;
    float e = (fl < deg) ? (as_[src] + ad) : -3.0e38f;
    e = (e >= 0.f) ? e : 0.2f * e;
    float m = half_reduce_max(e);
    float p = (fl < deg) ? __expf(e - m) : 0.f;
    inv = 1.f / (half_reduce_sum(p) + 1e-16f);
    psbuf[wid][hh][fl] = make_float2(p, __int_as_float(src));

    float b0 = 0.f, b1 = 0.f;
    int jj = 0;
    for (; jj + 2 <= deg; jj += 2) {
      float2 ps0 = psbuf[wid][hh][jj];
      float2 ps1 = psbuf[wid][hh][jj + 1];
      unsigned v0 = hp[(size_t)__float_as_int(ps0.y) * 32 + fl];
      unsigned v1 = hp[(size_t)__float_as_int(ps1.y) * 32 + fl];
      acc0 = fmaf(ps0.x, __uint_as_float(v0 << 16), acc0);
      acc1 = fmaf(ps0.x, __uint_as_float(v0 & 0xffff0000u), acc1);
      b0 = fmaf(ps1.x, __uint_as_float(v1 << 16), b0);
      b1 = fmaf(ps1.x, __uint_as_float(v1 & 0xffff0000u), b1);
    }
    if (jj < deg) {
      float2 ps0 = psbuf[wid][hh][jj];
      unsigned v0 = hp[(size_t)__float_as_int(ps0.y) * 32 + fl];
      acc0 = fmaf(ps0.x, __uint_as_float(v0 << 16), acc0);
      acc1 = fmaf(ps0.x, __uint_as_float(v0 & 0xffff0000u), acc1);
    }
    acc0 = (acc0 + b0) * inv;
    acc1 = (acc1 + b1) * inv;
  } else {
    // rare fallback (deg > 32): two-pass, serial recompute in pass 2
    float m = -3.0e38f;
    for (int j = r0 + fl; j < r1; j += 32) {
      float e = as_[csr_src[j]] + ad;
      e = (e >= 0.f) ? e : 0.2f * e;
      m = fmaxf(m, e);
    }
    m = half_reduce_max(m);
    float ssum = 0.f;
    for (int j = r0; j < r1; ++j) {
      int src = csr_src[j];
      float e = as_[src] + ad;
      e = (e >= 0.f) ? e : 0.2f * e;
      float p = __expf(e - m);
      ssum += p;
      unsigned v = hp[(size_t)src * 32 + fl];
      acc0 = fmaf(p, __uint_as_float(v << 16), acc0);
      acc1 = fmaf(p, __uint_as_float(v & 0xffff0000u), acc1);
    }
    float inv2 = 1.f / (ssum + 1e-16f);
    acc0 *= inv2;
    acc1 *= inv2;
  }

  float2 bi = ((const float2*)bias)[fl];
  float o0 = fmaxf(acc0 + bi.x, 0.f);
  float o1 = fmaxf(acc1 + bi.y, 0.f);
  if (FINAL) {
    float2 wl = ((const float2*)Wlin)[fl];
    float rv = half_reduce_sum(o0 * wl.x + o1 * wl.y);
    if (valid && fl == 0) {
      float z = rv + blin[0];
      fout[n] = 1.f / (1.f + __expf(-z));
    }
  } else {
    if (valid) ((float2*)out)[(size_t)n * 32 + fl] = make_float2(o0, o1);
  }
}

extern "C" void kernel_launch(void* const* d_in, const int* in_sizes, int n_in,
                              void* d_out, int out_size, void* d_ws, size_t ws_size,
                              hipStream_t stream) {
  const float* x   = (const float*)d_in[0];
  const int*   ei  = (const int*)d_in[1];
  const float* W1  = (const float*)d_in[2];
  const float* a1s = (const float*)d_in[3];
  const float* a1d = (const float*)d_in[4];
  const float* b1  = (const float*)d_in[5];
  const float* W2  = (const float*)d_in[6];
  const float* a2s = (const float*)d_in[7];
  const float* a2d = (const float*)d_in[8];
  const float* b2  = (const float*)d_in[9];
  const float* W3  = (const float*)d_in[10];
  const float* a3s = (const float*)d_in[11];
  const float* a3d = (const float*)d_in[12];
  const float* b3  = (const float*)d_in[13];
  const float* Wl  = (const float*)d_in[14];
  const float* bl  = (const float*)d_in[15];

  const int N  = in_sizes[0] / 128;
  const int E  = in_sizes[1] / 2;
  const int EE = E + N;
  const int nbk = (N + 255) >> 8;

  char* p = (char*)d_ws;
  auto alloc = [&](size_t bytes) { char* r = p; p += (bytes + 255) & ~(size_t)255; return r; };
  unsigned* gbucket = (unsigned*)alloc((size_t)MAXBK * 4);
  unsigned* bbase   = (unsigned*)alloc((size_t)(MAXBK + 1) * 4);
  unsigned* bfill   = (unsigned*)alloc((size_t)MAXBK * 4);
  int*      rowptr  = (int*)alloc((size_t)(N + 1) * 4);
  int*      csr_src = (int*)alloc((size_t)EE * 4);
  unsigned* hbuf    = (unsigned*)alloc((size_t)N * 64 * 2);   // bf16 packed x2
  float*    obuf    = (float*)alloc((size_t)N * 64 * 4);
  float*    as_     = (float*)alloc((size_t)N * 4);
  float*    ad_     = (float*)alloc((size_t)N * 4);

  // part[] (EE uint2 = 13.6 MB) aliases obuf (25.6 MB): dead before agg1 writes obuf
  uint2* part = (uint2*)obuf;

  hipMemsetAsync(gbucket, 0, (size_t)MAXBK * 4, stream);

  k_bhist<<<256, 256, 0, stream>>>(ei, gbucket, E, EE, nbk);
  k_bscan<<<1, 256, 0, stream>>>(gbucket, bbase, bfill, nbk, EE);
  k_part<<<(EE + PCHUNK - 1) / PCHUNK, 256, 0, stream>>>(ei, bfill, part, E, EE);
  k_bcsr<<<nbk, 256, 0, stream>>>(part, bbase, rowptr, csr_src, N, nbk);

  int ntiles = (N + 31) / 32;
  int g1 = ntiles < 512 ? ntiles : 512;    // FIN=128: 64 KB LDS -> 2 blocks/CU
  int g2 = ntiles < 1024 ? ntiles : 1024;  // FIN=64:  32 KB LDS
  int nb = (N + 7) / 8;

  // layer 1
  k_gemm5<128><<<g1, 256, 0, stream>>>(x, W1, a1s, a1d, hbuf, as_, ad_, N, ntiles);
  k_agg6<0><<<nb, 256, 0, stream>>>(rowptr, csr_src, hbuf, as_, ad_, b1, obuf,
                                    nullptr, nullptr, nullptr, N);
  // layer 2
  k_gemm5<64><<<g2, 256, 0, stream>>>(obuf, W2, a2s, a2d, hbuf, as_, ad_, N, ntiles);
  k_agg6<0><<<nb, 256, 0, stream>>>(rowptr, csr_src, hbuf, as_, ad_, b2, obuf,
                                    nullptr, nullptr, nullptr, N);
  // layer 3 (+ fused readout)
  k_gemm5<64><<<g2, 256, 0, stream>>>(obuf, W3, a3s, a3d, hbuf, as_, ad_, N, ntiles);
  k_agg6<1><<<nb, 256, 0, stream>>>(rowptr, csr_src, hbuf, as_, ad_, b3, nullptr,
                                    Wl, bl, (float*)d_out, N);
}

// Round 10
// 265.140 us; speedup vs baseline: 6.4398x; 1.1149x over previous
//
#include <hip/hip_runtime.h>
#include <hip/hip_bf16.h>
#include <math.h>

#define BSH 8          // 256 nodes per bucket
#define MAXBK 512      // >= nbk = ceil(N/256)
#define PCHUNK 4096    // edges per k_part block

typedef __attribute__((ext_vector_type(8)))  short short8;
typedef __attribute__((ext_vector_type(16))) float f32x16;

__device__ __forceinline__ float half_reduce_max(float v) {
  #pragma unroll
  for (int off = 16; off; off >>= 1) v = fmaxf(v, __shfl_xor(v, off));
  return v;
}
__device__ __forceinline__ float half_reduce_sum(float v) {
  #pragma unroll
  for (int off = 16; off; off >>= 1) v += __shfl_xor(v, off);
  return v;
}

// round-to-nearest-even f32 -> bf16 (as unsigned)
__device__ __forceinline__ unsigned f2bf(float f) {
  unsigned u = __float_as_uint(f);
  return (u + 0x7fffu + ((u >> 16) & 1u)) >> 16;
}

// async global->LDS, 16 B per lane (global_load_lds_dwordx4)
__device__ __forceinline__ void async_copy16(const void* gsrc, void* ldst) {
  __builtin_amdgcn_global_load_lds(
      (const __attribute__((address_space(1))) void*)gsrc,
      (__attribute__((address_space(3))) void*)ldst, 16, 0, 0);
}

// exclusive scan of arr[0..n) (n multiple of 64, <= MAXBK) by wave 0 of block
__device__ __forceinline__ void wave0_excl_scan(unsigned* arr, unsigned* out, int n, int t) {
  if (t < 64) {
    unsigned carry = 0;
    for (int c = 0; c < n / 64; c++) {
      unsigned v = arr[c * 64 + t];
      unsigned s = v;
      #pragma unroll
      for (int off = 1; off < 64; off <<= 1) {
        unsigned u = __shfl_up(s, off);
        if ((t & 63) >= off) s += u;
      }
      out[c * 64 + t] = s - v + carry;
      carry += __shfl(s, 63);
    }
  }
}

// ---------------- radix-bucketed CSR build (no global data atomics) -------

__global__ __launch_bounds__(256) void k_bhist(const int* __restrict__ ei,
                                               unsigned* __restrict__ gbucket,
                                               int E, int EE, int nbk) {
  __shared__ unsigned hist[MAXBK];
  int t = threadIdx.x;
  for (int i = t; i < nbk; i += 256) hist[i] = 0;
  __syncthreads();
  for (int e = blockIdx.x * 256 + t; e < EE; e += gridDim.x * 256) {
    int d = (e < E) ? ei[E + e] : (e - E);
    atomicAdd(&hist[d >> BSH], 1u);
  }
  __syncthreads();
  for (int i = t; i < nbk; i += 256)
    if (hist[i]) atomicAdd(&gbucket[i], hist[i]);
}

__global__ __launch_bounds__(256) void k_bscan(const unsigned* __restrict__ gbucket,
                                               unsigned* __restrict__ bbase,
                                               unsigned* __restrict__ bfill,
                                               int nbk, int EE) {
  __shared__ unsigned arr[MAXBK], exc[MAXBK];
  int t = threadIdx.x;
  for (int i = t; i < MAXBK; i += 256) arr[i] = (i < nbk) ? gbucket[i] : 0u;
  __syncthreads();
  wave0_excl_scan(arr, exc, MAXBK, t);
  __syncthreads();
  for (int i = t; i < nbk; i += 256) { bbase[i] = exc[i]; bfill[i] = exc[i]; }
  if (t == 0) bbase[nbk] = (unsigned)EE;
}

__global__ __launch_bounds__(256) void k_part(const int* __restrict__ ei,
                                              unsigned* __restrict__ bfill,
                                              uint2* __restrict__ part,
                                              int E, int EE) {
  __shared__ uint2 stage[PCHUNK];
  __shared__ unsigned lcnt[MAXBK], lexcl[MAXBK], lbase[MAXBK];
  int t = threadIdx.x;
  int base = blockIdx.x * PCHUNK;
  int cnt = EE - base; if (cnt > PCHUNK) cnt = PCHUNK;
  for (int i = t; i < MAXBK; i += 256) lcnt[i] = 0;
  __syncthreads();

  uint2 ed[16]; unsigned loc[16];
  #pragma unroll
  for (int i = 0; i < 16; i++) {
    int e = base + i * 256 + t;
    if (e < EE) {
      int s, d;
      if (e < E) { s = ei[e]; d = ei[E + e]; } else { s = e - E; d = s; }
      ed[i] = make_uint2((unsigned)s, (unsigned)d);
      loc[i] = atomicAdd(&lcnt[(unsigned)d >> BSH], 1u);
    }
  }
  __syncthreads();
  wave0_excl_scan(lcnt, lexcl, MAXBK, t);
  __syncthreads();
  for (int i = t; i < MAXBK; i += 256) {
    unsigned c = lcnt[i];
    lbase[i] = c ? atomicAdd(&bfill[i], c) : 0u;
  }
  __syncthreads();
  #pragma unroll
  for (int i = 0; i < 16; i++) {
    int e = base + i * 256 + t;
    if (e < EE) stage[lexcl[ed[i].y >> BSH] + loc[i]] = ed[i];
  }
  __syncthreads();
  for (int i = t; i < cnt; i += 256) {
    uint2 v = stage[i];
    unsigned b = v.y >> BSH;
    part[lbase[b] + ((unsigned)i - lexcl[b])] = v;
  }
}

__global__ __launch_bounds__(256) void k_bcsr(const uint2* __restrict__ part,
                                              const unsigned* __restrict__ bbase,
                                              int* __restrict__ rowptr,
                                              int* __restrict__ csr_src,
                                              int Nn, int nbk) {
  __shared__ unsigned sdeg[256], sexcl[256], sfill[256];
  int t = threadIdx.x, b = blockIdx.x;
  int e0 = (int)bbase[b], e1 = (int)bbase[b + 1];
  sdeg[t] = 0; sfill[t] = 0;
  __syncthreads();
  for (int j = e0 + t; j < e1; j += 256)
    atomicAdd(&sdeg[part[j].y & 255u], 1u);
  __syncthreads();
  wave0_excl_scan(sdeg, sexcl, 256, t);
  __syncthreads();
  int node = (b << BSH) + t;
  if (node < Nn) rowptr[node] = e0 + (int)sexcl[t];
  if (b == nbk - 1 && t == 0) rowptr[Nn] = e1;
  for (int j = e0 + t; j < e1; j += 256) {
    uint2 v = part[j];
    unsigned dl = v.y & 255u;
    unsigned k = atomicAdd(&sfill[dl], 1u);
    csr_src[e0 + (int)sexcl[dl] + (int)k] = (int)v.x;
  }
}

// ---------------- W fragment prep (frag-ordered bf16 for MFMA A-operand) --
// entry layout: group g in [0,32): g<16 -> L1 (s=g>>1, t=g&1, K=128);
// 16<=g<24 -> L2; 24<=g<32 -> L3 (K=64). Each group: 64 lanes x short8.
// frag elem e of lane l: W[(s*16 + (l>>5)*8 + e)*64 + (t*32 + (l&31))]

__global__ __launch_bounds__(256) void k_wprep(const float* __restrict__ W1,
                                               const float* __restrict__ W2,
                                               const float* __restrict__ W3,
                                               short8* __restrict__ wf) {
  int idx = blockIdx.x * 256 + threadIdx.x;
  if (idx >= 2048) return;
  int g = idx >> 6, l = idx & 63;
  const float* W; int s, t;
  if (g < 16)      { W = W1; s = g >> 1;        t = g & 1; }
  else if (g < 24) { W = W2; s = (g - 16) >> 1; t = g & 1; }
  else             { W = W3; s = (g - 24) >> 1; t = g & 1; }
  int of = t * 32 + (l & 31);
  int k0 = s * 16 + (l >> 5) * 8;
  short8 v;
  #pragma unroll
  for (int e = 0; e < 8; e++) v[e] = (short)f2bf(W[(k0 + e) * 64 + of]);
  wf[idx] = v;
}

// ---------------- MFMA GEMM: h = x@W + fused alpha reductions -------------
// D = A(W: of x k) * B(x^T: k x row)  => lane holds 16 of-values of ONE row.
// 128 rows/block, 4 waves x 32 rows. x-tile in LDS via global_load_lds with
// pre-swizzled SOURCE (rule: linear dest + inv-swz src + swz read).

template <int K, bool F32IN>
__global__ __launch_bounds__(256) void k_gemm7(
    const void* __restrict__ xin, const short8* __restrict__ wf,
    const float* __restrict__ avs, const float* __restrict__ avd,
    unsigned* __restrict__ h, float* __restrict__ as_out,
    float* __restrict__ ad_out, int Nn) {
  constexpr int NS = K / 16;                 // k-steps
  constexpr int RB = F32IN ? K * 4 : K * 2;  // row bytes
  constexpr int RSH = F32IN ? (K == 128 ? 9 : 8) : (K == 128 ? 8 : 7);
  __shared__ __align__(16) char xs_raw[128 * RB];
  int t = threadIdx.x, lane = t & 63, wid = t >> 6;
  int l31 = lane & 31, hi = lane >> 5;

  // W fragments -> registers (coalesced b128 from frag-ordered buffer)
  short8 wa[NS * 2];
  #pragma unroll
  for (int i = 0; i < NS * 2; i++) wa[i] = wf[i * 64 + lane];

  // stage 128-row x tile (swizzled source, linear LDS dest)
  int tile0 = blockIdx.x * 128;
  const char* xg = (const char*)xin;
  constexpr int CH = (128 * RB) / (256 * 16);
  #pragma unroll
  for (int i = 0; i < CH; i++) {
    int off = (i * 256 + t) * 16;
    int row = off >> RSH;
    int inrow = off & (RB - 1);
    long grow = (long)tile0 + row;
    if (grow > (long)Nn - 1) grow = Nn - 1;   // tail clamp (outputs guarded)
    async_copy16(xg + grow * RB + (inrow ^ ((row & 7) << 4)), xs_raw + off);
  }
  __syncthreads();

  f32x16 acc0 = {0,0,0,0,0,0,0,0,0,0,0,0,0,0,0,0};
  f32x16 acc1 = {0,0,0,0,0,0,0,0,0,0,0,0,0,0,0,0};
  int rowl = wid * 32 + l31;
  int swz = (rowl & 7) << 4;

  #pragma unroll
  for (int s = 0; s < NS; s++) {
    short8 bf;
    if constexpr (F32IN) {
      int ph = (rowl * RB + s * 64 + hi * 32) ^ swz;
      float4 fA = *(const float4*)(xs_raw + ph);
      float4 fB = *(const float4*)(xs_raw + (ph ^ 16));
      bf[0] = (short)f2bf(fA.x); bf[1] = (short)f2bf(fA.y);
      bf[2] = (short)f2bf(fA.z); bf[3] = (short)f2bf(fA.w);
      bf[4] = (short)f2bf(fB.x); bf[5] = (short)f2bf(fB.y);
      bf[6] = (short)f2bf(fB.z); bf[7] = (short)f2bf(fB.w);
    } else {
      int ph = (rowl * RB + s * 32 + hi * 16) ^ swz;
      bf = *(const short8*)(xs_raw + ph);
    }
    acc0 = __builtin_amdgcn_mfma_f32_32x32x16_bf16(wa[2 * s], bf, acc0, 0, 0, 0);
    acc1 = __builtin_amdgcn_mfma_f32_32x32x16_bf16(wa[2 * s + 1], bf, acc1, 0, 0, 0);
  }

  int xrow = tile0 + rowl;
  bool ok = xrow < Nn;
  float asp = 0.f, adp = 0.f;
  #pragma unroll
  for (int r = 0; r < 16; r += 2) {
    int rof = (r & 3) + 8 * (r >> 2);     // D row mapping (m74-verified)
    int of0 = rof + 4 * hi;               // of pair (of0, of0+1) in-lane
    if (ok) {
      h[(size_t)xrow * 32 + (of0 >> 1)] =
          (f2bf(acc0[r + 1]) << 16) | f2bf(acc0[r]);
      h[(size_t)xrow * 32 + 16 + (of0 >> 1)] =
          (f2bf(acc1[r + 1]) << 16) | f2bf(acc1[r]);
    }
    asp += acc0[r] * avs[of0] + acc0[r + 1] * avs[of0 + 1]
         + acc1[r] * avs[of0 + 32] + acc1[r + 1] * avs[of0 + 33];
    adp += acc0[r] * avd[of0] + acc0[r + 1] * avd[of0 + 1]
         + acc1[r] * avd[of0 + 32] + acc1[r + 1] * avd[of0 + 33];
  }
  asp += __shfl_xor(asp, 32);
  adp += __shfl_xor(adp, 32);
  if (ok && hi == 0) { as_out[xrow] = asp; ad_out[xrow] = adp; }
}

// ---------------- per-dst-node softmax aggregation ----------------
// Half-wave (32 lanes) per node. FINAL=0 writes packed-bf16 obuf.

template <int FINAL>
__global__ __launch_bounds__(256) void k_agg7(
    const int* __restrict__ rowptr, const int* __restrict__ csr_src,
    const unsigned* __restrict__ hp, const float* __restrict__ as_,
    const float* __restrict__ ad_, const float* __restrict__ bias,
    unsigned* __restrict__ out, const float* __restrict__ Wlin,
    const float* __restrict__ blin, float* __restrict__ fout, int Nn) {
  __shared__ float2 psbuf[4][2][32];
  int t = threadIdx.x, lane = t & 63, wid = t >> 6;
  int fl = lane & 31, hh = lane >> 5;
  int n = blockIdx.x * 8 + wid * 2 + hh;
  bool valid = n < Nn;
  int nn = valid ? n : (Nn - 1);
  int r0 = rowptr[nn], r1 = rowptr[nn + 1];
  int deg = valid ? (r1 - r0) : 0;
  float ad = ad_[nn];
  float acc0 = 0.f, acc1 = 0.f;

  if (deg <= 32) {
    int src = (fl < deg) ? csr_src[r0 + fl] : 0;
    float e = (fl < deg) ? (as_[src] + ad) : -3.0e38f;
    e = (e >= 0.f) ? e : 0.2f * e;
    float m = half_reduce_max(e);
    float p = (fl < deg) ? __expf(e - m) : 0.f;
    float inv = 1.f / (half_reduce_sum(p) + 1e-16f);
    psbuf[wid][hh][fl] = make_float2(p, __int_as_float(src));

    float b0 = 0.f, b1 = 0.f;
    int jj = 0;
    for (; jj + 2 <= deg; jj += 2) {
      float2 ps0 = psbuf[wid][hh][jj];
      float2 ps1 = psbuf[wid][hh][jj + 1];
      unsigned v0 = hp[(size_t)__float_as_int(ps0.y) * 32 + fl];
      unsigned v1 = hp[(size_t)__float_as_int(ps1.y) * 32 + fl];
      acc0 = fmaf(ps0.x, __uint_as_float(v0 << 16), acc0);
      acc1 = fmaf(ps0.x, __uint_as_float(v0 & 0xffff0000u), acc1);
      b0 = fmaf(ps1.x, __uint_as_float(v1 << 16), b0);
      b1 = fmaf(ps1.x, __uint_as_float(v1 & 0xffff0000u), b1);
    }
    if (jj < deg) {
      float2 ps0 = psbuf[wid][hh][jj];
      unsigned v0 = hp[(size_t)__float_as_int(ps0.y) * 32 + fl];
      acc0 = fmaf(ps0.x, __uint_as_float(v0 << 16), acc0);
      acc1 = fmaf(ps0.x, __uint_as_float(v0 & 0xffff0000u), acc1);
    }
    acc0 = (acc0 + b0) * inv;
    acc1 = (acc1 + b1) * inv;
  } else {
    float m = -3.0e38f;
    for (int j = r0 + fl; j < r1; j += 32) {
      float e = as_[csr_src[j]] + ad;
      e = (e >= 0.f) ? e : 0.2f * e;
      m = fmaxf(m, e);
    }
    m = half_reduce_max(m);
    float ssum = 0.f;
    for (int j = r0; j < r1; ++j) {
      int src = csr_src[j];
      float e = as_[src] + ad;
      e = (e >= 0.f) ? e : 0.2f * e;
      float p = __expf(e - m);
      ssum += p;
      unsigned v = hp[(size_t)src * 32 + fl];
      acc0 = fmaf(p, __uint_as_float(v << 16), acc0);
      acc1 = fmaf(p, __uint_as_float(v & 0xffff0000u), acc1);
    }
    float inv2 = 1.f / (ssum + 1e-16f);
    acc0 *= inv2;
    acc1 *= inv2;
  }

  float2 bi = ((const float2*)bias)[fl];
  float o0 = fmaxf(acc0 + bi.x, 0.f);
  float o1 = fmaxf(acc1 + bi.y, 0.f);
  if (FINAL) {
    float2 wl = ((const float2*)Wlin)[fl];
    float rv = half_reduce_sum(o0 * wl.x + o1 * wl.y);
    if (valid && fl == 0) {
      float z = rv + blin[0];
      fout[n] = 1.f / (1.f + __expf(-z));
    }
  } else {
    if (valid) out[(size_t)n * 32 + fl] = (f2bf(o1) << 16) | f2bf(o0);
  }
}

extern "C" void kernel_launch(void* const* d_in, const int* in_sizes, int n_in,
                              void* d_out, int out_size, void* d_ws, size_t ws_size,
                              hipStream_t stream) {
  const float* x   = (const float*)d_in[0];
  const int*   ei  = (const int*)d_in[1];
  const float* W1  = (const float*)d_in[2];
  const float* a1s = (const float*)d_in[3];
  const float* a1d = (const float*)d_in[4];
  const float* b1  = (const float*)d_in[5];
  const float* W2  = (const float*)d_in[6];
  const float* a2s = (const float*)d_in[7];
  const float* a2d = (const float*)d_in[8];
  const float* b2  = (const float*)d_in[9];
  const float* W3  = (const float*)d_in[10];
  const float* a3s = (const float*)d_in[11];
  const float* a3d = (const float*)d_in[12];
  const float* b3  = (const float*)d_in[13];
  const float* Wl  = (const float*)d_in[14];
  const float* bl  = (const float*)d_in[15];

  const int N  = in_sizes[0] / 128;
  const int E  = in_sizes[1] / 2;
  const int EE = E + N;
  const int nbk = (N + 255) >> 8;

  char* p = (char*)d_ws;
  auto alloc = [&](size_t bytes) { char* r = p; p += (bytes + 255) & ~(size_t)255; return r; };
  unsigned* gbucket = (unsigned*)alloc((size_t)MAXBK * 4);
  unsigned* bbase   = (unsigned*)alloc((size_t)(MAXBK + 1) * 4);
  unsigned* bfill   = (unsigned*)alloc((size_t)MAXBK * 4);
  short8*   wf      = (short8*)alloc(2048 * 16);
  int*      rowptr  = (int*)alloc((size_t)(N + 1) * 4);
  int*      csr_src = (int*)alloc((size_t)EE * 4);
  unsigned* hbuf    = (unsigned*)alloc((size_t)N * 32 * 4);   // bf16-pair packed
  char*     regionA = alloc((size_t)EE * 8);                  // part[] then obuf
  float*    as_     = (float*)alloc((size_t)N * 4);
  float*    ad_     = (float*)alloc((size_t)N * 4);

  uint2*    part = (uint2*)regionA;            // CSR build scratch
  unsigned* obuf = (unsigned*)regionA;         // bf16-pair packed layer io

  hipMemsetAsync(gbucket, 0, (size_t)MAXBK * 4, stream);

  k_wprep<<<8, 256, 0, stream>>>(W1, W2, W3, wf);
  k_bhist<<<256, 256, 0, stream>>>(ei, gbucket, E, EE, nbk);
  k_bscan<<<1, 256, 0, stream>>>(gbucket, bbase, bfill, nbk, EE);
  k_part<<<(EE + PCHUNK - 1) / PCHUNK, 256, 0, stream>>>(ei, bfill, part, E, EE);
  k_bcsr<<<nbk, 256, 0, stream>>>(part, bbase, rowptr, csr_src, N, nbk);

  int gb = (N + 127) / 128;
  int nb = (N + 7) / 8;

  // layer 1 (f32 x input, K=128)
  k_gemm7<128, true><<<gb, 256, 0, stream>>>(x, wf, a1s, a1d, hbuf, as_, ad_, N);
  k_agg7<0><<<nb, 256, 0, stream>>>(rowptr, csr_src, hbuf, as_, ad_, b1, obuf,
                                    nullptr, nullptr, nullptr, N);
  // layer 2 (bf16 obuf input, K=64)
  k_gemm7<64, false><<<gb, 256, 0, stream>>>(obuf, wf + 16 * 64, a2s, a2d,
                                             hbuf, as_, ad_, N);
  k_agg7<0><<<nb, 256, 0, stream>>>(rowptr, csr_src, hbuf, as_, ad_, b2, obuf,
                                    nullptr, nullptr, nullptr, N);
  // layer 3 (+ fused readout)
  k_gemm7<64, false><<<gb, 256, 0, stream>>>(obuf, wf + 24 * 64, a3s, a3d,
                                             hbuf, as_, ad_, N);
  k_agg7<1><<<nb, 256, 0, stream>>>(rowptr, csr_src, hbuf, as_, ad_, b3, nullptr,
                                    Wl, bl, (float*)d_out, N);
}

// Round 11
// 256.484 us; speedup vs baseline: 6.6571x; 1.0337x over previous
//
#include <hip/hip_runtime.h>
#include <hip/hip_bf16.h>
#include <math.h>

#define BSH 8          // 256 nodes per bucket
#define MAXBK 512      // >= nbk = ceil(N/256)
#define PCHUNK 4096    // edges per k_part block

typedef __attribute__((ext_vector_type(8)))  short short8;
typedef __attribute__((ext_vector_type(16))) float f32x16;

__device__ __forceinline__ float half_reduce_max(float v) {
  #pragma unroll
  for (int off = 16; off; off >>= 1) v = fmaxf(v, __shfl_xor(v, off));
  return v;
}
__device__ __forceinline__ float half_reduce_sum(float v) {
  #pragma unroll
  for (int off = 16; off; off >>= 1) v += __shfl_xor(v, off);
  return v;
}

// round-to-nearest-even f32 -> bf16 (as unsigned)
__device__ __forceinline__ unsigned f2bf(float f) {
  unsigned u = __float_as_uint(f);
  return (u + 0x7fffu + ((u >> 16) & 1u)) >> 16;
}
__device__ __forceinline__ float bf_lo(unsigned u) { return __uint_as_float(u << 16); }
__device__ __forceinline__ float bf_hi(unsigned u) { return __uint_as_float(u & 0xffff0000u); }

// async global->LDS, 16 B per lane (global_load_lds_dwordx4)
__device__ __forceinline__ void async_copy16(const void* gsrc, void* ldst) {
  __builtin_amdgcn_global_load_lds(
      (const __attribute__((address_space(1))) void*)gsrc,
      (__attribute__((address_space(3))) void*)ldst, 16, 0, 0);
}

// exclusive scan of arr[0..n) (n multiple of 64, <= MAXBK) by wave 0 of block
__device__ __forceinline__ void wave0_excl_scan(unsigned* arr, unsigned* out, int n, int t) {
  if (t < 64) {
    unsigned carry = 0;
    for (int c = 0; c < n / 64; c++) {
      unsigned v = arr[c * 64 + t];
      unsigned s = v;
      #pragma unroll
      for (int off = 1; off < 64; off <<= 1) {
        unsigned u = __shfl_up(s, off);
        if ((t & 63) >= off) s += u;
      }
      out[c * 64 + t] = s - v + carry;
      carry += __shfl(s, 63);
    }
  }
}

// ---------------- radix-bucketed CSR build (no global data atomics) -------

__global__ __launch_bounds__(256) void k_bhist(const int* __restrict__ ei,
                                               unsigned* __restrict__ gbucket,
                                               int E, int EE, int nbk) {
  __shared__ unsigned hist[MAXBK];
  int t = threadIdx.x;
  for (int i = t; i < nbk; i += 256) hist[i] = 0;
  __syncthreads();
  for (int e = blockIdx.x * 256 + t; e < EE; e += gridDim.x * 256) {
    int d = (e < E) ? ei[E + e] : (e - E);
    atomicAdd(&hist[d >> BSH], 1u);
  }
  __syncthreads();
  for (int i = t; i < nbk; i += 256)
    if (hist[i]) atomicAdd(&gbucket[i], hist[i]);
}

__global__ __launch_bounds__(256) void k_bscan(const unsigned* __restrict__ gbucket,
                                               unsigned* __restrict__ bbase,
                                               unsigned* __restrict__ bfill,
                                               int nbk, int EE) {
  __shared__ unsigned arr[MAXBK], exc[MAXBK];
  int t = threadIdx.x;
  for (int i = t; i < MAXBK; i += 256) arr[i] = (i < nbk) ? gbucket[i] : 0u;
  __syncthreads();
  wave0_excl_scan(arr, exc, MAXBK, t);
  __syncthreads();
  for (int i = t; i < nbk; i += 256) { bbase[i] = exc[i]; bfill[i] = exc[i]; }
  if (t == 0) bbase[nbk] = (unsigned)EE;
}

__global__ __launch_bounds__(256) void k_part(const int* __restrict__ ei,
                                              unsigned* __restrict__ bfill,
                                              uint2* __restrict__ part,
                                              int E, int EE) {
  __shared__ uint2 stage[PCHUNK];
  __shared__ unsigned lcnt[MAXBK], lexcl[MAXBK], lbase[MAXBK];
  int t = threadIdx.x;
  int base = blockIdx.x * PCHUNK;
  int cnt = EE - base; if (cnt > PCHUNK) cnt = PCHUNK;
  for (int i = t; i < MAXBK; i += 256) lcnt[i] = 0;
  __syncthreads();

  uint2 ed[16]; unsigned loc[16];
  #pragma unroll
  for (int i = 0; i < 16; i++) {
    int e = base + i * 256 + t;
    if (e < EE) {
      int s, d;
      if (e < E) { s = ei[e]; d = ei[E + e]; } else { s = e - E; d = s; }
      ed[i] = make_uint2((unsigned)s, (unsigned)d);
      loc[i] = atomicAdd(&lcnt[(unsigned)d >> BSH], 1u);
    }
  }
  __syncthreads();
  wave0_excl_scan(lcnt, lexcl, MAXBK, t);
  __syncthreads();
  for (int i = t; i < MAXBK; i += 256) {
    unsigned c = lcnt[i];
    lbase[i] = c ? atomicAdd(&bfill[i], c) : 0u;
  }
  __syncthreads();
  #pragma unroll
  for (int i = 0; i < 16; i++) {
    int e = base + i * 256 + t;
    if (e < EE) stage[lexcl[ed[i].y >> BSH] + loc[i]] = ed[i];
  }
  __syncthreads();
  for (int i = t; i < cnt; i += 256) {
    uint2 v = stage[i];
    unsigned b = v.y >> BSH;
    part[lbase[b] + ((unsigned)i - lexcl[b])] = v;
  }
}

__global__ __launch_bounds__(256) void k_bcsr(const uint2* __restrict__ part,
                                              const unsigned* __restrict__ bbase,
                                              int* __restrict__ rowptr,
                                              int* __restrict__ csr_src,
                                              int Nn, int nbk) {
  __shared__ unsigned sdeg[256], sexcl[256], sfill[256];
  int t = threadIdx.x, b = blockIdx.x;
  int e0 = (int)bbase[b], e1 = (int)bbase[b + 1];
  sdeg[t] = 0; sfill[t] = 0;
  __syncthreads();
  for (int j = e0 + t; j < e1; j += 256)
    atomicAdd(&sdeg[part[j].y & 255u], 1u);
  __syncthreads();
  wave0_excl_scan(sdeg, sexcl, 256, t);
  __syncthreads();
  int node = (b << BSH) + t;
  if (node < Nn) rowptr[node] = e0 + (int)sexcl[t];
  if (b == nbk - 1 && t == 0) rowptr[Nn] = e1;
  for (int j = e0 + t; j < e1; j += 256) {
    uint2 v = part[j];
    unsigned dl = v.y & 255u;
    unsigned k = atomicAdd(&sfill[dl], 1u);
    csr_src[e0 + (int)sexcl[dl] + (int)k] = (int)v.x;
  }
}

// ---------------- W fragment prep (frag-ordered bf16 for MFMA A-operand) --

__global__ __launch_bounds__(256) void k_wprep(const float* __restrict__ W1,
                                               const float* __restrict__ W2,
                                               const float* __restrict__ W3,
                                               short8* __restrict__ wf) {
  int idx = blockIdx.x * 256 + threadIdx.x;
  if (idx >= 2048) return;
  int g = idx >> 6, l = idx & 63;
  const float* W; int s, t;
  if (g < 16)      { W = W1; s = g >> 1;        t = g & 1; }
  else if (g < 24) { W = W2; s = (g - 16) >> 1; t = g & 1; }
  else             { W = W3; s = (g - 24) >> 1; t = g & 1; }
  int of = t * 32 + (l & 31);
  int k0 = s * 16 + (l >> 5) * 8;
  short8 v;
  #pragma unroll
  for (int e = 0; e < 8; e++) v[e] = (short)f2bf(W[(k0 + e) * 64 + of]);
  wf[idx] = v;
}

// ---------------- MFMA GEMM: h = x@W + fused alpha reductions -------------

template <int K, bool F32IN>
__global__ __launch_bounds__(256) void k_gemm7(
    const void* __restrict__ xin, const short8* __restrict__ wf,
    const float* __restrict__ avs, const float* __restrict__ avd,
    unsigned* __restrict__ h, float* __restrict__ as_out,
    float* __restrict__ ad_out, int Nn) {
  constexpr int NS = K / 16;                 // k-steps
  constexpr int RB = F32IN ? K * 4 : K * 2;  // row bytes
  constexpr int RSH = F32IN ? (K == 128 ? 9 : 8) : (K == 128 ? 8 : 7);
  __shared__ __align__(16) char xs_raw[128 * RB];
  int t = threadIdx.x, lane = t & 63, wid = t >> 6;
  int l31 = lane & 31, hi = lane >> 5;

  short8 wa[NS * 2];
  #pragma unroll
  for (int i = 0; i < NS * 2; i++) wa[i] = wf[i * 64 + lane];

  int tile0 = blockIdx.x * 128;
  const char* xg = (const char*)xin;
  constexpr int CH = (128 * RB) / (256 * 16);
  #pragma unroll
  for (int i = 0; i < CH; i++) {
    int off = (i * 256 + t) * 16;
    int row = off >> RSH;
    int inrow = off & (RB - 1);
    long grow = (long)tile0 + row;
    if (grow > (long)Nn - 1) grow = Nn - 1;   // tail clamp (outputs guarded)
    async_copy16(xg + grow * RB + (inrow ^ ((row & 7) << 4)), xs_raw + off);
  }
  __syncthreads();

  f32x16 acc0 = {0,0,0,0,0,0,0,0,0,0,0,0,0,0,0,0};
  f32x16 acc1 = {0,0,0,0,0,0,0,0,0,0,0,0,0,0,0,0};
  int rowl = wid * 32 + l31;
  int swz = (rowl & 7) << 4;

  #pragma unroll
  for (int s = 0; s < NS; s++) {
    short8 bf;
    if constexpr (F32IN) {
      int ph = (rowl * RB + s * 64 + hi * 32) ^ swz;
      float4 fA = *(const float4*)(xs_raw + ph);
      float4 fB = *(const float4*)(xs_raw + (ph ^ 16));
      bf[0] = (short)f2bf(fA.x); bf[1] = (short)f2bf(fA.y);
      bf[2] = (short)f2bf(fA.z); bf[3] = (short)f2bf(fA.w);
      bf[4] = (short)f2bf(fB.x); bf[5] = (short)f2bf(fB.y);
      bf[6] = (short)f2bf(fB.z); bf[7] = (short)f2bf(fB.w);
    } else {
      int ph = (rowl * RB + s * 32 + hi * 16) ^ swz;
      bf = *(const short8*)(xs_raw + ph);
    }
    acc0 = __builtin_amdgcn_mfma_f32_32x32x16_bf16(wa[2 * s], bf, acc0, 0, 0, 0);
    acc1 = __builtin_amdgcn_mfma_f32_32x32x16_bf16(wa[2 * s + 1], bf, acc1, 0, 0, 0);
  }

  int xrow = tile0 + rowl;
  bool ok = xrow < Nn;
  float asp = 0.f, adp = 0.f;
  #pragma unroll
  for (int r = 0; r < 16; r += 2) {
    int rof = (r & 3) + 8 * (r >> 2);     // D row mapping (m74-verified)
    int of0 = rof + 4 * hi;
    if (ok) {
      h[(size_t)xrow * 32 + (of0 >> 1)] =
          (f2bf(acc0[r + 1]) << 16) | f2bf(acc0[r]);
      h[(size_t)xrow * 32 + 16 + (of0 >> 1)] =
          (f2bf(acc1[r + 1]) << 16) | f2bf(acc1[r]);
    }
    asp += acc0[r] * avs[of0] + acc0[r + 1] * avs[of0 + 1]
         + acc1[r] * avs[of0 + 32] + acc1[r + 1] * avs[of0 + 33];
    adp += acc0[r] * avd[of0] + acc0[r + 1] * avd[of0 + 1]
         + acc1[r] * avd[of0 + 32] + acc1[r + 1] * avd[of0 + 33];
  }
  asp += __shfl_xor(asp, 32);
  adp += __shfl_xor(adp, 32);
  if (ok && hi == 0) { as_out[xrow] = asp; ad_out[xrow] = adp; }
}

// ---------------- per-dst-node softmax aggregation ----------------
// Half-wave per node. Phase B: uint2 loads — 16 lanes cover one edge row, so
// one instruction gathers TWO edges (sub = fl>>4 edge parity, q = fl&15).
// Lane accumulates features 4q..4q+3; parities combined via shfl_xor(16).

template <int FINAL>
__global__ __launch_bounds__(256) void k_agg8(
    const int* __restrict__ rowptr, const int* __restrict__ csr_src,
    const unsigned* __restrict__ hp, const float* __restrict__ as_,
    const float* __restrict__ ad_, const float* __restrict__ bias,
    unsigned* __restrict__ out, const float* __restrict__ Wlin,
    const float* __restrict__ blin, float* __restrict__ fout, int Nn) {
  __shared__ float2 psbuf[4][2][32];
  int t = threadIdx.x, lane = t & 63, wid = t >> 6;
  int fl = lane & 31, hh = lane >> 5;
  int n = blockIdx.x * 8 + wid * 2 + hh;
  bool valid = n < Nn;
  int nn = valid ? n : (Nn - 1);
  int r0 = rowptr[nn], r1 = rowptr[nn + 1];
  int deg = valid ? (r1 - r0) : 0;
  float ad = ad_[nn];

  if (deg <= 32) {
    // phase A: edge-parallel scores + softmax (32 lanes)
    int src = (fl < deg) ? csr_src[r0 + fl] : 0;
    float e = (fl < deg) ? (as_[src] + ad) : -3.0e38f;
    e = (e >= 0.f) ? e : 0.2f * e;
    float m = half_reduce_max(e);
    float p = (fl < deg) ? __expf(e - m) : 0.f;
    float inv = 1.f / (half_reduce_sum(p) + 1e-16f);
    psbuf[wid][hh][fl] = make_float2(p, __uint_as_float((unsigned)src * 128u));

    // phase B: 4 edges per iteration, 2 uint2 gathers in flight
    int sub = fl >> 4, q = fl & 15;
    const char* hq = (const char*)hp + q * 8;
    float a0 = 0.f, a1 = 0.f, a2 = 0.f, a3 = 0.f;
    float b0 = 0.f, b1 = 0.f, b2 = 0.f, b3 = 0.f;
    for (int jj = 0; jj < deg; jj += 4) {
      float2 ps0 = psbuf[wid][hh][jj + sub];
      float2 ps1 = psbuf[wid][hh][jj + 2 + sub];
      uint2 v0 = *(const uint2*)(hq + __float_as_uint(ps0.y));
      uint2 v1 = *(const uint2*)(hq + __float_as_uint(ps1.y));
      a0 = fmaf(ps0.x, bf_lo(v0.x), a0);
      a1 = fmaf(ps0.x, bf_hi(v0.x), a1);
      a2 = fmaf(ps0.x, bf_lo(v0.y), a2);
      a3 = fmaf(ps0.x, bf_hi(v0.y), a3);
      b0 = fmaf(ps1.x, bf_lo(v1.x), b0);
      b1 = fmaf(ps1.x, bf_hi(v1.x), b1);
      b2 = fmaf(ps1.x, bf_lo(v1.y), b2);
      b3 = fmaf(ps1.x, bf_hi(v1.y), b3);
    }
    a0 += b0; a1 += b1; a2 += b2; a3 += b3;
    a0 += __shfl_xor(a0, 16);              // combine edge parities
    a1 += __shfl_xor(a1, 16);
    a2 += __shfl_xor(a2, 16);
    a3 += __shfl_xor(a3, 16);

    float4 bi = ((const float4*)bias)[q];
    float o0 = fmaxf(fmaf(a0, inv, bi.x), 0.f);
    float o1 = fmaxf(fmaf(a1, inv, bi.y), 0.f);
    float o2 = fmaxf(fmaf(a2, inv, bi.z), 0.f);
    float o3 = fmaxf(fmaf(a3, inv, bi.w), 0.f);
    if (FINAL) {
      float4 wl = ((const float4*)Wlin)[q];
      float rv = (sub == 0) ? (o0 * wl.x + o1 * wl.y + o2 * wl.z + o3 * wl.w) : 0.f;
      rv = half_reduce_sum(rv);
      if (valid && fl == 0) {
        float z = rv + blin[0];
        fout[n] = 1.f / (1.f + __expf(-z));
      }
    } else if (valid && sub == 0) {
      uint2 pk;
      pk.x = (f2bf(o1) << 16) | f2bf(o0);
      pk.y = (f2bf(o3) << 16) | f2bf(o2);
      *(uint2*)(out + (size_t)n * 32 + 2 * q) = pk;
    }
  } else {
    // rare fallback (deg > 32): two-pass, serial recompute; old layout
    float acc0 = 0.f, acc1 = 0.f;
    float m = -3.0e38f;
    for (int j = r0 + fl; j < r1; j += 32) {
      float e = as_[csr_src[j]] + ad;
      e = (e >= 0.f) ? e : 0.2f * e;
      m = fmaxf(m, e);
    }
    m = half_reduce_max(m);
    float ssum = 0.f;
    for (int j = r0; j < r1; ++j) {
      int src = csr_src[j];
      float e = as_[src] + ad;
      e = (e >= 0.f) ? e : 0.2f * e;
      float p = __expf(e - m);
      ssum += p;
      unsigned v = hp[(size_t)src * 32 + fl];
      acc0 = fmaf(p, bf_lo(v), acc0);
      acc1 = fmaf(p, bf_hi(v), acc1);
    }
    float inv2 = 1.f / (ssum + 1e-16f);
    acc0 *= inv2;
    acc1 *= inv2;
    float2 bi = ((const float2*)bias)[fl];
    float o0 = fmaxf(acc0 + bi.x, 0.f);
    float o1 = fmaxf(acc1 + bi.y, 0.f);
    if (FINAL) {
      float2 wl = ((const float2*)Wlin)[fl];
      float rv = half_reduce_sum(o0 * wl.x + o1 * wl.y);
      if (valid && fl == 0) {
        float z = rv + blin[0];
        fout[n] = 1.f / (1.f + __expf(-z));
      }
    } else {
      if (valid) out[(size_t)n * 32 + fl] = (f2bf(o1) << 16) | f2bf(o0);
    }
  }
}

extern "C" void kernel_launch(void* const* d_in, const int* in_sizes, int n_in,
                              void* d_out, int out_size, void* d_ws, size_t ws_size,
                              hipStream_t stream) {
  const float* x   = (const float*)d_in[0];
  const int*   ei  = (const int*)d_in[1];
  const float* W1  = (const float*)d_in[2];
  const float* a1s = (const float*)d_in[3];
  const float* a1d = (const float*)d_in[4];
  const float* b1  = (const float*)d_in[5];
  const float* W2  = (const float*)d_in[6];
  const float* a2s = (const float*)d_in[7];
  const float* a2d = (const float*)d_in[8];
  const float* b2  = (const float*)d_in[9];
  const float* W3  = (const float*)d_in[10];
  const float* a3s = (const float*)d_in[11];
  const float* a3d = (const float*)d_in[12];
  const float* b3  = (const float*)d_in[13];
  const float* Wl  = (const float*)d_in[14];
  const float* bl  = (const float*)d_in[15];

  const int N  = in_sizes[0] / 128;
  const int E  = in_sizes[1] / 2;
  const int EE = E + N;
  const int nbk = (N + 255) >> 8;

  char* p = (char*)d_ws;
  auto alloc = [&](size_t bytes) { char* r = p; p += (bytes + 255) & ~(size_t)255; return r; };
  unsigned* gbucket = (unsigned*)alloc((size_t)MAXBK * 4);
  unsigned* bbase   = (unsigned*)alloc((size_t)(MAXBK + 1) * 4);
  unsigned* bfill   = (unsigned*)alloc((size_t)MAXBK * 4);
  short8*   wf      = (short8*)alloc(2048 * 16);
  int*      rowptr  = (int*)alloc((size_t)(N + 1) * 4);
  int*      csr_src = (int*)alloc((size_t)EE * 4);
  unsigned* hbuf    = (unsigned*)alloc((size_t)N * 32 * 4);   // bf16-pair packed
  char*     regionA = alloc((size_t)EE * 8);                  // part[] then obuf
  float*    as_     = (float*)alloc((size_t)N * 4);
  float*    ad_     = (float*)alloc((size_t)N * 4);

  uint2*    part = (uint2*)regionA;            // CSR build scratch
  unsigned* obuf = (unsigned*)regionA;         // bf16-pair packed layer io

  hipMemsetAsync(gbucket, 0, (size_t)MAXBK * 4, stream);

  k_wprep<<<8, 256, 0, stream>>>(W1, W2, W3, wf);
  k_bhist<<<256, 256, 0, stream>>>(ei, gbucket, E, EE, nbk);
  k_bscan<<<1, 256, 0, stream>>>(gbucket, bbase, bfill, nbk, EE);
  k_part<<<(EE + PCHUNK - 1) / PCHUNK, 256, 0, stream>>>(ei, bfill, part, E, EE);
  k_bcsr<<<nbk, 256, 0, stream>>>(part, bbase, rowptr, csr_src, N, nbk);

  int gb = (N + 127) / 128;
  int nb = (N + 7) / 8;

  // layer 1 (f32 x input, K=128)
  k_gemm7<128, true><<<gb, 256, 0, stream>>>(x, wf, a1s, a1d, hbuf, as_, ad_, N);
  k_agg8<0><<<nb, 256, 0, stream>>>(rowptr, csr_src, hbuf, as_, ad_, b1, obuf,
                                    nullptr, nullptr, nullptr, N);
  // layer 2 (bf16 obuf input, K=64)
  k_gemm7<64, false><<<gb, 256, 0, stream>>>(obuf, wf + 16 * 64, a2s, a2d,
                                             hbuf, as_, ad_, N);
  k_agg8<0><<<nb, 256, 0, stream>>>(rowptr, csr_src, hbuf, as_, ad_, b2, obuf,
                                    nullptr, nullptr, nullptr, N);
  // layer 3 (+ fused readout)
  k_gemm7<64, false><<<gb, 256, 0, stream>>>(obuf, wf + 24 * 64, a3s, a3d,
                                             hbuf, as_, ad_, N);
  k_agg8<1><<<nb, 256, 0, stream>>>(rowptr, csr_src, hbuf, as_, ad_, b3, nullptr,
                                    Wl, bl, (float*)d_out, N);
}

// Round 12
// 252.366 us; speedup vs baseline: 6.7657x; 1.0163x over previous
//
#include <hip/hip_runtime.h>
#include <hip/hip_bf16.h>
#include <math.h>

#define BSH 8          // 256 nodes per bucket
#define MAXBK 512      // >= nbk = ceil(N/256)
#define PCHUNK 4096    // edges per k_part block
#define BCSR_CAP 6144  // LDS-staged edges per bucket (48 KB)

typedef __attribute__((ext_vector_type(8)))  short short8;
typedef __attribute__((ext_vector_type(16))) float f32x16;

__device__ __forceinline__ float half_reduce_max(float v) {
  #pragma unroll
  for (int off = 16; off; off >>= 1) v = fmaxf(v, __shfl_xor(v, off));
  return v;
}
__device__ __forceinline__ float half_reduce_sum(float v) {
  #pragma unroll
  for (int off = 16; off; off >>= 1) v += __shfl_xor(v, off);
  return v;
}

// round-to-nearest-even f32 -> bf16 (as unsigned)
__device__ __forceinline__ unsigned f2bf(float f) {
  unsigned u = __float_as_uint(f);
  return (u + 0x7fffu + ((u >> 16) & 1u)) >> 16;
}
__device__ __forceinline__ float bf_lo(unsigned u) { return __uint_as_float(u << 16); }
__device__ __forceinline__ float bf_hi(unsigned u) { return __uint_as_float(u & 0xffff0000u); }

// async global->LDS, 16 B per lane (global_load_lds_dwordx4)
__device__ __forceinline__ void async_copy16(const void* gsrc, void* ldst) {
  __builtin_amdgcn_global_load_lds(
      (const __attribute__((address_space(1))) void*)gsrc,
      (__attribute__((address_space(3))) void*)ldst, 16, 0, 0);
}

// exclusive scan of arr[0..n) (n multiple of 64, <= MAXBK) by wave 0 of block
__device__ __forceinline__ void wave0_excl_scan(unsigned* arr, unsigned* out, int n, int t) {
  if (t < 64) {
    unsigned carry = 0;
    for (int c = 0; c < n / 64; c++) {
      unsigned v = arr[c * 64 + t];
      unsigned s = v;
      #pragma unroll
      for (int off = 1; off < 64; off <<= 1) {
        unsigned u = __shfl_up(s, off);
        if ((t & 63) >= off) s += u;
      }
      out[c * 64 + t] = s - v + carry;
      carry += __shfl(s, 63);
    }
  }
}

// ---------------- radix-bucketed CSR build (no global data atomics) -------

__global__ __launch_bounds__(256) void k_bhist(const int* __restrict__ ei,
                                               unsigned* __restrict__ gbucket,
                                               int E, int nbk) {
  __shared__ unsigned hist[MAXBK];
  int t = threadIdx.x;
  for (int i = t; i < nbk; i += 256) hist[i] = 0;
  __syncthreads();
  const int4* d4 = (const int4*)(ei + E);
  int nd4 = E >> 2;
  for (int i = blockIdx.x * 256 + t; i < nd4; i += gridDim.x * 256) {
    int4 d = d4[i];
    atomicAdd(&hist[d.x >> BSH], 1u);
    atomicAdd(&hist[d.y >> BSH], 1u);
    atomicAdd(&hist[d.z >> BSH], 1u);
    atomicAdd(&hist[d.w >> BSH], 1u);
  }
  if (blockIdx.x == 0) {
    for (int e = (nd4 << 2) + t; e < E; e += 256)
      atomicAdd(&hist[ei[E + e] >> BSH], 1u);
  }
  __syncthreads();
  for (int i = t; i < nbk; i += 256)
    if (hist[i]) atomicAdd(&gbucket[i], hist[i]);
}

// self-loop counts are analytic: bucket b holds min(256, N-256b) self loops
__global__ __launch_bounds__(256) void k_bscan(const unsigned* __restrict__ gbucket,
                                               unsigned* __restrict__ bbase,
                                               unsigned* __restrict__ bfill,
                                               int nbk, int EE, int Nn) {
  __shared__ unsigned arr[MAXBK], exc[MAXBK];
  int t = threadIdx.x;
  for (int i = t; i < MAXBK; i += 256) {
    unsigned v = 0;
    if (i < nbk) {
      int rem = Nn - (i << BSH);
      unsigned sl = rem >= 256 ? 256u : (unsigned)(rem > 0 ? rem : 0);
      v = gbucket[i] + sl;
    }
    arr[i] = v;
  }
  __syncthreads();
  wave0_excl_scan(arr, exc, MAXBK, t);
  __syncthreads();
  for (int i = t; i < nbk; i += 256) { bbase[i] = exc[i]; bfill[i] = exc[i]; }
  if (t == 0) bbase[nbk] = (unsigned)EE;
}

__global__ __launch_bounds__(256) void k_part(const int* __restrict__ ei,
                                              unsigned* __restrict__ bfill,
                                              uint2* __restrict__ part,
                                              int E, int EE) {
  __shared__ uint2 stage[PCHUNK];
  __shared__ unsigned lcnt[MAXBK], lexcl[MAXBK], lbase[MAXBK];
  int t = threadIdx.x;
  int base = blockIdx.x * PCHUNK;
  int cnt = EE - base; if (cnt > PCHUNK) cnt = PCHUNK;
  for (int i = t; i < MAXBK; i += 256) lcnt[i] = 0;
  __syncthreads();

  uint2 ed[16]; unsigned loc[16];
  #pragma unroll
  for (int i = 0; i < 16; i++) {
    int e = base + i * 256 + t;
    if (e < EE) {
      int s, d;
      if (e < E) { s = ei[e]; d = ei[E + e]; } else { s = e - E; d = s; }
      ed[i] = make_uint2((unsigned)s, (unsigned)d);
      loc[i] = atomicAdd(&lcnt[(unsigned)d >> BSH], 1u);
    }
  }
  __syncthreads();
  wave0_excl_scan(lcnt, lexcl, MAXBK, t);
  __syncthreads();
  for (int i = t; i < MAXBK; i += 256) {
    unsigned c = lcnt[i];
    lbase[i] = c ? atomicAdd(&bfill[i], c) : 0u;
  }
  __syncthreads();
  #pragma unroll
  for (int i = 0; i < 16; i++) {
    int e = base + i * 256 + t;
    if (e < EE) stage[lexcl[ed[i].y >> BSH] + loc[i]] = ed[i];
  }
  __syncthreads();
  for (int i = t; i < cnt; i += 256) {
    uint2 v = stage[i];
    unsigned b = v.y >> BSH;
    part[lbase[b] + ((unsigned)i - lexcl[b])] = v;
  }
}

__global__ __launch_bounds__(256) void k_bcsr(const uint2* __restrict__ part,
                                              const unsigned* __restrict__ bbase,
                                              int* __restrict__ rowptr,
                                              int* __restrict__ csr_src,
                                              int Nn, int nbk) {
  __shared__ unsigned sdeg[256], sexcl[256], sfill[256];
  __shared__ uint2 epart[BCSR_CAP];
  int t = threadIdx.x, b = blockIdx.x;
  int e0 = (int)bbase[b], e1 = (int)bbase[b + 1];
  int cnt = e1 - e0;
  bool fits = cnt <= BCSR_CAP;
  sdeg[t] = 0; sfill[t] = 0;
  __syncthreads();
  if (fits) {
    for (int j = t; j < cnt; j += 256) {
      uint2 v = part[e0 + j];
      epart[j] = v;
      atomicAdd(&sdeg[v.y & 255u], 1u);
    }
  } else {
    for (int j = e0 + t; j < e1; j += 256)
      atomicAdd(&sdeg[part[j].y & 255u], 1u);
  }
  __syncthreads();
  wave0_excl_scan(sdeg, sexcl, 256, t);
  __syncthreads();
  int node = (b << BSH) + t;
  if (node < Nn) rowptr[node] = e0 + (int)sexcl[t];
  if (b == nbk - 1 && t == 0) rowptr[Nn] = e1;
  if (fits) {
    for (int j = t; j < cnt; j += 256) {
      uint2 v = epart[j];
      unsigned dl = v.y & 255u;
      unsigned k = atomicAdd(&sfill[dl], 1u);
      csr_src[e0 + (int)sexcl[dl] + (int)k] = (int)v.x;
    }
  } else {
    for (int j = e0 + t; j < e1; j += 256) {
      uint2 v = part[j];
      unsigned dl = v.y & 255u;
      unsigned k = atomicAdd(&sfill[dl], 1u);
      csr_src[e0 + (int)sexcl[dl] + (int)k] = (int)v.x;
    }
  }
}

// ---------------- W fragment prep (frag-ordered bf16 for MFMA A-operand) --

__global__ __launch_bounds__(256) void k_wprep(const float* __restrict__ W1,
                                               const float* __restrict__ W2,
                                               const float* __restrict__ W3,
                                               short8* __restrict__ wf) {
  int idx = blockIdx.x * 256 + threadIdx.x;
  if (idx >= 2048) return;
  int g = idx >> 6, l = idx & 63;
  const float* W; int s, t;
  if (g < 16)      { W = W1; s = g >> 1;        t = g & 1; }
  else if (g < 24) { W = W2; s = (g - 16) >> 1; t = g & 1; }
  else             { W = W3; s = (g - 24) >> 1; t = g & 1; }
  int of = t * 32 + (l & 31);
  int k0 = s * 16 + (l >> 5) * 8;
  short8 v;
  #pragma unroll
  for (int e = 0; e < 8; e++) v[e] = (short)f2bf(W[(k0 + e) * 64 + of]);
  wf[idx] = v;
}

// ---------------- MFMA GEMM: h = x@W + fused alpha reductions -------------

template <int K, bool F32IN>
__global__ __launch_bounds__(256) void k_gemm7(
    const void* __restrict__ xin, const short8* __restrict__ wf,
    const float* __restrict__ avs, const float* __restrict__ avd,
    unsigned* __restrict__ h, float* __restrict__ as_out,
    float* __restrict__ ad_out, int Nn) {
  constexpr int NS = K / 16;                 // k-steps
  constexpr int RB = F32IN ? K * 4 : K * 2;  // row bytes
  constexpr int RSH = F32IN ? (K == 128 ? 9 : 8) : (K == 128 ? 8 : 7);
  __shared__ __align__(16) char xs_raw[128 * RB];
  int t = threadIdx.x, lane = t & 63, wid = t >> 6;
  int l31 = lane & 31, hi = lane >> 5;

  short8 wa[NS * 2];
  #pragma unroll
  for (int i = 0; i < NS * 2; i++) wa[i] = wf[i * 64 + lane];

  int tile0 = blockIdx.x * 128;
  const char* xg = (const char*)xin;
  constexpr int CH = (128 * RB) / (256 * 16);
  #pragma unroll
  for (int i = 0; i < CH; i++) {
    int off = (i * 256 + t) * 16;
    int row = off >> RSH;
    int inrow = off & (RB - 1);
    long grow = (long)tile0 + row;
    if (grow > (long)Nn - 1) grow = Nn - 1;   // tail clamp (outputs guarded)
    async_copy16(xg + grow * RB + (inrow ^ ((row & 7) << 4)), xs_raw + off);
  }
  __syncthreads();

  f32x16 acc0 = {0,0,0,0,0,0,0,0,0,0,0,0,0,0,0,0};
  f32x16 acc1 = {0,0,0,0,0,0,0,0,0,0,0,0,0,0,0,0};
  int rowl = wid * 32 + l31;
  int swz = (rowl & 7) << 4;

  #pragma unroll
  for (int s = 0; s < NS; s++) {
    short8 bf;
    if constexpr (F32IN) {
      int ph = (rowl * RB + s * 64 + hi * 32) ^ swz;
      float4 fA = *(const float4*)(xs_raw + ph);
      float4 fB = *(const float4*)(xs_raw + (ph ^ 16));
      bf[0] = (short)f2bf(fA.x); bf[1] = (short)f2bf(fA.y);
      bf[2] = (short)f2bf(fA.z); bf[3] = (short)f2bf(fA.w);
      bf[4] = (short)f2bf(fB.x); bf[5] = (short)f2bf(fB.y);
      bf[6] = (short)f2bf(fB.z); bf[7] = (short)f2bf(fB.w);
    } else {
      int ph = (rowl * RB + s * 32 + hi * 16) ^ swz;
      bf = *(const short8*)(xs_raw + ph);
    }
    acc0 = __builtin_amdgcn_mfma_f32_32x32x16_bf16(wa[2 * s], bf, acc0, 0, 0, 0);
    acc1 = __builtin_amdgcn_mfma_f32_32x32x16_bf16(wa[2 * s + 1], bf, acc1, 0, 0, 0);
  }

  int xrow = tile0 + rowl;
  bool ok = xrow < Nn;
  float asp = 0.f, adp = 0.f;
  #pragma unroll
  for (int r = 0; r < 16; r += 2) {
    int rof = (r & 3) + 8 * (r >> 2);     // D row mapping (m74-verified)
    int of0 = rof + 4 * hi;
    if (ok) {
      h[(size_t)xrow * 32 + (of0 >> 1)] =
          (f2bf(acc0[r + 1]) << 16) | f2bf(acc0[r]);
      h[(size_t)xrow * 32 + 16 + (of0 >> 1)] =
          (f2bf(acc1[r + 1]) << 16) | f2bf(acc1[r]);
    }
    asp += acc0[r] * avs[of0] + acc0[r + 1] * avs[of0 + 1]
         + acc1[r] * avs[of0 + 32] + acc1[r + 1] * avs[of0 + 33];
    adp += acc0[r] * avd[of0] + acc0[r + 1] * avd[of0 + 1]
         + acc1[r] * avd[of0 + 32] + acc1[r + 1] * avd[of0 + 33];
  }
  asp += __shfl_xor(asp, 32);
  adp += __shfl_xor(adp, 32);
  if (ok && hi == 0) { as_out[xrow] = asp; ad_out[xrow] = adp; }
}

// ---------------- per-dst-node softmax aggregation ----------------
// Half-wave per node; uint2 phase-B gathers (2 edges/instr) with an explicit
// 1-deep software pipeline: next iteration's psbuf reads + gathers issue
// before current iteration's FMAs consume (doubles loads in flight).

template <int FINAL>
__global__ __launch_bounds__(256) void k_agg9(
    const int* __restrict__ rowptr, const int* __restrict__ csr_src,
    const unsigned* __restrict__ hp, const float* __restrict__ as_,
    const float* __restrict__ ad_, const float* __restrict__ bias,
    unsigned* __restrict__ out, const float* __restrict__ Wlin,
    const float* __restrict__ blin, float* __restrict__ fout, int Nn) {
  __shared__ float2 psbuf[4][2][32];
  int t = threadIdx.x, lane = t & 63, wid = t >> 6;
  int fl = lane & 31, hh = lane >> 5;
  int n = blockIdx.x * 8 + wid * 2 + hh;
  bool valid = n < Nn;
  int nn = valid ? n : (Nn - 1);
  int r0 = rowptr[nn], r1 = rowptr[nn + 1];
  int deg = valid ? (r1 - r0) : 0;
  float ad = ad_[nn];

  if (deg <= 32) {
    // phase A: edge-parallel scores + softmax (32 lanes)
    int src = (fl < deg) ? csr_src[r0 + fl] : 0;
    float e = (fl < deg) ? (as_[src] + ad) : -3.0e38f;
    e = (e >= 0.f) ? e : 0.2f * e;
    float m = half_reduce_max(e);
    float p = (fl < deg) ? __expf(e - m) : 0.f;
    float inv = 1.f / (half_reduce_sum(p) + 1e-16f);
    psbuf[wid][hh][fl] = make_float2(p, __uint_as_float((unsigned)src * 128u));

    // phase B: 4 edges/iter, 1-deep software pipeline
    int sub = fl >> 4, q = fl & 15;
    const char* hq = (const char*)hp + q * 8;
    const float2* psb = psbuf[wid][hh];
    float a0 = 0.f, a1 = 0.f, a2 = 0.f, a3 = 0.f;
    float b0 = 0.f, b1 = 0.f, b2 = 0.f, b3 = 0.f;

    float2 ps0 = psb[sub];
    float2 ps1 = psb[2 + sub];
    uint2 v0 = *(const uint2*)(hq + __float_as_uint(ps0.y));
    uint2 v1 = *(const uint2*)(hq + __float_as_uint(ps1.y));
    for (int jj = 4; jj < deg; jj += 4) {
      float2 nps0 = psb[jj + sub];
      float2 nps1 = psb[jj + 2 + sub];
      uint2 nv0 = *(const uint2*)(hq + __float_as_uint(nps0.y));
      uint2 nv1 = *(const uint2*)(hq + __float_as_uint(nps1.y));
      a0 = fmaf(ps0.x, bf_lo(v0.x), a0);
      a1 = fmaf(ps0.x, bf_hi(v0.x), a1);
      a2 = fmaf(ps0.x, bf_lo(v0.y), a2);
      a3 = fmaf(ps0.x, bf_hi(v0.y), a3);
      b0 = fmaf(ps1.x, bf_lo(v1.x), b0);
      b1 = fmaf(ps1.x, bf_hi(v1.x), b1);
      b2 = fmaf(ps1.x, bf_lo(v1.y), b2);
      b3 = fmaf(ps1.x, bf_hi(v1.y), b3);
      ps0 = nps0; ps1 = nps1; v0 = nv0; v1 = nv1;
    }
    a0 = fmaf(ps0.x, bf_lo(v0.x), a0);
    a1 = fmaf(ps0.x, bf_hi(v0.x), a1);
    a2 = fmaf(ps0.x, bf_lo(v0.y), a2);
    a3 = fmaf(ps0.x, bf_hi(v0.y), a3);
    b0 = fmaf(ps1.x, bf_lo(v1.x), b0);
    b1 = fmaf(ps1.x, bf_hi(v1.x), b1);
    b2 = fmaf(ps1.x, bf_lo(v1.y), b2);
    b3 = fmaf(ps1.x, bf_hi(v1.y), b3);

    a0 += b0; a1 += b1; a2 += b2; a3 += b3;
    a0 += __shfl_xor(a0, 16);              // combine edge parities
    a1 += __shfl_xor(a1, 16);
    a2 += __shfl_xor(a2, 16);
    a3 += __shfl_xor(a3, 16);

    float4 bi = ((const float4*)bias)[q];
    float o0 = fmaxf(fmaf(a0, inv, bi.x), 0.f);
    float o1 = fmaxf(fmaf(a1, inv, bi.y), 0.f);
    float o2 = fmaxf(fmaf(a2, inv, bi.z), 0.f);
    float o3 = fmaxf(fmaf(a3, inv, bi.w), 0.f);
    if (FINAL) {
      float4 wl = ((const float4*)Wlin)[q];
      float rv = (sub == 0) ? (o0 * wl.x + o1 * wl.y + o2 * wl.z + o3 * wl.w) : 0.f;
      rv = half_reduce_sum(rv);
      if (valid && fl == 0) {
        float z = rv + blin[0];
        fout[n] = 1.f / (1.f + __expf(-z));
      }
    } else if (valid && sub == 0) {
      uint2 pk;
      pk.x = (f2bf(o1) << 16) | f2bf(o0);
      pk.y = (f2bf(o3) << 16) | f2bf(o2);
      *(uint2*)(out + (size_t)n * 32 + 2 * q) = pk;
    }
  } else {
    // rare fallback (deg > 32): two-pass, serial recompute
    float acc0 = 0.f, acc1 = 0.f;
    float m = -3.0e38f;
    for (int j = r0 + fl; j < r1; j += 32) {
      float e = as_[csr_src[j]] + ad;
      e = (e >= 0.f) ? e : 0.2f * e;
      m = fmaxf(m, e);
    }
    m = half_reduce_max(m);
    float ssum = 0.f;
    for (int j = r0; j < r1; ++j) {
      int src = csr_src[j];
      float e = as_[src] + ad;
      e = (e >= 0.f) ? e : 0.2f * e;
      float p = __expf(e - m);
      ssum += p;
      unsigned v = hp[(size_t)src * 32 + fl];
      acc0 = fmaf(p, bf_lo(v), acc0);
      acc1 = fmaf(p, bf_hi(v), acc1);
    }
    float inv2 = 1.f / (ssum + 1e-16f);
    acc0 *= inv2;
    acc1 *= inv2;
    float2 bi = ((const float2*)bias)[fl];
    float o0 = fmaxf(acc0 + bi.x, 0.f);
    float o1 = fmaxf(acc1 + bi.y, 0.f);
    if (FINAL) {
      float2 wl = ((const float2*)Wlin)[fl];
      float rv = half_reduce_sum(o0 * wl.x + o1 * wl.y);
      if (valid && fl == 0) {
        float z = rv + blin[0];
        fout[n] = 1.f / (1.f + __expf(-z));
      }
    } else {
      if (valid) out[(size_t)n * 32 + fl] = (f2bf(o1) << 16) | f2bf(o0);
    }
  }
}

extern "C" void kernel_launch(void* const* d_in, const int* in_sizes, int n_in,
                              void* d_out, int out_size, void* d_ws, size_t ws_size,
                              hipStream_t stream) {
  const float* x   = (const float*)d_in[0];
  const int*   ei  = (const int*)d_in[1];
  const float* W1  = (const float*)d_in[2];
  const float* a1s = (const float*)d_in[3];
  const float* a1d = (const float*)d_in[4];
  const float* b1  = (const float*)d_in[5];
  const float* W2  = (const float*)d_in[6];
  const float* a2s = (const float*)d_in[7];
  const float* a2d = (const float*)d_in[8];
  const float* b2  = (const float*)d_in[9];
  const float* W3  = (const float*)d_in[10];
  const float* a3s = (const float*)d_in[11];
  const float* a3d = (const float*)d_in[12];
  const float* b3  = (const float*)d_in[13];
  const float* Wl  = (const float*)d_in[14];
  const float* bl  = (const float*)d_in[15];

  const int N  = in_sizes[0] / 128;
  const int E  = in_sizes[1] / 2;
  const int EE = E + N;
  const int nbk = (N + 255) >> 8;

  char* p = (char*)d_ws;
  auto alloc = [&](size_t bytes) { char* r = p; p += (bytes + 255) & ~(size_t)255; return r; };
  unsigned* gbucket = (unsigned*)alloc((size_t)MAXBK * 4);
  unsigned* bbase   = (unsigned*)alloc((size_t)(MAXBK + 1) * 4);
  unsigned* bfill   = (unsigned*)alloc((size_t)MAXBK * 4);
  short8*   wf      = (short8*)alloc(2048 * 16);
  int*      rowptr  = (int*)alloc((size_t)(N + 1) * 4);
  int*      csr_src = (int*)alloc((size_t)EE * 4);
  unsigned* hbuf    = (unsigned*)alloc((size_t)N * 32 * 4);   // bf16-pair packed
  char*     regionA = alloc((size_t)EE * 8);                  // part[] then obuf
  float*    as_     = (float*)alloc((size_t)N * 4);
  float*    ad_     = (float*)alloc((size_t)N * 4);

  uint2*    part = (uint2*)regionA;            // CSR build scratch
  unsigned* obuf = (unsigned*)regionA;         // bf16-pair packed layer io

  hipMemsetAsync(gbucket, 0, (size_t)MAXBK * 4, stream);

  k_wprep<<<8, 256, 0, stream>>>(W1, W2, W3, wf);
  k_bhist<<<256, 256, 0, stream>>>(ei, gbucket, E, nbk);
  k_bscan<<<1, 256, 0, stream>>>(gbucket, bbase, bfill, nbk, EE, N);
  k_part<<<(EE + PCHUNK - 1) / PCHUNK, 256, 0, stream>>>(ei, bfill, part, E, EE);
  k_bcsr<<<nbk, 256, 0, stream>>>(part, bbase, rowptr, csr_src, N, nbk);

  int gb = (N + 127) / 128;
  int nb = (N + 7) / 8;

  // layer 1 (f32 x input, K=128)
  k_gemm7<128, true><<<gb, 256, 0, stream>>>(x, wf, a1s, a1d, hbuf, as_, ad_, N);
  k_agg9<0><<<nb, 256, 0, stream>>>(rowptr, csr_src, hbuf, as_, ad_, b1, obuf,
                                    nullptr, nullptr, nullptr, N);
  // layer 2 (bf16 obuf input, K=64)
  k_gemm7<64, false><<<gb, 256, 0, stream>>>(obuf, wf + 16 * 64, a2s, a2d,
                                             hbuf, as_, ad_, N);
  k_agg9<0><<<nb, 256, 0, stream>>>(rowptr, csr_src, hbuf, as_, ad_, b2, obuf,
                                    nullptr, nullptr, nullptr, N);
  // layer 3 (+ fused readout)
  k_gemm7<64, false><<<gb, 256, 0, stream>>>(obuf, wf + 24 * 64, a3s, a3d,
                                             hbuf, as_, ad_, N);
  k_agg9<1><<<nb, 256, 0, stream>>>(rowptr, csr_src, hbuf, as_, ad_, b3, nullptr,
                                    Wl, bl, (float*)d_out, N);
}

// Round 13
// 240.504 us; speedup vs baseline: 7.0994x; 1.0493x over previous
//
#include <hip/hip_runtime.h>
#include <hip/hip_bf16.h>
#include <math.h>

#define BSH 8          // 256 nodes per bucket
#define MAXBK 512      // >= nbk = ceil(N/256)
#define PCHUNK 4096    // edges per k_part block
#define BCSR_CAP 6144  // LDS-staged edges per bucket (48 KB)

typedef __attribute__((ext_vector_type(8)))  short short8;
typedef __attribute__((ext_vector_type(16))) float f32x16;

__device__ __forceinline__ float half_reduce_max(float v) {
  #pragma unroll
  for (int off = 16; off; off >>= 1) v = fmaxf(v, __shfl_xor(v, off));
  return v;
}
__device__ __forceinline__ float half_reduce_sum(float v) {
  #pragma unroll
  for (int off = 16; off; off >>= 1) v += __shfl_xor(v, off);
  return v;
}

// round-to-nearest-even f32 -> bf16 (as unsigned)
__device__ __forceinline__ unsigned f2bf(float f) {
  unsigned u = __float_as_uint(f);
  return (u + 0x7fffu + ((u >> 16) & 1u)) >> 16;
}
__device__ __forceinline__ float bf_lo(unsigned u) { return __uint_as_float(u << 16); }
__device__ __forceinline__ float bf_hi(unsigned u) { return __uint_as_float(u & 0xffff0000u); }

// async global->LDS, 16 B per lane (global_load_lds_dwordx4)
__device__ __forceinline__ void async_copy16(const void* gsrc, void* ldst) {
  __builtin_amdgcn_global_load_lds(
      (const __attribute__((address_space(1))) void*)gsrc,
      (__attribute__((address_space(3))) void*)ldst, 16, 0, 0);
}

// exclusive scan of arr[0..n) (n multiple of 64, <= MAXBK) by wave 0 of block
__device__ __forceinline__ void wave0_excl_scan(unsigned* arr, unsigned* out, int n, int t) {
  if (t < 64) {
    unsigned carry = 0;
    for (int c = 0; c < n / 64; c++) {
      unsigned v = arr[c * 64 + t];
      unsigned s = v;
      #pragma unroll
      for (int off = 1; off < 64; off <<= 1) {
        unsigned u = __shfl_up(s, off);
        if ((t & 63) >= off) s += u;
      }
      out[c * 64 + t] = s - v + carry;
      carry += __shfl(s, 63);
    }
  }
}

// ---------------- radix-bucketed CSR build (no global data atomics) -------

__global__ __launch_bounds__(256) void k_bhist(const int* __restrict__ ei,
                                               unsigned* __restrict__ gbucket,
                                               int E, int nbk) {
  __shared__ unsigned hist[MAXBK];
  int t = threadIdx.x;
  for (int i = t; i < nbk; i += 256) hist[i] = 0;
  __syncthreads();
  const int4* d4 = (const int4*)(ei + E);
  int nd4 = E >> 2;
  for (int i = blockIdx.x * 256 + t; i < nd4; i += gridDim.x * 256) {
    int4 d = d4[i];
    atomicAdd(&hist[d.x >> BSH], 1u);
    atomicAdd(&hist[d.y >> BSH], 1u);
    atomicAdd(&hist[d.z >> BSH], 1u);
    atomicAdd(&hist[d.w >> BSH], 1u);
  }
  if (blockIdx.x == 0) {
    for (int e = (nd4 << 2) + t; e < E; e += 256)
      atomicAdd(&hist[ei[E + e] >> BSH], 1u);
  }
  __syncthreads();
  for (int i = t; i < nbk; i += 256)
    if (hist[i]) atomicAdd(&gbucket[i], hist[i]);
}

// self-loop counts are analytic: bucket b holds min(256, N-256b) self loops
__global__ __launch_bounds__(256) void k_bscan(const unsigned* __restrict__ gbucket,
                                               unsigned* __restrict__ bbase,
                                               unsigned* __restrict__ bfill,
                                               int nbk, int EE, int Nn) {
  __shared__ unsigned arr[MAXBK], exc[MAXBK];
  int t = threadIdx.x;
  for (int i = t; i < MAXBK; i += 256) {
    unsigned v = 0;
    if (i < nbk) {
      int rem = Nn - (i << BSH);
      unsigned sl = rem >= 256 ? 256u : (unsigned)(rem > 0 ? rem : 0);
      v = gbucket[i] + sl;
    }
    arr[i] = v;
  }
  __syncthreads();
  wave0_excl_scan(arr, exc, MAXBK, t);
  __syncthreads();
  for (int i = t; i < nbk; i += 256) { bbase[i] = exc[i]; bfill[i] = exc[i]; }
  if (t == 0) bbase[nbk] = (unsigned)EE;
}

__global__ __launch_bounds__(256) void k_part(const int* __restrict__ ei,
                                              unsigned* __restrict__ bfill,
                                              uint2* __restrict__ part,
                                              int E, int EE) {
  __shared__ uint2 stage[PCHUNK];
  __shared__ unsigned lcnt[MAXBK], lexcl[MAXBK], lbase[MAXBK];
  int t = threadIdx.x;
  int base = blockIdx.x * PCHUNK;
  int cnt = EE - base; if (cnt > PCHUNK) cnt = PCHUNK;
  for (int i = t; i < MAXBK; i += 256) lcnt[i] = 0;
  __syncthreads();

  uint2 ed[16]; unsigned loc[16];
  #pragma unroll
  for (int i = 0; i < 16; i++) {
    int e = base + i * 256 + t;
    if (e < EE) {
      int s, d;
      if (e < E) { s = ei[e]; d = ei[E + e]; } else { s = e - E; d = s; }
      ed[i] = make_uint2((unsigned)s, (unsigned)d);
      loc[i] = atomicAdd(&lcnt[(unsigned)d >> BSH], 1u);
    }
  }
  __syncthreads();
  wave0_excl_scan(lcnt, lexcl, MAXBK, t);
  __syncthreads();
  for (int i = t; i < MAXBK; i += 256) {
    unsigned c = lcnt[i];
    lbase[i] = c ? atomicAdd(&bfill[i], c) : 0u;
  }
  __syncthreads();
  #pragma unroll
  for (int i = 0; i < 16; i++) {
    int e = base + i * 256 + t;
    if (e < EE) stage[lexcl[ed[i].y >> BSH] + loc[i]] = ed[i];
  }
  __syncthreads();
  for (int i = t; i < cnt; i += 256) {
    uint2 v = stage[i];
    unsigned b = v.y >> BSH;
    part[lbase[b] + ((unsigned)i - lexcl[b])] = v;
  }
}

__global__ __launch_bounds__(256) void k_bcsr(const uint2* __restrict__ part,
                                              const unsigned* __restrict__ bbase,
                                              int* __restrict__ rowptr,
                                              int* __restrict__ csr_src,
                                              int Nn, int nbk) {
  __shared__ unsigned sdeg[256], sexcl[256], sfill[256];
  __shared__ uint2 epart[BCSR_CAP];
  int t = threadIdx.x, b = blockIdx.x;
  int e0 = (int)bbase[b], e1 = (int)bbase[b + 1];
  int cnt = e1 - e0;
  bool fits = cnt <= BCSR_CAP;
  sdeg[t] = 0; sfill[t] = 0;
  __syncthreads();
  if (fits) {
    for (int j = t; j < cnt; j += 256) {
      uint2 v = part[e0 + j];
      epart[j] = v;
      atomicAdd(&sdeg[v.y & 255u], 1u);
    }
  } else {
    for (int j = e0 + t; j < e1; j += 256)
      atomicAdd(&sdeg[part[j].y & 255u], 1u);
  }
  __syncthreads();
  wave0_excl_scan(sdeg, sexcl, 256, t);
  __syncthreads();
  int node = (b << BSH) + t;
  if (node < Nn) rowptr[node] = e0 + (int)sexcl[t];
  if (b == nbk - 1 && t == 0) rowptr[Nn] = e1;
  if (fits) {
    for (int j = t; j < cnt; j += 256) {
      uint2 v = epart[j];
      unsigned dl = v.y & 255u;
      unsigned k = atomicAdd(&sfill[dl], 1u);
      csr_src[e0 + (int)sexcl[dl] + (int)k] = (int)v.x;
    }
  } else {
    for (int j = e0 + t; j < e1; j += 256) {
      uint2 v = part[j];
      unsigned dl = v.y & 255u;
      unsigned k = atomicAdd(&sfill[dl], 1u);
      csr_src[e0 + (int)sexcl[dl] + (int)k] = (int)v.x;
    }
  }
}

// ---------------- W fragment prep (frag-ordered bf16 for MFMA A-operand) --

__global__ __launch_bounds__(256) void k_wprep(const float* __restrict__ W1,
                                               const float* __restrict__ W2,
                                               const float* __restrict__ W3,
                                               short8* __restrict__ wf) {
  int idx = blockIdx.x * 256 + threadIdx.x;
  if (idx >= 2048) return;
  int g = idx >> 6, l = idx & 63;
  const float* W; int s, t;
  if (g < 16)      { W = W1; s = g >> 1;        t = g & 1; }
  else if (g < 24) { W = W2; s = (g - 16) >> 1; t = g & 1; }
  else             { W = W3; s = (g - 24) >> 1; t = g & 1; }
  int of = t * 32 + (l & 31);
  int k0 = s * 16 + (l >> 5) * 8;
  short8 v;
  #pragma unroll
  for (int e = 0; e < 8; e++) v[e] = (short)f2bf(W[(k0 + e) * 64 + of]);
  wf[idx] = v;
}

// ---------------- MFMA GEMM: h = x@W + fused alpha reductions -------------
// 128-thread/2-wave blocks, 64-row tiles, double-buffered LDS, grid-stride
// persistent: stage(t+1) issues before compute(t) so HBM fill overlaps MFMA.

template <int K, bool F32IN>
__global__ __launch_bounds__(128) void k_gemm8(
    const void* __restrict__ xin, const short8* __restrict__ wf,
    const float* __restrict__ avs, const float* __restrict__ avd,
    unsigned* __restrict__ h, float* __restrict__ as_out,
    float* __restrict__ ad_out, int Nn, int ntiles) {
  constexpr int NS = K / 16;                 // k-steps
  constexpr int RB = F32IN ? K * 4 : K * 2;  // row bytes (512 / 128)
  constexpr int RSH = F32IN ? 9 : (K == 128 ? 8 : 7);
  __shared__ __align__(16) char xs[2][64 * RB];
  int t = threadIdx.x, lane = t & 63, wid = t >> 6;   // wid in 0..1
  int l31 = lane & 31, hi = lane >> 5;

  short8 wa[NS * 2];
  #pragma unroll
  for (int i = 0; i < NS * 2; i++) wa[i] = wf[i * 64 + lane];

  const char* xg = (const char*)xin;
  auto stage = [&](int buf, int tl) {
    constexpr int CH = (64 * RB) / (128 * 16);
    #pragma unroll
    for (int i = 0; i < CH; i++) {
      int off = (i * 128 + t) * 16;
      int row = off >> RSH;
      int inrow = off & (RB - 1);
      long grow = (long)tl * 64 + row;
      if (grow > (long)Nn - 1) grow = Nn - 1;  // tail clamp (outputs guarded)
      async_copy16(xg + grow * RB + (inrow ^ ((row & 7) << 4)), xs[buf] + off);
    }
  };

  int tile = blockIdx.x;
  if (tile >= ntiles) return;
  stage(0, tile);
  __syncthreads();
  int buf = 0;

  while (tile < ntiles) {
    int nxt = tile + gridDim.x;
    if (nxt < ntiles) stage(buf ^ 1, nxt);

    f32x16 acc0 = {0,0,0,0,0,0,0,0,0,0,0,0,0,0,0,0};
    f32x16 acc1 = {0,0,0,0,0,0,0,0,0,0,0,0,0,0,0,0};
    int rowl = wid * 32 + l31;                 // 0..63
    int swz = (rowl & 7) << 4;
    const char* xb = xs[buf];

    #pragma unroll
    for (int s = 0; s < NS; s++) {
      short8 bf;
      if constexpr (F32IN) {
        int ph = (rowl * RB + s * 64 + hi * 32) ^ swz;
        float4 fA = *(const float4*)(xb + ph);
        float4 fB = *(const float4*)(xb + (ph ^ 16));
        bf[0] = (short)f2bf(fA.x); bf[1] = (short)f2bf(fA.y);
        bf[2] = (short)f2bf(fA.z); bf[3] = (short)f2bf(fA.w);
        bf[4] = (short)f2bf(fB.x); bf[5] = (short)f2bf(fB.y);
        bf[6] = (short)f2bf(fB.z); bf[7] = (short)f2bf(fB.w);
      } else {
        int ph = (rowl * RB + s * 32 + hi * 16) ^ swz;
        bf = *(const short8*)(xb + ph);
      }
      acc0 = __builtin_amdgcn_mfma_f32_32x32x16_bf16(wa[2 * s], bf, acc0, 0, 0, 0);
      acc1 = __builtin_amdgcn_mfma_f32_32x32x16_bf16(wa[2 * s + 1], bf, acc1, 0, 0, 0);
    }

    int xrow = tile * 64 + rowl;
    bool ok = xrow < Nn;
    float asp = 0.f, adp = 0.f;
    #pragma unroll
    for (int r = 0; r < 16; r += 2) {
      int rof = (r & 3) + 8 * (r >> 2);     // D row mapping (m74-verified)
      int of0 = rof + 4 * hi;
      if (ok) {
        h[(size_t)xrow * 32 + (of0 >> 1)] =
            (f2bf(acc0[r + 1]) << 16) | f2bf(acc0[r]);
        h[(size_t)xrow * 32 + 16 + (of0 >> 1)] =
            (f2bf(acc1[r + 1]) << 16) | f2bf(acc1[r]);
      }
      asp += acc0[r] * avs[of0] + acc0[r + 1] * avs[of0 + 1]
           + acc1[r] * avs[of0 + 32] + acc1[r + 1] * avs[of0 + 33];
      adp += acc0[r] * avd[of0] + acc0[r + 1] * avd[of0 + 1]
           + acc1[r] * avd[of0 + 32] + acc1[r + 1] * avd[of0 + 33];
    }
    asp += __shfl_xor(asp, 32);
    adp += __shfl_xor(adp, 32);
    if (ok && hi == 0) { as_out[xrow] = asp; ad_out[xrow] = adp; }

    __syncthreads();
    buf ^= 1;
    tile = nxt;
  }
}

// ---------------- per-dst-node softmax aggregation ----------------
// Half-wave per node. Phase B fully unrolled (8 static iterations, deg<=32):
// ALL uint2 gathers issue before any FMA consumes -> gather latency paid
// once per node instead of once per iteration.

template <int FINAL>
__global__ __launch_bounds__(256) void k_agg10(
    const int* __restrict__ rowptr, const int* __restrict__ csr_src,
    const unsigned* __restrict__ hp, const float* __restrict__ as_,
    const float* __restrict__ ad_, const float* __restrict__ bias,
    unsigned* __restrict__ out, const float* __restrict__ Wlin,
    const float* __restrict__ blin, float* __restrict__ fout, int Nn) {
  __shared__ float2 psbuf[4][2][32];
  int t = threadIdx.x, lane = t & 63, wid = t >> 6;
  int fl = lane & 31, hh = lane >> 5;
  int n = blockIdx.x * 8 + wid * 2 + hh;
  bool valid = n < Nn;
  int nn = valid ? n : (Nn - 1);
  int r0 = rowptr[nn], r1 = rowptr[nn + 1];
  int deg = valid ? (r1 - r0) : 0;
  float ad = ad_[nn];

  if (deg <= 32) {
    // phase A: edge-parallel scores + softmax (32 lanes)
    int src = (fl < deg) ? csr_src[r0 + fl] : 0;
    float e = (fl < deg) ? (as_[src] + ad) : -3.0e38f;
    e = (e >= 0.f) ? e : 0.2f * e;
    float m = half_reduce_max(e);
    float p = (fl < deg) ? __expf(e - m) : 0.f;
    float inv = 1.f / (half_reduce_sum(p) + 1e-16f);
    psbuf[wid][hh][fl] = make_float2(p, __uint_as_float((unsigned)src * 128u));

    // phase B: static 8-iteration unroll; all gathers issued before consume
    int sub = fl >> 4, q = fl & 15;
    const char* hq = (const char*)hp + q * 8;
    const float2* psb = psbuf[wid][hh];

    float pp0[8], pp1[8];
    uint2 vv0[8], vv1[8];
    #pragma unroll
    for (int it = 0; it < 8; it++) {
      if (it * 4 < deg) {
        float2 ps0 = psb[it * 4 + sub];
        float2 ps1 = psb[it * 4 + 2 + sub];
        pp0[it] = ps0.x;
        pp1[it] = ps1.x;
        vv0[it] = *(const uint2*)(hq + __float_as_uint(ps0.y));
        vv1[it] = *(const uint2*)(hq + __float_as_uint(ps1.y));
      }
    }
    float a0 = 0.f, a1 = 0.f, a2 = 0.f, a3 = 0.f;
    float b0 = 0.f, b1 = 0.f, b2 = 0.f, b3 = 0.f;
    #pragma unroll
    for (int it = 0; it < 8; it++) {
      if (it * 4 < deg) {
        a0 = fmaf(pp0[it], bf_lo(vv0[it].x), a0);
        a1 = fmaf(pp0[it], bf_hi(vv0[it].x), a1);
        a2 = fmaf(pp0[it], bf_lo(vv0[it].y), a2);
        a3 = fmaf(pp0[it], bf_hi(vv0[it].y), a3);
        b0 = fmaf(pp1[it], bf_lo(vv1[it].x), b0);
        b1 = fmaf(pp1[it], bf_hi(vv1[it].x), b1);
        b2 = fmaf(pp1[it], bf_lo(vv1[it].y), b2);
        b3 = fmaf(pp1[it], bf_hi(vv1[it].y), b3);
      }
    }
    a0 += b0; a1 += b1; a2 += b2; a3 += b3;
    a0 += __shfl_xor(a0, 16);              // combine edge parities
    a1 += __shfl_xor(a1, 16);
    a2 += __shfl_xor(a2, 16);
    a3 += __shfl_xor(a3, 16);

    float4 bi = ((const float4*)bias)[q];
    float o0 = fmaxf(fmaf(a0, inv, bi.x), 0.f);
    float o1 = fmaxf(fmaf(a1, inv, bi.y), 0.f);
    float o2 = fmaxf(fmaf(a2, inv, bi.z), 0.f);
    float o3 = fmaxf(fmaf(a3, inv, bi.w), 0.f);
    if (FINAL) {
      float4 wl = ((const float4*)Wlin)[q];
      float rv = (sub == 0) ? (o0 * wl.x + o1 * wl.y + o2 * wl.z + o3 * wl.w) : 0.f;
      rv = half_reduce_sum(rv);
      if (valid && fl == 0) {
        float z = rv + blin[0];
        fout[n] = 1.f / (1.f + __expf(-z));
      }
    } else if (valid && sub == 0) {
      uint2 pk;
      pk.x = (f2bf(o1) << 16) | f2bf(o0);
      pk.y = (f2bf(o3) << 16) | f2bf(o2);
      *(uint2*)(out + (size_t)n * 32 + 2 * q) = pk;
    }
  } else {
    // rare fallback (deg > 32): two-pass, serial recompute
    float acc0 = 0.f, acc1 = 0.f;
    float m = -3.0e38f;
    for (int j = r0 + fl; j < r1; j += 32) {
      float e = as_[csr_src[j]] + ad;
      e = (e >= 0.f) ? e : 0.2f * e;
      m = fmaxf(m, e);
    }
    m = half_reduce_max(m);
    float ssum = 0.f;
    for (int j = r0; j < r1; ++j) {
      int src = csr_src[j];
      float e = as_[src] + ad;
      e = (e >= 0.f) ? e : 0.2f * e;
      float p = __expf(e - m);
      ssum += p;
      unsigned v = hp[(size_t)src * 32 + fl];
      acc0 = fmaf(p, bf_lo(v), acc0);
      acc1 = fmaf(p, bf_hi(v), acc1);
    }
    float inv2 = 1.f / (ssum + 1e-16f);
    acc0 *= inv2;
    acc1 *= inv2;
    float2 bi = ((const float2*)bias)[fl];
    float o0 = fmaxf(acc0 + bi.x, 0.f);
    float o1 = fmaxf(acc1 + bi.y, 0.f);
    if (FINAL) {
      float2 wl = ((const float2*)Wlin)[fl];
      float rv = half_reduce_sum(o0 * wl.x + o1 * wl.y);
      if (valid && fl == 0) {
        float z = rv + blin[0];
        fout[n] = 1.f / (1.f + __expf(-z));
      }
    } else {
      if (valid) out[(size_t)n * 32 + fl] = (f2bf(o1) << 16) | f2bf(o0);
    }
  }
}

extern "C" void kernel_launch(void* const* d_in, const int* in_sizes, int n_in,
                              void* d_out, int out_size, void* d_ws, size_t ws_size,
                              hipStream_t stream) {
  const float* x   = (const float*)d_in[0];
  const int*   ei  = (const int*)d_in[1];
  const float* W1  = (const float*)d_in[2];
  const float* a1s = (const float*)d_in[3];
  const float* a1d = (const float*)d_in[4];
  const float* b1  = (const float*)d_in[5];
  const float* W2  = (const float*)d_in[6];
  const float* a2s = (const float*)d_in[7];
  const float* a2d = (const float*)d_in[8];
  const float* b2  = (const float*)d_in[9];
  const float* W3  = (const float*)d_in[10];
  const float* a3s = (const float*)d_in[11];
  const float* a3d = (const float*)d_in[12];
  const float* b3  = (const float*)d_in[13];
  const float* Wl  = (const float*)d_in[14];
  const float* bl  = (const float*)d_in[15];

  const int N  = in_sizes[0] / 128;
  const int E  = in_sizes[1] / 2;
  const int EE = E + N;
  const int nbk = (N + 255) >> 8;

  char* p = (char*)d_ws;
  auto alloc = [&](size_t bytes) { char* r = p; p += (bytes + 255) & ~(size_t)255; return r; };
  unsigned* gbucket = (unsigned*)alloc((size_t)MAXBK * 4);
  unsigned* bbase   = (unsigned*)alloc((size_t)(MAXBK + 1) * 4);
  unsigned* bfill   = (unsigned*)alloc((size_t)MAXBK * 4);
  short8*   wf      = (short8*)alloc(2048 * 16);
  int*      rowptr  = (int*)alloc((size_t)(N + 1) * 4);
  int*      csr_src = (int*)alloc((size_t)EE * 4);
  unsigned* hbuf    = (unsigned*)alloc((size_t)N * 32 * 4);   // bf16-pair packed
  char*     regionA = alloc((size_t)EE * 8);                  // part[] then obuf
  float*    as_     = (float*)alloc((size_t)N * 4);
  float*    ad_     = (float*)alloc((size_t)N * 4);

  uint2*    part = (uint2*)regionA;            // CSR build scratch
  unsigned* obuf = (unsigned*)regionA;         // bf16-pair packed layer io

  hipMemsetAsync(gbucket, 0, (size_t)MAXBK * 4, stream);

  k_wprep<<<8, 256, 0, stream>>>(W1, W2, W3, wf);
  k_bhist<<<256, 256, 0, stream>>>(ei, gbucket, E, nbk);
  k_bscan<<<1, 256, 0, stream>>>(gbucket, bbase, bfill, nbk, EE, N);
  k_part<<<(EE + PCHUNK - 1) / PCHUNK, 256, 0, stream>>>(ei, bfill, part, E, EE);
  k_bcsr<<<nbk, 256, 0, stream>>>(part, bbase, rowptr, csr_src, N, nbk);

  int ntile64 = (N + 63) / 64;
  int g1 = ntile64 < 512 ? ntile64 : 512;    // K=128: 64 KB LDS -> 2 blocks/CU
  int g2 = ntile64 < 768 ? ntile64 : 768;    // K=64: 16 KB LDS
  int nb = (N + 7) / 8;

  // layer 1 (f32 x input, K=128)
  k_gemm8<128, true><<<g1, 128, 0, stream>>>(x, wf, a1s, a1d, hbuf, as_, ad_, N, ntile64);
  k_agg10<0><<<nb, 256, 0, stream>>>(rowptr, csr_src, hbuf, as_, ad_, b1, obuf,
                                     nullptr, nullptr, nullptr, N);
  // layer 2 (bf16 obuf input, K=64)
  k_gemm8<64, false><<<g2, 128, 0, stream>>>(obuf, wf + 16 * 64, a2s, a2d,
                                             hbuf, as_, ad_, N, ntile64);
  k_agg10<0><<<nb, 256, 0, stream>>>(rowptr, csr_src, hbuf, as_, ad_, b2, obuf,
                                     nullptr, nullptr, nullptr, N);
  // layer 3 (+ fused readout)
  k_gemm8<64, false><<<g2, 128, 0, stream>>>(obuf, wf + 24 * 64, a3s, a3d,
                                             hbuf, as_, ad_, N, ntile64);
  k_agg10<1><<<nb, 256, 0, stream>>>(rowptr, csr_src, hbuf, as_, ad_, b3, nullptr,
                                     Wl, bl, (float*)d_out, N);
}

// Round 14
// 237.790 us; speedup vs baseline: 7.1805x; 1.0114x over previous
//
#include <hip/hip_runtime.h>
#include <hip/hip_bf16.h>
#include <math.h>

#define BSH 8          // 256 nodes per bucket
#define MAXBK 512      // >= nbk = ceil(N/256)
#define PCHUNK 4096    // edges per k_part block
#define BCSR_CAP 6144  // LDS-staged edges per bucket (48 KB)

typedef __attribute__((ext_vector_type(8)))  short short8;
typedef __attribute__((ext_vector_type(16))) float f32x16;

__device__ __forceinline__ float half_reduce_max(float v) {
  #pragma unroll
  for (int off = 16; off; off >>= 1) v = fmaxf(v, __shfl_xor(v, off));
  return v;
}
__device__ __forceinline__ float half_reduce_sum(float v) {
  #pragma unroll
  for (int off = 16; off; off >>= 1) v += __shfl_xor(v, off);
  return v;
}

// round-to-nearest-even f32 -> bf16 (as unsigned)
__device__ __forceinline__ unsigned f2bf(float f) {
  unsigned u = __float_as_uint(f);
  return (u + 0x7fffu + ((u >> 16) & 1u)) >> 16;
}
__device__ __forceinline__ float bf_lo(unsigned u) { return __uint_as_float(u << 16); }
__device__ __forceinline__ float bf_hi(unsigned u) { return __uint_as_float(u & 0xffff0000u); }

// async global->LDS, 16 B per lane (global_load_lds_dwordx4)
__device__ __forceinline__ void async_copy16(const void* gsrc, void* ldst) {
  __builtin_amdgcn_global_load_lds(
      (const __attribute__((address_space(1))) void*)gsrc,
      (__attribute__((address_space(3))) void*)ldst, 16, 0, 0);
}

// exclusive scan of arr[0..n) (n multiple of 64, <= MAXBK) by wave 0 of block
__device__ __forceinline__ void wave0_excl_scan(unsigned* arr, unsigned* out, int n, int t) {
  if (t < 64) {
    unsigned carry = 0;
    for (int c = 0; c < n / 64; c++) {
      unsigned v = arr[c * 64 + t];
      unsigned s = v;
      #pragma unroll
      for (int off = 1; off < 64; off <<= 1) {
        unsigned u = __shfl_up(s, off);
        if ((t & 63) >= off) s += u;
      }
      out[c * 64 + t] = s - v + carry;
      carry += __shfl(s, 63);
    }
  }
}

// ---------------- radix-bucketed CSR build (no global data atomics) -------

__global__ __launch_bounds__(256) void k_bhist(const int* __restrict__ ei,
                                               unsigned* __restrict__ gbucket,
                                               int E, int nbk) {
  __shared__ unsigned hist[MAXBK];
  int t = threadIdx.x;
  for (int i = t; i < nbk; i += 256) hist[i] = 0;
  __syncthreads();
  const int4* d4 = (const int4*)(ei + E);
  int nd4 = E >> 2;
  for (int i = blockIdx.x * 256 + t; i < nd4; i += gridDim.x * 256) {
    int4 d = d4[i];
    atomicAdd(&hist[d.x >> BSH], 1u);
    atomicAdd(&hist[d.y >> BSH], 1u);
    atomicAdd(&hist[d.z >> BSH], 1u);
    atomicAdd(&hist[d.w >> BSH], 1u);
  }
  if (blockIdx.x == 0) {
    for (int e = (nd4 << 2) + t; e < E; e += 256)
      atomicAdd(&hist[ei[E + e] >> BSH], 1u);
  }
  __syncthreads();
  for (int i = t; i < nbk; i += 256)
    if (hist[i]) atomicAdd(&gbucket[i], hist[i]);
}

// self-loop counts are analytic: bucket b holds min(256, N-256b) self loops
__global__ __launch_bounds__(256) void k_bscan(const unsigned* __restrict__ gbucket,
                                               unsigned* __restrict__ bbase,
                                               unsigned* __restrict__ bfill,
                                               int nbk, int EE, int Nn) {
  __shared__ unsigned arr[MAXBK], exc[MAXBK];
  int t = threadIdx.x;
  for (int i = t; i < MAXBK; i += 256) {
    unsigned v = 0;
    if (i < nbk) {
      int rem = Nn - (i << BSH);
      unsigned sl = rem >= 256 ? 256u : (unsigned)(rem > 0 ? rem : 0);
      v = gbucket[i] + sl;
    }
    arr[i] = v;
  }
  __syncthreads();
  wave0_excl_scan(arr, exc, MAXBK, t);
  __syncthreads();
  for (int i = t; i < nbk; i += 256) { bbase[i] = exc[i]; bfill[i] = exc[i]; }
  if (t == 0) bbase[nbk] = (unsigned)EE;
}

__global__ __launch_bounds__(256) void k_part(const int* __restrict__ ei,
                                              unsigned* __restrict__ bfill,
                                              uint2* __restrict__ part,
                                              int E, int EE) {
  __shared__ uint2 stage[PCHUNK];
  __shared__ unsigned lcnt[MAXBK], lexcl[MAXBK], lbase[MAXBK];
  int t = threadIdx.x;
  int base = blockIdx.x * PCHUNK;
  int cnt = EE - base; if (cnt > PCHUNK) cnt = PCHUNK;
  for (int i = t; i < MAXBK; i += 256) lcnt[i] = 0;
  __syncthreads();

  uint2 ed[16]; unsigned loc[16];
  #pragma unroll
  for (int i = 0; i < 16; i++) {
    int e = base + i * 256 + t;
    if (e < EE) {
      int s, d;
      if (e < E) { s = ei[e]; d = ei[E + e]; } else { s = e - E; d = s; }
      ed[i] = make_uint2((unsigned)s, (unsigned)d);
      loc[i] = atomicAdd(&lcnt[(unsigned)d >> BSH], 1u);
    }
  }
  __syncthreads();
  wave0_excl_scan(lcnt, lexcl, MAXBK, t);
  __syncthreads();
  for (int i = t; i < MAXBK; i += 256) {
    unsigned c = lcnt[i];
    lbase[i] = c ? atomicAdd(&bfill[i], c) : 0u;
  }
  __syncthreads();
  #pragma unroll
  for (int i = 0; i < 16; i++) {
    int e = base + i * 256 + t;
    if (e < EE) stage[lexcl[ed[i].y >> BSH] + loc[i]] = ed[i];
  }
  __syncthreads();
  for (int i = t; i < cnt; i += 256) {
    uint2 v = stage[i];
    unsigned b = v.y >> BSH;
    part[lbase[b] + ((unsigned)i - lexcl[b])] = v;
  }
}

__global__ __launch_bounds__(256) void k_bcsr(const uint2* __restrict__ part,
                                              const unsigned* __restrict__ bbase,
                                              int* __restrict__ rowptr,
                                              int* __restrict__ csr_src,
                                              int Nn, int nbk) {
  __shared__ unsigned sdeg[256], sexcl[256], sfill[256];
  __shared__ uint2 epart[BCSR_CAP];
  int t = threadIdx.x, b = blockIdx.x;
  int e0 = (int)bbase[b], e1 = (int)bbase[b + 1];
  int cnt = e1 - e0;
  bool fits = cnt <= BCSR_CAP;
  sdeg[t] = 0; sfill[t] = 0;
  __syncthreads();
  if (fits) {
    for (int j = t; j < cnt; j += 256) {
      uint2 v = part[e0 + j];
      epart[j] = v;
      atomicAdd(&sdeg[v.y & 255u], 1u);
    }
  } else {
    for (int j = e0 + t; j < e1; j += 256)
      atomicAdd(&sdeg[part[j].y & 255u], 1u);
  }
  __syncthreads();
  wave0_excl_scan(sdeg, sexcl, 256, t);
  __syncthreads();
  int node = (b << BSH) + t;
  if (node < Nn) rowptr[node] = e0 + (int)sexcl[t];
  if (b == nbk - 1 && t == 0) rowptr[Nn] = e1;
  if (fits) {
    for (int j = t; j < cnt; j += 256) {
      uint2 v = epart[j];
      unsigned dl = v.y & 255u;
      unsigned k = atomicAdd(&sfill[dl], 1u);
      csr_src[e0 + (int)sexcl[dl] + (int)k] = (int)v.x;
    }
  } else {
    for (int j = e0 + t; j < e1; j += 256) {
      uint2 v = part[j];
      unsigned dl = v.y & 255u;
      unsigned k = atomicAdd(&sfill[dl], 1u);
      csr_src[e0 + (int)sexcl[dl] + (int)k] = (int)v.x;
    }
  }
}

// ---------------- W fragment prep (frag-ordered bf16 for MFMA A-operand) --

__global__ __launch_bounds__(256) void k_wprep(const float* __restrict__ W1,
                                               const float* __restrict__ W2,
                                               const float* __restrict__ W3,
                                               short8* __restrict__ wf) {
  int idx = blockIdx.x * 256 + threadIdx.x;
  if (idx >= 2048) return;
  int g = idx >> 6, l = idx & 63;
  const float* W; int s, t;
  if (g < 16)      { W = W1; s = g >> 1;        t = g & 1; }
  else if (g < 24) { W = W2; s = (g - 16) >> 1; t = g & 1; }
  else             { W = W3; s = (g - 24) >> 1; t = g & 1; }
  int of = t * 32 + (l & 31);
  int k0 = s * 16 + (l >> 5) * 8;
  short8 v;
  #pragma unroll
  for (int e = 0; e < 8; e++) v[e] = (short)f2bf(W[(k0 + e) * 64 + of]);
  wf[idx] = v;
}

// ---------------- MFMA GEMM: h = x@W + fused alpha reductions -------------
// 128-thread/2-wave blocks, 64-row tiles, double-buffered LDS, grid-stride.

template <int K, bool F32IN>
__global__ __launch_bounds__(128) void k_gemm8(
    const void* __restrict__ xin, const short8* __restrict__ wf,
    const float* __restrict__ avs, const float* __restrict__ avd,
    unsigned* __restrict__ h, float* __restrict__ as_out,
    float* __restrict__ ad_out, int Nn, int ntiles) {
  constexpr int NS = K / 16;                 // k-steps
  constexpr int RB = F32IN ? K * 4 : K * 2;  // row bytes
  constexpr int RSH = F32IN ? 9 : (K == 128 ? 8 : 7);
  __shared__ __align__(16) char xs[2][64 * RB];
  int t = threadIdx.x, lane = t & 63, wid = t >> 6;   // wid in 0..1
  int l31 = lane & 31, hi = lane >> 5;

  short8 wa[NS * 2];
  #pragma unroll
  for (int i = 0; i < NS * 2; i++) wa[i] = wf[i * 64 + lane];

  const char* xg = (const char*)xin;
  auto stage = [&](int buf, int tl) {
    constexpr int CH = (64 * RB) / (128 * 16);
    #pragma unroll
    for (int i = 0; i < CH; i++) {
      int off = (i * 128 + t) * 16;
      int row = off >> RSH;
      int inrow = off & (RB - 1);
      long grow = (long)tl * 64 + row;
      if (grow > (long)Nn - 1) grow = Nn - 1;  // tail clamp (outputs guarded)
      async_copy16(xg + grow * RB + (inrow ^ ((row & 7) << 4)), xs[buf] + off);
    }
  };

  int tile = blockIdx.x;
  if (tile >= ntiles) return;
  stage(0, tile);
  __syncthreads();
  int buf = 0;

  while (tile < ntiles) {
    int nxt = tile + gridDim.x;
    if (nxt < ntiles) stage(buf ^ 1, nxt);

    f32x16 acc0 = {0,0,0,0,0,0,0,0,0,0,0,0,0,0,0,0};
    f32x16 acc1 = {0,0,0,0,0,0,0,0,0,0,0,0,0,0,0,0};
    int rowl = wid * 32 + l31;                 // 0..63
    int swz = (rowl & 7) << 4;
    const char* xb = xs[buf];

    #pragma unroll
    for (int s = 0; s < NS; s++) {
      short8 bf;
      if constexpr (F32IN) {
        int ph = (rowl * RB + s * 64 + hi * 32) ^ swz;
        float4 fA = *(const float4*)(xb + ph);
        float4 fB = *(const float4*)(xb + (ph ^ 16));
        bf[0] = (short)f2bf(fA.x); bf[1] = (short)f2bf(fA.y);
        bf[2] = (short)f2bf(fA.z); bf[3] = (short)f2bf(fA.w);
        bf[4] = (short)f2bf(fB.x); bf[5] = (short)f2bf(fB.y);
        bf[6] = (short)f2bf(fB.z); bf[7] = (short)f2bf(fB.w);
      } else {
        int ph = (rowl * RB + s * 32 + hi * 16) ^ swz;
        bf = *(const short8*)(xb + ph);
      }
      acc0 = __builtin_amdgcn_mfma_f32_32x32x16_bf16(wa[2 * s], bf, acc0, 0, 0, 0);
      acc1 = __builtin_amdgcn_mfma_f32_32x32x16_bf16(wa[2 * s + 1], bf, acc1, 0, 0, 0);
    }

    int xrow = tile * 64 + rowl;
    bool ok = xrow < Nn;
    float asp = 0.f, adp = 0.f;
    #pragma unroll
    for (int r = 0; r < 16; r += 2) {
      int rof = (r & 3) + 8 * (r >> 2);     // D row mapping (m74-verified)
      int of0 = rof + 4 * hi;
      if (ok) {
        h[(size_t)xrow * 32 + (of0 >> 1)] =
            (f2bf(acc0[r + 1]) << 16) | f2bf(acc0[r]);
        h[(size_t)xrow * 32 + 16 + (of0 >> 1)] =
            (f2bf(acc1[r + 1]) << 16) | f2bf(acc1[r]);
      }
      asp += acc0[r] * avs[of0] + acc0[r + 1] * avs[of0 + 1]
           + acc1[r] * avs[of0 + 32] + acc1[r + 1] * avs[of0 + 33];
      adp += acc0[r] * avd[of0] + acc0[r + 1] * avd[of0 + 1]
           + acc1[r] * avd[of0 + 32] + acc1[r + 1] * avd[of0 + 33];
    }
    asp += __shfl_xor(asp, 32);
    adp += __shfl_xor(adp, 32);
    if (ok && hi == 0) { as_out[xrow] = asp; ad_out[xrow] = adp; }

    __syncthreads();
    buf ^= 1;
    tile = nxt;
  }
}

// ---------------- per-dst-node softmax aggregation ----------------
// Half-wave per node. Phase B: uint4 gathers — 8 lanes cover one 128-B edge
// row, so one half-wave instruction fetches FOUR edges (sub = fl>>3 edge
// slot, oc = fl&7 row octant). Per node: <=4 gather rounds of 4 edges.
// Combine across edge slots via shfl_xor(8)+shfl_xor(16).

template <int FINAL>
__global__ __launch_bounds__(256) void k_agg11(
    const int* __restrict__ rowptr, const int* __restrict__ csr_src,
    const unsigned* __restrict__ hp, const float* __restrict__ as_,
    const float* __restrict__ ad_, const float* __restrict__ bias,
    unsigned* __restrict__ out, const float* __restrict__ Wlin,
    const float* __restrict__ blin, float* __restrict__ fout, int Nn) {
  __shared__ float2 psbuf[4][2][32];
  int t = threadIdx.x, lane = t & 63, wid = t >> 6;
  int fl = lane & 31, hh = lane >> 5;
  int n = blockIdx.x * 8 + wid * 2 + hh;
  bool valid = n < Nn;
  int nn = valid ? n : (Nn - 1);
  int r0 = rowptr[nn], r1 = rowptr[nn + 1];
  int deg = valid ? (r1 - r0) : 0;
  float ad = ad_[nn];

  if (deg <= 32) {
    // phase A: edge-parallel scores + softmax (32 lanes)
    int src = (fl < deg) ? csr_src[r0 + fl] : 0;
    float e = (fl < deg) ? (as_[src] + ad) : -3.0e38f;
    e = (e >= 0.f) ? e : 0.2f * e;
    float m = half_reduce_max(e);
    float p = (fl < deg) ? __expf(e - m) : 0.f;
    float inv = 1.f / (half_reduce_sum(p) + 1e-16f);
    psbuf[wid][hh][fl] = make_float2(p, __uint_as_float((unsigned)src * 128u));

    // phase B: 4 edges per gather instruction (8 lanes/edge)
    int sub = fl >> 3, oc = fl & 7;
    const char* hq = (const char*)hp + oc * 16;
    const float2* psb = psbuf[wid][hh];

    float pp[8];
    uint4 vv[8];
    #pragma unroll
    for (int it = 0; it < 8; it++) {
      if (it * 4 < deg) {
        float2 ps = psb[it * 4 + sub];
        pp[it] = ps.x;
        vv[it] = *(const uint4*)(hq + __float_as_uint(ps.y));
      }
    }
    float a0 = 0.f, a1 = 0.f, a2 = 0.f, a3 = 0.f;
    float a4 = 0.f, a5 = 0.f, a6 = 0.f, a7 = 0.f;
    #pragma unroll
    for (int it = 0; it < 8; it++) {
      if (it * 4 < deg) {
        a0 = fmaf(pp[it], bf_lo(vv[it].x), a0);
        a1 = fmaf(pp[it], bf_hi(vv[it].x), a1);
        a2 = fmaf(pp[it], bf_lo(vv[it].y), a2);
        a3 = fmaf(pp[it], bf_hi(vv[it].y), a3);
        a4 = fmaf(pp[it], bf_lo(vv[it].z), a4);
        a5 = fmaf(pp[it], bf_hi(vv[it].z), a5);
        a6 = fmaf(pp[it], bf_lo(vv[it].w), a6);
        a7 = fmaf(pp[it], bf_hi(vv[it].w), a7);
      }
    }
    #pragma unroll
    for (int off = 8; off <= 16; off <<= 1) {   // combine edge slots
      a0 += __shfl_xor(a0, off);
      a1 += __shfl_xor(a1, off);
      a2 += __shfl_xor(a2, off);
      a3 += __shfl_xor(a3, off);
      a4 += __shfl_xor(a4, off);
      a5 += __shfl_xor(a5, off);
      a6 += __shfl_xor(a6, off);
      a7 += __shfl_xor(a7, off);
    }

    float4 biA = ((const float4*)bias)[2 * oc];
    float4 biB = ((const float4*)bias)[2 * oc + 1];
    float o0 = fmaxf(fmaf(a0, inv, biA.x), 0.f);
    float o1 = fmaxf(fmaf(a1, inv, biA.y), 0.f);
    float o2 = fmaxf(fmaf(a2, inv, biA.z), 0.f);
    float o3 = fmaxf(fmaf(a3, inv, biA.w), 0.f);
    float o4 = fmaxf(fmaf(a4, inv, biB.x), 0.f);
    float o5 = fmaxf(fmaf(a5, inv, biB.y), 0.f);
    float o6 = fmaxf(fmaf(a6, inv, biB.z), 0.f);
    float o7 = fmaxf(fmaf(a7, inv, biB.w), 0.f);
    if (FINAL) {
      float4 wlA = ((const float4*)Wlin)[2 * oc];
      float4 wlB = ((const float4*)Wlin)[2 * oc + 1];
      float rv = (sub == 0)
          ? (o0 * wlA.x + o1 * wlA.y + o2 * wlA.z + o3 * wlA.w +
             o4 * wlB.x + o5 * wlB.y + o6 * wlB.z + o7 * wlB.w) : 0.f;
      rv = half_reduce_sum(rv);
      if (valid && fl == 0) {
        float z = rv + blin[0];
        fout[n] = 1.f / (1.f + __expf(-z));
      }
    } else if (valid && sub == 0) {
      uint4 pk;
      pk.x = (f2bf(o1) << 16) | f2bf(o0);
      pk.y = (f2bf(o3) << 16) | f2bf(o2);
      pk.z = (f2bf(o5) << 16) | f2bf(o4);
      pk.w = (f2bf(o7) << 16) | f2bf(o6);
      *(uint4*)(out + (size_t)n * 32 + 4 * oc) = pk;
    }
  } else {
    // rare fallback (deg > 32): two-pass, serial recompute
    float acc0 = 0.f, acc1 = 0.f;
    float m = -3.0e38f;
    for (int j = r0 + fl; j < r1; j += 32) {
      float e = as_[csr_src[j]] + ad;
      e = (e >= 0.f) ? e : 0.2f * e;
      m = fmaxf(m, e);
    }
    m = half_reduce_max(m);
    float ssum = 0.f;
    for (int j = r0; j < r1; ++j) {
      int src = csr_src[j];
      float e = as_[src] + ad;
      e = (e >= 0.f) ? e : 0.2f * e;
      float p = __expf(e - m);
      ssum += p;
      unsigned v = hp[(size_t)src * 32 + fl];
      acc0 = fmaf(p, bf_lo(v), acc0);
      acc1 = fmaf(p, bf_hi(v), acc1);
    }
    float inv2 = 1.f / (ssum + 1e-16f);
    acc0 *= inv2;
    acc1 *= inv2;
    float2 bi = ((const float2*)bias)[fl];
    float o0 = fmaxf(acc0 + bi.x, 0.f);
    float o1 = fmaxf(acc1 + bi.y, 0.f);
    if (FINAL) {
      float2 wl = ((const float2*)Wlin)[fl];
      float rv = half_reduce_sum(o0 * wl.x + o1 * wl.y);
      if (valid && fl == 0) {
        float z = rv + blin[0];
        fout[n] = 1.f / (1.f + __expf(-z));
      }
    } else {
      if (valid) out[(size_t)n * 32 + fl] = (f2bf(o1) << 16) | f2bf(o0);
    }
  }
}

extern "C" void kernel_launch(void* const* d_in, const int* in_sizes, int n_in,
                              void* d_out, int out_size, void* d_ws, size_t ws_size,
                              hipStream_t stream) {
  const float* x   = (const float*)d_in[0];
  const int*   ei  = (const int*)d_in[1];
  const float* W1  = (const float*)d_in[2];
  const float* a1s = (const float*)d_in[3];
  const float* a1d = (const float*)d_in[4];
  const float* b1  = (const float*)d_in[5];
  const float* W2  = (const float*)d_in[6];
  const float* a2s = (const float*)d_in[7];
  const float* a2d = (const float*)d_in[8];
  const float* b2  = (const float*)d_in[9];
  const float* W3  = (const float*)d_in[10];
  const float* a3s = (const float*)d_in[11];
  const float* a3d = (const float*)d_in[12];
  const float* b3  = (const float*)d_in[13];
  const float* Wl  = (const float*)d_in[14];
  const float* bl  = (const float*)d_in[15];

  const int N  = in_sizes[0] / 128;
  const int E  = in_sizes[1] / 2;
  const int EE = E + N;
  const int nbk = (N + 255) >> 8;

  char* p = (char*)d_ws;
  auto alloc = [&](size_t bytes) { char* r = p; p += (bytes + 255) & ~(size_t)255; return r; };
  unsigned* gbucket = (unsigned*)alloc((size_t)MAXBK * 4);
  unsigned* bbase   = (unsigned*)alloc((size_t)(MAXBK + 1) * 4);
  unsigned* bfill   = (unsigned*)alloc((size_t)MAXBK * 4);
  short8*   wf      = (short8*)alloc(2048 * 16);
  int*      rowptr  = (int*)alloc((size_t)(N + 1) * 4);
  int*      csr_src = (int*)alloc((size_t)EE * 4);
  unsigned* hbuf    = (unsigned*)alloc((size_t)N * 32 * 4);   // bf16-pair packed
  char*     regionA = alloc((size_t)EE * 8);                  // part[] then obuf
  float*    as_     = (float*)alloc((size_t)N * 4);
  float*    ad_     = (float*)alloc((size_t)N * 4);

  uint2*    part = (uint2*)regionA;            // CSR build scratch
  unsigned* obuf = (unsigned*)regionA;         // bf16-pair packed layer io

  hipMemsetAsync(gbucket, 0, (size_t)MAXBK * 4, stream);

  k_wprep<<<8, 256, 0, stream>>>(W1, W2, W3, wf);
  k_bhist<<<256, 256, 0, stream>>>(ei, gbucket, E, nbk);
  k_bscan<<<1, 256, 0, stream>>>(gbucket, bbase, bfill, nbk, EE, N);
  k_part<<<(EE + PCHUNK - 1) / PCHUNK, 256, 0, stream>>>(ei, bfill, part, E, EE);
  k_bcsr<<<nbk, 256, 0, stream>>>(part, bbase, rowptr, csr_src, N, nbk);

  int ntile64 = (N + 63) / 64;
  int g1 = ntile64 < 512 ? ntile64 : 512;
  int g2 = ntile64 < 768 ? ntile64 : 768;
  int nb = (N + 7) / 8;

  // layer 1 (f32 x input, K=128)
  k_gemm8<128, true><<<g1, 128, 0, stream>>>(x, wf, a1s, a1d, hbuf, as_, ad_, N, ntile64);
  k_agg11<0><<<nb, 256, 0, stream>>>(rowptr, csr_src, hbuf, as_, ad_, b1, obuf,
                                     nullptr, nullptr, nullptr, N);
  // layer 2 (bf16 obuf input, K=64)
  k_gemm8<64, false><<<g2, 128, 0, stream>>>(obuf, wf + 16 * 64, a2s, a2d,
                                             hbuf, as_, ad_, N, ntile64);
  k_agg11<0><<<nb, 256, 0, stream>>>(rowptr, csr_src, hbuf, as_, ad_, b2, obuf,
                                     nullptr, nullptr, nullptr, N);
  // layer 3 (+ fused readout)
  k_gemm8<64, false><<<g2, 128, 0, stream>>>(obuf, wf + 24 * 64, a3s, a3d,
                                             hbuf, as_, ad_, N, ntile64);
  k_agg11<1><<<nb, 256, 0, stream>>>(rowptr, csr_src, hbuf, as_, ad_, b3, nullptr,
                                     Wl, bl, (float*)d_out, N);
}